// Round 5
// baseline (507.295 us; speedup 1.0000x reference)
//
#include <hip/hip_runtime.h>
#include <stdint.h>

// Titans-L2 chunked delta-rule forward — WY (rank-structured) reformulation.
//   1. cast x -> bf16; transpose+cast Wq/Wk/Wv/Wo -> bf16 [N,K]
//   2. MFMA GEMMs: q,k,v = x@W  ([B,H,T,D] f32)
//   3. wy_solve (per chunk): normalize k; S = a*tril(K K^T,-1) (split-bf16 MFMA);
//      blocked forward substitution: (I+S)U = K, (I+S)W = b*V; writes U,W packed
//      hi/lo bf16 and normalized K.
//   4. ab_compute: A = I - a*U^T K, B = W^T K (MFMA on transpose-staged operands)
//   5. chunk_scan: M_{c+1} = M_c A_c + B_c (unchanged); emits Mstart + M_final
//   6. y_assemble: G = tril(Q K^T,-1); Wt = W - a*(U M0^T);
//      Y = Q M0^T + G Wt; writes y as bf16 [B*T, C] (fused cast+layout)
//   7. final MFMA GEMM y@Wo -> d_out
// All MFMA matmuls use hi/lo bf16 split (3 products) ~= fp32 precision.
// Dims: B=4 H=16 T=2048 C=1024 D=64 CS=128 nc=16 N=1024 tokens=8192

#define DEV __device__ __forceinline__

typedef __attribute__((ext_vector_type(4))) float f32x4;
typedef __attribute__((ext_vector_type(8))) __bf16 bf16x8;
typedef __attribute__((ext_vector_type(4))) __bf16 bf16x4;

typedef const __attribute__((address_space(1))) uint32_t* gas1_t;
typedef __attribute__((address_space(3))) uint32_t* las3_t;

DEV void gload_lds16(const void* g, void* l) {
  __builtin_amdgcn_global_load_lds((gas1_t)g, (las3_t)l, 16, 0, 0);
}

DEV float sgm(float x) { return 1.f / (1.f + __expf(-x)); }

template <int CTRL>
DEV float dpp_mov(float x) {
  return __builtin_bit_cast(
      float, __builtin_amdgcn_mov_dpp(__builtin_bit_cast(int, x), CTRL, 0xF, 0xF, true));
}
// cyclic rotate-reduce: sum over each 16-lane DPP row
DEV float row16_reduce(float x) {
  x += dpp_mov<0x121>(x);  // row_ror:1
  x += dpp_mov<0x122>(x);  // row_ror:2
  x += dpp_mov<0x124>(x);  // row_ror:4
  x += dpp_mov<0x128>(x);  // row_ror:8
  return x;
}

// ---- swizzled LDS helpers (row-major bf16 tiles; XOR bank swizzle) ----
DEV int swzb(int row, int col, int stride) {  // byte offset
  return ((row * stride + col) << 1) ^ ((row & 7) << 4);
}
DEV bf16x8 ldfrag(const __bf16* B, int row, int col, int stride) {
  return *(const bf16x8*)((const char*)B + swzb(row, col, stride));
}
DEV void sthl(__bf16* H, __bf16* L, int row, int col, int stride, float v) {
  __bf16 h = (__bf16)v;
  int off = swzb(row, col, stride);
  *(__bf16*)((char*)H + off) = h;
  *(__bf16*)((char*)L + off) = (__bf16)(v - (float)h);
}
DEV void sthl4(__bf16* H, __bf16* L, int row, int c4, int stride, float4 v) {
  float vv[4] = {v.x, v.y, v.z, v.w};
  bf16x4 hh, ll;
#pragma unroll
  for (int e = 0; e < 4; ++e) {
    __bf16 h = (__bf16)vv[e];
    hh[e] = h;
    ll[e] = (__bf16)(vv[e] - (float)h);
  }
  int off = swzb(row, c4, stride);
  *(bf16x4*)((char*)H + off) = hh;
  *(bf16x4*)((char*)L + off) = ll;
}
DEV void stpk(__bf16* H, __bf16* L, int row, int col, int stride, uint32_t p) {
  int off = swzb(row, col, stride);
  *(uint16_t*)((char*)H + off) = (uint16_t)(p >> 16);
  *(uint16_t*)((char*)L + off) = (uint16_t)p;
}
DEV uint32_t packhl(float v) {
  __bf16 h = (__bf16)v;
  __bf16 l = (__bf16)(v - (float)h);
  return ((uint32_t)__builtin_bit_cast(uint16_t, h) << 16) |
         (uint32_t)__builtin_bit_cast(uint16_t, l);
}
DEV float unpk(uint32_t p) {
  __bf16 h = __builtin_bit_cast(__bf16, (uint16_t)(p >> 16));
  __bf16 l = __builtin_bit_cast(__bf16, (uint16_t)(p & 0xffff));
  return (float)h + (float)l;
}
DEV f32x4 mm3(bf16x8 ah, bf16x8 al, bf16x8 bh, bf16x8 bl, f32x4 acc) {
  acc = __builtin_amdgcn_mfma_f32_16x16x32_bf16(ah, bh, acc, 0, 0, 0);
  acc = __builtin_amdgcn_mfma_f32_16x16x32_bf16(ah, bl, acc, 0, 0, 0);
  acc = __builtin_amdgcn_mfma_f32_16x16x32_bf16(al, bh, acc, 0, 0, 0);
  return acc;
}
// packed-lower G/S tile offsets: row tr holds tiles 0..tr (+1 zero pad for even tr)
DEV int goffn(int tr) {
  int m = tr >> 1;
  return (tr & 1) ? (2 * m * m + 4 * m + 2) : (2 * m * m + 2 * m);
}
DEV int stile(int tr, int sc) { return ((tr * (tr + 1)) / 2 + sc) * 256; }

// ---------------- casts ----------------
__global__ __launch_bounds__(256) void cast_f32_bf16(const float* __restrict__ in,
                                                     __bf16* __restrict__ out) {
  int idx = blockIdx.x * 256 + threadIdx.x;
  float4 v = ((const float4*)in)[idx];
  bf16x4 o;
  o[0] = (__bf16)v.x; o[1] = (__bf16)v.y; o[2] = (__bf16)v.z; o[3] = (__bf16)v.w;
  ((bf16x4*)out)[idx] = o;
}

__global__ __launch_bounds__(256) void transpose_cast(const float* __restrict__ W,
                                                      __bf16* __restrict__ Wt) {
  __shared__ float tile[32][33];
  int tx = threadIdx.x & 31, ty = threadIdx.x >> 5;
  int n0 = blockIdx.x * 32, k0 = blockIdx.y * 32;
#pragma unroll
  for (int u = 0; u < 4; ++u)
    tile[ty + u * 8][tx] = W[(size_t)(k0 + ty + u * 8) * 1024 + n0 + tx];
  __syncthreads();
#pragma unroll
  for (int u = 0; u < 4; ++u)
    Wt[(size_t)(n0 + ty + u * 8) * 1024 + k0 + tx] = (__bf16)tile[tx][ty + u * 8];
}

// ---------------- GEMM (unchanged) ----------------
__global__ __launch_bounds__(256) void gemm_bt(const __bf16* __restrict__ A,
                                               const __bf16* __restrict__ Bt,
                                               float* __restrict__ C, int mode) {
  const int t = threadIdx.x;
  const int wv = t >> 6, lane = t & 63;
  const int bm = blockIdx.y, bn = blockIdx.x;
  const int K = 1024;
  __shared__ __bf16 lA[4096];
  __shared__ __bf16 lB[4096];
  f32x4 acc[4][4];
#pragma unroll
  for (int m = 0; m < 4; ++m)
#pragma unroll
    for (int n = 0; n < 4; ++n) acc[m][n] = 0.f;
  const int wr = wv >> 1, wc = wv & 1;
  const int fr = lane & 15, fk = (lane >> 4) * 8;
  const int e0 = (wv * 128 + lane) * 8;
  const int e1 = (wv * 128 + 64 + lane) * 8;
  const int r0s = e0 >> 5, c0s = e0 & 31;
  const int r1s = e1 >> 5, c1s = e1 & 31;
  for (int k0 = 0; k0 < K; k0 += 32) {
    gload_lds16(A + (size_t)(bm * 128 + r0s) * K + k0 + c0s, lA + wv * 1024);
    gload_lds16(Bt + (size_t)(bn * 128 + r0s) * K + k0 + c0s, lB + wv * 1024);
    gload_lds16(A + (size_t)(bm * 128 + r1s) * K + k0 + c1s, lA + wv * 1024 + 512);
    gload_lds16(Bt + (size_t)(bn * 128 + r1s) * K + k0 + c1s, lB + wv * 1024 + 512);
    __syncthreads();
    bf16x8 af[4], bg[4];
#pragma unroll
    for (int m = 0; m < 4; ++m)
      af[m] = *(const bf16x8*)(lA + (wr * 64 + m * 16 + fr) * 32 + fk);
#pragma unroll
    for (int n = 0; n < 4; ++n)
      bg[n] = *(const bf16x8*)(lB + (wc * 64 + n * 16 + fr) * 32 + fk);
#pragma unroll
    for (int m = 0; m < 4; ++m)
#pragma unroll
      for (int n = 0; n < 4; ++n)
        acc[m][n] = __builtin_amdgcn_mfma_f32_16x16x32_bf16(af[m], bg[n], acc[m][n], 0, 0, 0);
    __syncthreads();
  }
  const int rr = (lane >> 4) * 4, cl = lane & 15;
#pragma unroll
  for (int m = 0; m < 4; ++m) {
#pragma unroll
    for (int n = 0; n < 4; ++n) {
#pragma unroll
      for (int rg = 0; rg < 4; ++rg) {
        int row = bm * 128 + wr * 64 + m * 16 + rr + rg;
        int col = bn * 128 + wc * 64 + n * 16 + cl;
        float val = acc[m][n][rg];
        if (mode == 0) {
          C[(size_t)row * 1024 + col] = val;
        } else {
          int b = row >> 11, tk = row & 2047;
          int h = col >> 6, d = col & 63;
          C[(((size_t)b * 16 + h) * 2048 + tk) * 64 + d] = val;
        }
      }
    }
  }
}

// ---------------- WY solve: U, W per chunk ----------------
// (I + a*tril(KK^T,-1)) U = K ; (I + a*L) W = b*V. K normalized in place.
__global__ __launch_bounds__(512) void wy_solve(float* __restrict__ kb,
                                                const float* __restrict__ vb,
                                                const float* __restrict__ ar,
                                                const float* __restrict__ br,
                                                uint32_t* __restrict__ Ug,
                                                uint32_t* __restrict__ Wg) {
  int n = blockIdx.x, h = (n >> 4) & 15;
  float a = sgm(ar[h]) * 0.5f;
  float b = sgm(br[h]) * 0.5f;
  int t = threadIdx.x, wid = t >> 6, lane = t & 63;
  int fr = lane & 15, fk = (lane >> 4) * 8;
  __shared__ __bf16 Kh[8192], Kl[8192];  // [128][64] swizzled
  __shared__ float Sa[9216];             // 36 packed 16x16 tiles = a*tril(KK^T)
  __shared__ float Uf[8192], Wf[8192];   // [128][64]
  float* kg = kb + (size_t)n * 8192;
  const float* vg = vb + (size_t)n * 8192;
  // stage + normalize k; init U=k, W=b*v
#pragma unroll
  for (int it = 0; it < 4; ++it) {
    int u = it * 512 + t;
    int row = u >> 4, c4 = (u & 15) * 4;
    float4 kv = ((const float4*)kg)[u];
    float ssq = kv.x * kv.x + kv.y * kv.y + kv.z * kv.z + kv.w * kv.w;
    ssq = row16_reduce(ssq);
    float inv = 1.f / fmaxf(sqrtf(ssq), 1e-12f);
    kv.x *= inv; kv.y *= inv; kv.z *= inv; kv.w *= inv;
    ((float4*)kg)[u] = kv;
    sthl4(Kh, Kl, row, c4, 64, kv);
    *(float4*)(Uf + row * 64 + c4) = kv;
    float4 vv = ((const float4*)vg)[u];
    vv.x *= b; vv.y *= b; vv.z *= b; vv.w *= b;
    *(float4*)(Wf + row * 64 + c4) = vv;
  }
  __syncthreads();
  // S tiles (lower incl diag, strict-lower masked), scaled by a
  for (int p = wid; p < 36; p += 8) {
    int tr = 0, pp = p;
    while (pp > tr) { pp -= (tr + 1); ++tr; }
    int sc = pp;
    f32x4 acc = {0.f, 0.f, 0.f, 0.f};
#pragma unroll
    for (int ks = 0; ks < 2; ++ks) {
      bf16x8 ah = ldfrag(Kh, tr * 16 + fr, ks * 32 + fk, 64);
      bf16x8 al = ldfrag(Kl, tr * 16 + fr, ks * 32 + fk, 64);
      bf16x8 bh = ldfrag(Kh, sc * 16 + fr, ks * 32 + fk, 64);
      bf16x8 bl = ldfrag(Kl, sc * 16 + fr, ks * 32 + fk, 64);
      acc = mm3(ah, al, bh, bl, acc);
    }
    float* dst = Sa + stile(tr, sc);
    int row0 = (lane >> 4) * 4, col = lane & 15;
#pragma unroll
    for (int rg = 0; rg < 4; ++rg) {
      int r = row0 + rg;
      float v = a * acc[rg];
      if (tr == sc && col >= r) v = 0.f;
      dst[r * 16 + col] = v;
    }
  }
  __syncthreads();
  // blocked forward substitution
  for (int bb = 0; bb < 8; ++bb) {
    if (bb) {
      // off-diagonal: M[16bb+tt][d] -= sum_{s<16bb} Sa[t][s]*M[s][d]
#pragma unroll
      for (int p = 0; p < 4; ++p) {
        int g = p * 8 + wid;           // 0..31
        int tt = g & 15, mat = g >> 4; // wave-uniform
        float* M = mat ? Wf : Uf;
        int trow = bb * 16 + tt;
        float acc = 0.f;
        for (int s = 0; s < bb * 16; ++s)
          acc += Sa[stile(bb, s >> 4) + tt * 16 + (s & 15)] * M[s * 64 + lane];
        M[trow * 64 + lane] -= acc;
      }
      __syncthreads();
    }
    // diagonal 16-step solve: wave0 -> U, wave1 -> W (lane = d)
    if (wid < 2) {
      float* M = wid ? Wf : Uf;
      const float* Sd = Sa + stile(bb, bb);
      float r[16];
#pragma unroll
      for (int j = 0; j < 16; ++j) r[j] = M[(bb * 16 + j) * 64 + lane];
#pragma unroll
      for (int tt = 1; tt < 16; ++tt) {
        float acc = 0.f;
#pragma unroll
        for (int s = 0; s < tt; ++s) acc += Sd[tt * 16 + s] * r[s];
        r[tt] -= acc;
      }
#pragma unroll
      for (int j = 0; j < 16; ++j) M[(bb * 16 + j) * 64 + lane] = r[j];
    }
    __syncthreads();
  }
  // write out packed hi/lo
  uint32_t* ug = Ug + (size_t)n * 8192;
  uint32_t* wgo = Wg + (size_t)n * 8192;
#pragma unroll
  for (int it = 0; it < 16; ++it) {
    int e = it * 512 + t;
    ug[e] = packhl(Uf[e]);
    wgo[e] = packhl(Wf[e]);
  }
}

// ---------------- A = I - a U^T K, B = W^T K ----------------
__global__ __launch_bounds__(512) void ab_compute(const uint32_t* __restrict__ Ug,
                                                  const uint32_t* __restrict__ Wg,
                                                  const float* __restrict__ kb,
                                                  const float* __restrict__ ar,
                                                  float* __restrict__ Aop,
                                                  float* __restrict__ Bop) {
  int n = blockIdx.x, h = (n >> 4) & 15;
  float a = sgm(ar[h]) * 0.5f;
  int t = threadIdx.x, wid = t >> 6, lane = t & 63;
  int fr = lane & 15, fk = (lane >> 4) * 8;
  __shared__ __bf16 KTh[8192], KTl[8192];  // [64][128] (d-major) swizzled
  __shared__ __bf16 UTh[8192], UTl[8192];
  __shared__ __bf16 WTh[8192], WTl[8192];
  const float* kg = kb + (size_t)n * 8192;
  const uint32_t* ug = Ug + (size_t)n * 8192;
  const uint32_t* wg = Wg + (size_t)n * 8192;
#pragma unroll
  for (int it = 0; it < 4; ++it) {
    int u = it * 512 + t;
    int tr = u >> 4, d0 = (u & 15) * 4;
    float4 kv = ((const float4*)kg)[u];
    uint4 uu = ((const uint4*)ug)[u];
    uint4 ww = ((const uint4*)wg)[u];
    float kk[4] = {kv.x, kv.y, kv.z, kv.w};
    uint32_t ua[4] = {uu.x, uu.y, uu.z, uu.w};
    uint32_t wa[4] = {ww.x, ww.y, ww.z, ww.w};
#pragma unroll
    for (int e = 0; e < 4; ++e) {
      sthl(KTh, KTl, d0 + e, tr, 128, kk[e]);
      stpk(UTh, UTl, d0 + e, tr, 128, ua[e]);
      stpk(WTh, WTl, d0 + e, tr, 128, wa[e]);
    }
  }
  __syncthreads();
#pragma unroll
  for (int q = 0; q < 4; ++q) {
    int tile = wid + q * 8;  // 0..31: 0-15 -> A, 16-31 -> B
    int mat = tile >> 4;
    int ti = (tile >> 2) & 3, tj = tile & 3;
    const __bf16* Ah = mat ? WTh : UTh;
    const __bf16* Al = mat ? WTl : UTl;
    f32x4 acc = {0.f, 0.f, 0.f, 0.f};
#pragma unroll
    for (int ks = 0; ks < 4; ++ks) {
      bf16x8 ah = ldfrag(Ah, ti * 16 + fr, ks * 32 + fk, 128);
      bf16x8 al = ldfrag(Al, ti * 16 + fr, ks * 32 + fk, 128);
      bf16x8 bh = ldfrag(KTh, tj * 16 + fr, ks * 32 + fk, 128);
      bf16x8 bl = ldfrag(KTl, tj * 16 + fr, ks * 32 + fk, 128);
      acc = mm3(ah, al, bh, bl, acc);
    }
    float* dst = (mat ? Bop : Aop) + (size_t)n * 4096;
    int row0 = (lane >> 4) * 4, col = lane & 15;
#pragma unroll
    for (int rg = 0; rg < 4; ++rg) {
      int i = ti * 16 + row0 + rg, j = tj * 16 + col;
      float v = mat ? acc[rg] : ((i == j ? 1.f : 0.f) - a * acc[rg]);
      dst[i * 64 + j] = v;
    }
  }
}

// ---------------- inter-chunk scan (unchanged) ----------------
__global__ __launch_bounds__(256) void chunk_scan(const float* __restrict__ Aop,
                                                  const float* __restrict__ Bop,
                                                  float* __restrict__ Mstart,
                                                  float* __restrict__ Mfinal) {
  int bh = blockIdx.x;
  int t = threadIdx.x, i = t >> 2, qd = t & 3;
  float M[16] __attribute__((aligned(16)));
#pragma unroll
  for (int j = 0; j < 16; ++j) M[j] = 0.f;
  __shared__ float As[4096];
  for (int c = 0; c < 16; ++c) {
    size_t cb = ((size_t)bh * 16 + c) * 4096;
#pragma unroll
    for (int u = 0; u < 4; ++u)
      *(float4*)(Mstart + cb + i * 64 + qd * 16 + u * 4) = *(const float4*)(&M[u * 4]);
    __syncthreads();
    for (int u = t; u < 1024; u += 256)
      ((float4*)As)[u] = ((const float4*)(Aop + cb))[u];
    __syncthreads();
    float acc[16] __attribute__((aligned(16)));
#pragma unroll
    for (int j = 0; j < 16; ++j) acc[j] = 0.f;
#pragma unroll
    for (int l = 0; l < 64; ++l) {
      float mil = __shfl(M[l & 15], ((t >> 2) & 15) * 4 + (l >> 4), 64);
      const float* arow = As + l * 64 + qd * 16;
#pragma unroll
      for (int j = 0; j < 16; ++j) acc[j] += mil * arow[j];
    }
#pragma unroll
    for (int u = 0; u < 4; ++u) {
      float4 bv = *(const float4*)(Bop + cb + i * 64 + qd * 16 + u * 4);
      acc[u * 4 + 0] += bv.x; acc[u * 4 + 1] += bv.y;
      acc[u * 4 + 2] += bv.z; acc[u * 4 + 3] += bv.w;
    }
#pragma unroll
    for (int j = 0; j < 16; ++j) M[j] = acc[j];
  }
#pragma unroll
  for (int u = 0; u < 4; ++u)
    *(float4*)(Mfinal + (size_t)bh * 4096 + i * 64 + qd * 16 + u * 4) =
        *(const float4*)(&M[u * 4]);
}

// ---------------- Y assembly ----------------
// Y = Q M0^T + tril(QK^T,-1) (W - a U M0^T); y -> bf16 [B*T,C]
__global__ __launch_bounds__(512) void y_assemble(const float* __restrict__ qb,
                                                  const float* __restrict__ kb,
                                                  const uint32_t* __restrict__ Ug,
                                                  const uint32_t* __restrict__ Wg,
                                                  const float* __restrict__ Mst,
                                                  const float* __restrict__ ar,
                                                  __bf16* __restrict__ ybf) {
  int n = blockIdx.x, h = (n >> 4) & 15, b = n >> 8, c = n & 15;
  float a = sgm(ar[h]) * 0.5f;
  int t = threadIdx.x, wid = t >> 6, lane = t & 63;
  int fr = lane & 15, fk = (lane >> 4) * 8;
  __shared__ __bf16 Qh[8192], Ql[8192];      // [128][64] swz
  __shared__ __bf16 Rh[8192], Rl[8192];      // [128][64] swz: K then U
  __shared__ __bf16 M0h[4096], M0l[4096];    // [64][64] swz
  __shared__ __bf16 Gh[10240], Gl[10240];    // 40 packed 16x16 tiles (padded rows)
  __shared__ __bf16 WtTh[8192], WtTl[8192];  // [64][128] swz
  const float* qg = qb + (size_t)n * 8192;
  const float* kg = kb + (size_t)n * 8192;
  const float* mg = Mst + (size_t)n * 4096;
  // P0: stage Q, K, M0; zero G pad tiles
#pragma unroll
  for (int it = 0; it < 4; ++it) {
    int u = it * 512 + t;
    int row = u >> 4, c4 = (u & 15) * 4;
    sthl4(Qh, Ql, row, c4, 64, ((const float4*)qg)[u]);
    sthl4(Rh, Rl, row, c4, 64, ((const float4*)kg)[u]);
  }
#pragma unroll
  for (int it = 0; it < 2; ++it) {
    int u = it * 512 + t;
    int row = u >> 4, c4 = (u & 15) * 4;
    sthl4(M0h, M0l, row, c4, 64, ((const float4*)mg)[u]);
  }
#pragma unroll
  for (int pz = 0; pz < 2; ++pz) {
    int e = pz * 512 + t;            // 1024 pad halfwords
    int m = e >> 8, idx = e & 255;   // pad tile for even rows: 2m^2+4m+1
    int off = (2 * m * m + 4 * m + 1) * 256 + idx;
    Gh[off] = (__bf16)0.f;
    Gl[off] = (__bf16)0.f;
  }
  __syncthreads();
  // P1: G = tril(Q K^T, -1), packed-lower, split-stored
  for (int p = wid; p < 36; p += 8) {
    int tr = 0, pp = p;
    while (pp > tr) { pp -= (tr + 1); ++tr; }
    int sc = pp;
    f32x4 acc = {0.f, 0.f, 0.f, 0.f};
#pragma unroll
    for (int ks = 0; ks < 2; ++ks) {
      bf16x8 ah = ldfrag(Qh, tr * 16 + fr, ks * 32 + fk, 64);
      bf16x8 al = ldfrag(Ql, tr * 16 + fr, ks * 32 + fk, 64);
      bf16x8 bh = ldfrag(Rh, sc * 16 + fr, ks * 32 + fk, 64);
      bf16x8 bl = ldfrag(Rl, sc * 16 + fr, ks * 32 + fk, 64);
      acc = mm3(ah, al, bh, bl, acc);
    }
    int row0 = (lane >> 4) * 4, col = lane & 15;
    int goffv = goffn(tr);
    __bf16* gh = Gh + (goffv + sc) * 256;
    __bf16* gl = Gl + (goffv + sc) * 256;
#pragma unroll
    for (int rg = 0; rg < 4; ++rg) {
      int r = row0 + rg;
      float v = acc[rg];
      if (tr == sc && col >= r) v = 0.f;
      __bf16 hh = (__bf16)v;
      gh[r * 16 + col] = hh;
      gl[r * 16 + col] = (__bf16)(v - (float)hh);
    }
  }
  __syncthreads();
  // P2: restage R <- U
  const uint32_t* ug = Ug + (size_t)n * 8192;
  const uint32_t* wg = Wg + (size_t)n * 8192;
#pragma unroll
  for (int it = 0; it < 4; ++it) {
    int u = it * 512 + t;
    int row = u >> 4, c0 = (u & 15) * 4;
    uint4 uu = ((const uint4*)ug)[u];
    uint32_t ua[4] = {uu.x, uu.y, uu.z, uu.w};
#pragma unroll
    for (int e = 0; e < 4; ++e) stpk(Rh, Rl, row, c0 + e, 64, ua[e]);
  }
  __syncthreads();
  // P3: WtT[i][s] = W[s][i] - a*(U M0^T)[s][i]
#pragma unroll
  for (int q = 0; q < 4; ++q) {
    int tile = wid + q * 8;
    int ti = tile >> 2, tj = tile & 3;
    f32x4 acc = {0.f, 0.f, 0.f, 0.f};
#pragma unroll
    for (int ks = 0; ks < 2; ++ks) {
      bf16x8 ah = ldfrag(Rh, ti * 16 + fr, ks * 32 + fk, 64);
      bf16x8 al = ldfrag(Rl, ti * 16 + fr, ks * 32 + fk, 64);
      bf16x8 bh = ldfrag(M0h, tj * 16 + fr, ks * 32 + fk, 64);
      bf16x8 bl = ldfrag(M0l, tj * 16 + fr, ks * 32 + fk, 64);
      acc = mm3(ah, al, bh, bl, acc);
    }
    int row0 = (lane >> 4) * 4, col = lane & 15;
#pragma unroll
    for (int rg = 0; rg < 4; ++rg) {
      int s = ti * 16 + row0 + rg, i = tj * 16 + col;
      float wv = unpk(wg[s * 64 + i]);
      sthl(WtTh, WtTl, i, s, 128, wv - a * acc[rg]);
    }
  }
  __syncthreads();
  // P4: Y = Q M0^T + G Wt
  __bf16* yg = ybf + ((size_t)(b * 2048 + c * 128)) * 1024 + h * 64;
#pragma unroll
  for (int q = 0; q < 4; ++q) {
    int tile = wid + q * 8;
    int ti = tile >> 2, tj = tile & 3;
    f32x4 acc = {0.f, 0.f, 0.f, 0.f};
#pragma unroll
    for (int ks = 0; ks < 2; ++ks) {
      bf16x8 ah = ldfrag(Qh, ti * 16 + fr, ks * 32 + fk, 64);
      bf16x8 al = ldfrag(Ql, ti * 16 + fr, ks * 32 + fk, 64);
      bf16x8 bh = ldfrag(M0h, tj * 16 + fr, ks * 32 + fk, 64);
      bf16x8 bl = ldfrag(M0l, tj * 16 + fr, ks * 32 + fk, 64);
      acc = mm3(ah, al, bh, bl, acc);
    }
    int goffv = goffn(ti);
    int np = (ti + 2) >> 1;
    for (int ks = 0; ks < np; ++ks) {
      int gtile = goffv + ks * 2 + (fk >> 4);
      const __bf16* gh = Gh + gtile * 256 + fr * 16 + (fk & 15);
      const __bf16* gl = Gl + gtile * 256 + fr * 16 + (fk & 15);
      bf16x8 ah = *(const bf16x8*)gh;
      bf16x8 al = *(const bf16x8*)gl;
      bf16x8 bh = ldfrag(WtTh, tj * 16 + fr, ks * 32 + fk, 128);
      bf16x8 bl = ldfrag(WtTl, tj * 16 + fr, ks * 32 + fk, 128);
      acc = mm3(ah, al, bh, bl, acc);
    }
    int row0 = (lane >> 4) * 4, col = lane & 15;
#pragma unroll
    for (int rg = 0; rg < 4; ++rg) {
      int tt = ti * 16 + row0 + rg, d = tj * 16 + col;
      yg[(size_t)tt * 1024 + d] = (__bf16)acc[rg];
    }
  }
}

extern "C" void kernel_launch(void* const* d_in, const int* in_sizes, int n_in,
                              void* d_out, int out_size, void* d_ws, size_t ws_size,
                              hipStream_t stream) {
  const float* x  = (const float*)d_in[0];
  const float* Wq = (const float*)d_in[1];
  const float* Wk = (const float*)d_in[2];
  const float* Wv = (const float*)d_in[3];
  const float* Wo = (const float*)d_in[4];
  const float* ar = (const float*)d_in[5];
  const float* br = (const float*)d_in[6];

  char* ws = (char*)d_ws;
  // region [0,16M): xb (cast input) -> Aop (ab->scan) -> ybf (yasm->final gemm)
  __bf16* xb  = (__bf16*)ws;
  float*  Aop = (float*)ws;
  __bf16* ybf = (__bf16*)ws;
  __bf16* wqt = (__bf16*)(ws + (16u << 20));
  __bf16* wkt = wqt + (1u << 20);
  __bf16* wvt = wkt + (1u << 20);
  __bf16* wot = wvt + (1u << 20);
  float* qb = (float*)(ws + (24u << 20));
  float* kb = (float*)(ws + (56u << 20));
  float* vb = (float*)(ws + (88u << 20));
  uint32_t* Wg = (uint32_t*)vb;  // per-block in-place reuse of vb
  float* Mst = (float*)(ws + (120u << 20));
  uint32_t* Ug = (uint32_t*)(ws + (136u << 20));  // ..168M

  float* yout = (float*)d_out;            // [8192,1024] f32
  float* Bop  = yout;                     // scratch in d_out (overwritten by final gemm)
  float* Mfin = yout + 8388608;

  cast_f32_bf16<<<8192, 256, 0, stream>>>(x, xb);
  dim3 tg(32, 32);
  transpose_cast<<<tg, 256, 0, stream>>>(Wq, wqt);
  transpose_cast<<<tg, 256, 0, stream>>>(Wk, wkt);
  transpose_cast<<<tg, 256, 0, stream>>>(Wv, wvt);
  transpose_cast<<<tg, 256, 0, stream>>>(Wo, wot);

  dim3 gg(8, 64);
  gemm_bt<<<gg, 256, 0, stream>>>(xb, wqt, qb, 1);
  gemm_bt<<<gg, 256, 0, stream>>>(xb, wkt, kb, 1);
  gemm_bt<<<gg, 256, 0, stream>>>(xb, wvt, vb, 1);

  wy_solve<<<1024, 512, 0, stream>>>(kb, vb, ar, br, Ug, Wg);
  ab_compute<<<1024, 512, 0, stream>>>(Ug, Wg, kb, ar, Aop, Bop);
  chunk_scan<<<64, 256, 0, stream>>>(Aop, Bop, Mst, Mfin);
  y_assemble<<<1024, 512, 0, stream>>>(qb, kb, Ug, Wg, Mst, ar, ybf);

  gemm_bt<<<gg, 256, 0, stream>>>(ybf, wot, yout, 0);
}

// Round 6
// 449.459 us; speedup vs baseline: 1.1287x; 1.1287x over previous
//
#include <hip/hip_runtime.h>
#include <stdint.h>

// Titans-L2 chunked delta-rule forward — WY reformulation, plain-bf16 edition.
//   1. cast x -> bf16; transpose+cast Wq/Wk/Wv/Wo -> bf16 [N,K]
//   2. MFMA GEMMs: q,k,v = x@W  (written DIRECTLY as bf16 [B,H,T,D])
//   3. wy_ab (per chunk, fused): normalize k (LDS); S = a*tril(KK^T,-1) (MFMA,
//      fp32 LDS); blocked forward substitution (I+S)U=K, (I+S)W=b*V (fp32);
//      transpose U,W in-LDS (overlay Sa) + store bf16 U,W to global;
//      A = I - a*U^T K, B = W^T K via MFMA -> fp32 Aop/Bop.
//   4. chunk_scan: M_{c+1} = M_c A_c + B_c; emits Mstart + M_final(out)
//   5. y_assemble (plain bf16): G = tril(QK^T,-1); Wt = W - a*(U M0^T);
//      Y = Q M0^T + G Wt; writes y as bf16 [B*T, C]
//   6. final MFMA GEMM y@Wo -> d_out (fp32)
// Dims: B=4 H=16 T=2048 C=1024 D=64 CS=128 nc=16 N=1024 tokens=8192

#define DEV __device__ __forceinline__

typedef __attribute__((ext_vector_type(4))) float f32x4;
typedef __attribute__((ext_vector_type(8))) __bf16 bf16x8;
typedef __attribute__((ext_vector_type(4))) __bf16 bf16x4;

typedef const __attribute__((address_space(1))) uint32_t* gas1_t;
typedef __attribute__((address_space(3))) uint32_t* las3_t;

DEV void gload_lds16(const void* g, void* l) {
  __builtin_amdgcn_global_load_lds((gas1_t)g, (las3_t)l, 16, 0, 0);
}

DEV float sgm(float x) { return 1.f / (1.f + __expf(-x)); }

template <int CTRL>
DEV float dpp_mov(float x) {
  return __builtin_bit_cast(
      float, __builtin_amdgcn_mov_dpp(__builtin_bit_cast(int, x), CTRL, 0xF, 0xF, true));
}
// cyclic rotate-reduce: sum over each 16-lane DPP row
DEV float row16_reduce(float x) {
  x += dpp_mov<0x121>(x);  // row_ror:1
  x += dpp_mov<0x122>(x);  // row_ror:2
  x += dpp_mov<0x124>(x);  // row_ror:4
  x += dpp_mov<0x128>(x);  // row_ror:8
  return x;
}

// ---- swizzled LDS helpers (row-major bf16 tiles; XOR bank swizzle) ----
DEV int swzb(int row, int col, int stride) {  // byte offset
  return ((row * stride + col) << 1) ^ ((row & 7) << 4);
}
DEV bf16x8 ldfrag(const __bf16* B, int row, int col, int stride) {
  return *(const bf16x8*)((const char*)B + swzb(row, col, stride));
}
DEV void stb(__bf16* B, int row, int col, int stride, __bf16 v) {
  *(__bf16*)((char*)B + swzb(row, col, stride)) = v;
}
DEV void stb4(__bf16* B, int row, int c4, int stride, bf16x4 v) {
  *(bf16x4*)((char*)B + swzb(row, c4, stride)) = v;
}
// packed-lower tile offsets: row tr holds tiles 0..tr (+1 zero pad for even tr)
DEV int goffn(int tr) {
  int m = tr >> 1;
  return (tr & 1) ? (2 * m * m + 4 * m + 2) : (2 * m * m + 2 * m);
}
DEV int stile(int tr, int sc) { return ((tr * (tr + 1)) / 2 + sc) * 256; }

// ---------------- casts ----------------
__global__ __launch_bounds__(256) void cast_f32_bf16(const float* __restrict__ in,
                                                     __bf16* __restrict__ out) {
  int idx = blockIdx.x * 256 + threadIdx.x;
  float4 v = ((const float4*)in)[idx];
  bf16x4 o;
  o[0] = (__bf16)v.x; o[1] = (__bf16)v.y; o[2] = (__bf16)v.z; o[3] = (__bf16)v.w;
  ((bf16x4*)out)[idx] = o;
}

__global__ __launch_bounds__(256) void transpose_cast(const float* __restrict__ W,
                                                      __bf16* __restrict__ Wt) {
  __shared__ float tile[32][33];
  int tx = threadIdx.x & 31, ty = threadIdx.x >> 5;
  int n0 = blockIdx.x * 32, k0 = blockIdx.y * 32;
#pragma unroll
  for (int u = 0; u < 4; ++u)
    tile[ty + u * 8][tx] = W[(size_t)(k0 + ty + u * 8) * 1024 + n0 + tx];
  __syncthreads();
#pragma unroll
  for (int u = 0; u < 4; ++u)
    Wt[(size_t)(n0 + ty + u * 8) * 1024 + k0 + tx] = (__bf16)tile[tx][ty + u * 8];
}

// ---------------- GEMM: C[M=8192,N=1024] = A[M,K=1024] * Bt[N,K]^T ----------------
// mode 0: fp32 C row-major [M,1024]. mode 1: bf16 scatter to [B,H,T,D]
__global__ __launch_bounds__(256) void gemm_bt(const __bf16* __restrict__ A,
                                               const __bf16* __restrict__ Bt,
                                               float* __restrict__ Cf,
                                               __bf16* __restrict__ Cb, int mode) {
  const int t = threadIdx.x;
  const int wv = t >> 6, lane = t & 63;
  const int bm = blockIdx.y, bn = blockIdx.x;
  const int K = 1024;
  __shared__ __bf16 lA[4096];
  __shared__ __bf16 lB[4096];
  f32x4 acc[4][4];
#pragma unroll
  for (int m = 0; m < 4; ++m)
#pragma unroll
    for (int n = 0; n < 4; ++n) acc[m][n] = 0.f;
  const int wr = wv >> 1, wc = wv & 1;
  const int fr = lane & 15, fk = (lane >> 4) * 8;
  const int e0 = (wv * 128 + lane) * 8;
  const int e1 = (wv * 128 + 64 + lane) * 8;
  const int r0s = e0 >> 5, c0s = e0 & 31;
  const int r1s = e1 >> 5, c1s = e1 & 31;
  for (int k0 = 0; k0 < K; k0 += 32) {
    gload_lds16(A + (size_t)(bm * 128 + r0s) * K + k0 + c0s, lA + wv * 1024);
    gload_lds16(Bt + (size_t)(bn * 128 + r0s) * K + k0 + c0s, lB + wv * 1024);
    gload_lds16(A + (size_t)(bm * 128 + r1s) * K + k0 + c1s, lA + wv * 1024 + 512);
    gload_lds16(Bt + (size_t)(bn * 128 + r1s) * K + k0 + c1s, lB + wv * 1024 + 512);
    __syncthreads();
    bf16x8 af[4], bg[4];
#pragma unroll
    for (int m = 0; m < 4; ++m)
      af[m] = *(const bf16x8*)(lA + (wr * 64 + m * 16 + fr) * 32 + fk);
#pragma unroll
    for (int n = 0; n < 4; ++n)
      bg[n] = *(const bf16x8*)(lB + (wc * 64 + n * 16 + fr) * 32 + fk);
#pragma unroll
    for (int m = 0; m < 4; ++m)
#pragma unroll
      for (int n = 0; n < 4; ++n)
        acc[m][n] = __builtin_amdgcn_mfma_f32_16x16x32_bf16(af[m], bg[n], acc[m][n], 0, 0, 0);
    __syncthreads();
  }
  const int rr = (lane >> 4) * 4, cl = lane & 15;
#pragma unroll
  for (int m = 0; m < 4; ++m) {
#pragma unroll
    for (int n = 0; n < 4; ++n) {
#pragma unroll
      for (int rg = 0; rg < 4; ++rg) {
        int row = bm * 128 + wr * 64 + m * 16 + rr + rg;
        int col = bn * 128 + wc * 64 + n * 16 + cl;
        float val = acc[m][n][rg];
        if (mode == 0) {
          Cf[(size_t)row * 1024 + col] = val;
        } else {
          int b = row >> 11, tk = row & 2047;
          int h = col >> 6, d = col & 63;
          Cb[(((size_t)b * 16 + h) * 2048 + tk) * 64 + d] = (__bf16)val;
        }
      }
    }
  }
}

// ---------------- fused WY solve + A/B ----------------
// LDS: Ks[128][64] + KT[64][128] bf16 (16KB ea), Sa 36KB fp32 (overlaid by
// UT/WT bf16 after substitution), Uf/Wf [128][64] fp32 (32KB ea) = 132KB.
__global__ __launch_bounds__(512) void wy_ab(const __bf16* __restrict__ kb,
                                             const __bf16* __restrict__ vb,
                                             const float* __restrict__ ar,
                                             const float* __restrict__ br,
                                             __bf16* __restrict__ Ug,
                                             __bf16* __restrict__ Wgb,
                                             float* __restrict__ Aop,
                                             float* __restrict__ Bop) {
  int n = blockIdx.x, h = (n >> 4) & 15;
  float a = sgm(ar[h]) * 0.5f;
  float b = sgm(br[h]) * 0.5f;
  int t = threadIdx.x, wid = t >> 6, lane = t & 63;
  int fr = lane & 15, fk = (lane >> 4) * 8;
  __shared__ __bf16 Ks[8192];
  __shared__ __bf16 KT[8192];
  __shared__ float Sa[9216];
  __shared__ float Uf[8192];
  __shared__ float Wf[8192];
  __bf16* UT = (__bf16*)Sa;  // overlay: [64][128] swz, after substitution
  __bf16* WT = UT + 8192;
  const __bf16* kg = kb + (size_t)n * 8192;
  const __bf16* vg = vb + (size_t)n * 8192;
  // stage + normalize k; init U = k_norm, W = b*v
#pragma unroll
  for (int it = 0; it < 4; ++it) {
    int u = it * 512 + t;
    int row = u >> 4, c4 = (u & 15) * 4;
    bf16x4 kh = ((const bf16x4*)kg)[u];
    float kf[4];
#pragma unroll
    for (int e = 0; e < 4; ++e) kf[e] = (float)kh[e];
    float ssq = kf[0] * kf[0] + kf[1] * kf[1] + kf[2] * kf[2] + kf[3] * kf[3];
    ssq = row16_reduce(ssq);
    float inv = 1.f / fmaxf(sqrtf(ssq), 1e-12f);
    bf16x4 kn;
#pragma unroll
    for (int e = 0; e < 4; ++e) kn[e] = (__bf16)(kf[e] * inv);
    stb4(Ks, row, c4, 64, kn);
#pragma unroll
    for (int e = 0; e < 4; ++e) {
      stb(KT, c4 + e, row, 128, kn[e]);
      Uf[row * 64 + c4 + e] = (float)kn[e];
    }
    bf16x4 vh = ((const bf16x4*)vg)[u];
#pragma unroll
    for (int e = 0; e < 4; ++e) Wf[row * 64 + c4 + e] = b * (float)vh[e];
  }
  __syncthreads();
  // S = a*tril(KK^T) packed-lower tiles (strict-lower masked), fp32
  for (int p = wid; p < 36; p += 8) {
    int tr = 0, pp = p;
    while (pp > tr) { pp -= (tr + 1); ++tr; }
    int sc = pp;
    f32x4 acc = {0.f, 0.f, 0.f, 0.f};
#pragma unroll
    for (int ks = 0; ks < 2; ++ks)
      acc = __builtin_amdgcn_mfma_f32_16x16x32_bf16(
          ldfrag(Ks, tr * 16 + fr, ks * 32 + fk, 64),
          ldfrag(Ks, sc * 16 + fr, ks * 32 + fk, 64), acc, 0, 0, 0);
    float* dst = Sa + stile(tr, sc);
    int row0 = (lane >> 4) * 4, col = lane & 15;
#pragma unroll
    for (int rg = 0; rg < 4; ++rg) {
      int r = row0 + rg;
      float v = a * acc[rg];
      if (tr == sc && col >= r) v = 0.f;
      dst[r * 16 + col] = v;
    }
  }
  __syncthreads();
  // blocked forward substitution (fp32)
  for (int bb = 0; bb < 8; ++bb) {
    if (bb) {
#pragma unroll
      for (int p = 0; p < 4; ++p) {
        int g = p * 8 + wid;
        int tt = g & 15, mat = g >> 4;
        float* M = mat ? Wf : Uf;
        int trow = bb * 16 + tt;
        float acc = 0.f;
        for (int s = 0; s < bb * 16; ++s)
          acc += Sa[stile(bb, s >> 4) + tt * 16 + (s & 15)] * M[s * 64 + lane];
        M[trow * 64 + lane] -= acc;
      }
      __syncthreads();
    }
    if (wid < 2) {
      float* M = wid ? Wf : Uf;
      const float* Sd = Sa + stile(bb, bb);
      float r[16];
#pragma unroll
      for (int j = 0; j < 16; ++j) r[j] = M[(bb * 16 + j) * 64 + lane];
#pragma unroll
      for (int tt = 1; tt < 16; ++tt) {
        float acc = 0.f;
#pragma unroll
        for (int s = 0; s < tt; ++s) acc += Sd[tt * 16 + s] * r[s];
        r[tt] -= acc;
      }
#pragma unroll
      for (int j = 0; j < 16; ++j) M[(bb * 16 + j) * 64 + lane] = r[j];
    }
    __syncthreads();
  }
  // transpose U,W -> UT/WT (overlay Sa) + global bf16 writeout
  __bf16* ug = Ug + (size_t)n * 8192;
  __bf16* wg = Wgb + (size_t)n * 8192;
#pragma unroll
  for (int it = 0; it < 16; ++it) {
    int e = it * 512 + t;
    int row = e >> 6, col = e & 63;
    __bf16 ub = (__bf16)Uf[row * 64 + col];
    __bf16 wb = (__bf16)Wf[row * 64 + col];
    ug[e] = ub;
    wg[e] = wb;
    stb(UT, col, row, 128, ub);
    stb(WT, col, row, 128, wb);
  }
  __syncthreads();
  // A = I - a U^T K, B = W^T K
#pragma unroll
  for (int q = 0; q < 4; ++q) {
    int tile = wid + q * 8;  // 0-15 -> A, 16-31 -> B
    int mat = tile >> 4;
    int ti = (tile >> 2) & 3, tj = tile & 3;
    const __bf16* Ah = mat ? WT : UT;
    f32x4 acc = {0.f, 0.f, 0.f, 0.f};
#pragma unroll
    for (int ks = 0; ks < 4; ++ks)
      acc = __builtin_amdgcn_mfma_f32_16x16x32_bf16(
          ldfrag(Ah, ti * 16 + fr, ks * 32 + fk, 128),
          ldfrag(KT, tj * 16 + fr, ks * 32 + fk, 128), acc, 0, 0, 0);
    float* dst = (mat ? Bop : Aop) + (size_t)n * 4096;
    int row0 = (lane >> 4) * 4, col = lane & 15;
#pragma unroll
    for (int rg = 0; rg < 4; ++rg) {
      int i = ti * 16 + row0 + rg, j = tj * 16 + col;
      float v = mat ? acc[rg] : ((i == j ? 1.f : 0.f) - a * acc[rg]);
      dst[i * 64 + j] = v;
    }
  }
}

// ---------------- inter-chunk scan (unchanged) ----------------
__global__ __launch_bounds__(256) void chunk_scan(const float* __restrict__ Aop,
                                                  const float* __restrict__ Bop,
                                                  float* __restrict__ Mstart,
                                                  float* __restrict__ Mfinal) {
  int bh = blockIdx.x;
  int t = threadIdx.x, i = t >> 2, qd = t & 3;
  float M[16] __attribute__((aligned(16)));
#pragma unroll
  for (int j = 0; j < 16; ++j) M[j] = 0.f;
  __shared__ float As[4096];
  for (int c = 0; c < 16; ++c) {
    size_t cb = ((size_t)bh * 16 + c) * 4096;
#pragma unroll
    for (int u = 0; u < 4; ++u)
      *(float4*)(Mstart + cb + i * 64 + qd * 16 + u * 4) = *(const float4*)(&M[u * 4]);
    __syncthreads();
    for (int u = t; u < 1024; u += 256)
      ((float4*)As)[u] = ((const float4*)(Aop + cb))[u];
    __syncthreads();
    float acc[16] __attribute__((aligned(16)));
#pragma unroll
    for (int j = 0; j < 16; ++j) acc[j] = 0.f;
#pragma unroll
    for (int l = 0; l < 64; ++l) {
      float mil = __shfl(M[l & 15], ((t >> 2) & 15) * 4 + (l >> 4), 64);
      const float* arow = As + l * 64 + qd * 16;
#pragma unroll
      for (int j = 0; j < 16; ++j) acc[j] += mil * arow[j];
    }
#pragma unroll
    for (int u = 0; u < 4; ++u) {
      float4 bv = *(const float4*)(Bop + cb + i * 64 + qd * 16 + u * 4);
      acc[u * 4 + 0] += bv.x; acc[u * 4 + 1] += bv.y;
      acc[u * 4 + 2] += bv.z; acc[u * 4 + 3] += bv.w;
    }
#pragma unroll
    for (int j = 0; j < 16; ++j) M[j] = acc[j];
  }
#pragma unroll
  for (int u = 0; u < 4; ++u)
    *(float4*)(Mfinal + (size_t)bh * 4096 + i * 64 + qd * 16 + u * 4) =
        *(const float4*)(&M[u * 4]);
}

// ---------------- Y assembly (plain bf16) ----------------
// Y = Q M0^T + tril(QK^T,-1)(W - a U M0^T); y -> bf16 [B*T,C]. LDS 76KB.
__global__ __launch_bounds__(512, 4) void y_assemble(const __bf16* __restrict__ qb,
                                                     const __bf16* __restrict__ kb,
                                                     const __bf16* __restrict__ Ug,
                                                     const __bf16* __restrict__ Wgb,
                                                     const float* __restrict__ Mst,
                                                     const float* __restrict__ ar,
                                                     __bf16* __restrict__ ybf) {
  int n = blockIdx.x, h = (n >> 4) & 15, b = n >> 8, c = n & 15;
  float a = sgm(ar[h]) * 0.5f;
  int t = threadIdx.x, wid = t >> 6, lane = t & 63;
  int fr = lane & 15, fk = (lane >> 4) * 8;
  __shared__ __bf16 Qs[8192];    // [128][64] swz
  __shared__ __bf16 Rs[8192];    // [128][64] swz: K then U
  __shared__ __bf16 M0s[4096];   // [64][64] swz
  __shared__ __bf16 Gs[10240];   // 40 packed 16x16 tiles
  __shared__ __bf16 WtT[8192];   // [64][128] swz
  const __bf16* qg = qb + (size_t)n * 8192;
  const __bf16* kg = kb + (size_t)n * 8192;
  const float* mg = Mst + (size_t)n * 4096;
  // P0: stage Q (copy), K (normalize), M0 (cast); zero G pad tiles
#pragma unroll
  for (int it = 0; it < 4; ++it) {
    int u = it * 512 + t;
    int row = u >> 4, c4 = (u & 15) * 4;
    stb4(Qs, row, c4, 64, ((const bf16x4*)qg)[u]);
    bf16x4 kh = ((const bf16x4*)kg)[u];
    float kf[4];
#pragma unroll
    for (int e = 0; e < 4; ++e) kf[e] = (float)kh[e];
    float ssq = kf[0] * kf[0] + kf[1] * kf[1] + kf[2] * kf[2] + kf[3] * kf[3];
    ssq = row16_reduce(ssq);
    float inv = 1.f / fmaxf(sqrtf(ssq), 1e-12f);
    bf16x4 kn;
#pragma unroll
    for (int e = 0; e < 4; ++e) kn[e] = (__bf16)(kf[e] * inv);
    stb4(Rs, row, c4, 64, kn);
  }
#pragma unroll
  for (int it = 0; it < 2; ++it) {
    int u = it * 512 + t;
    int row = u >> 4, c4 = (u & 15) * 4;
    float4 mv = ((const float4*)mg)[u];
    bf16x4 mb;
    mb[0] = (__bf16)mv.x; mb[1] = (__bf16)mv.y;
    mb[2] = (__bf16)mv.z; mb[3] = (__bf16)mv.w;
    stb4(M0s, row, c4, 64, mb);
  }
#pragma unroll
  for (int pz = 0; pz < 2; ++pz) {
    int e = pz * 512 + t;
    int m = e >> 8, idx = e & 255;
    Gs[(2 * m * m + 4 * m + 1) * 256 + idx] = (__bf16)0.f;
  }
  __syncthreads();
  // P1: G = tril(Q K^T, -1), packed-lower bf16
  for (int p = wid; p < 36; p += 8) {
    int tr = 0, pp = p;
    while (pp > tr) { pp -= (tr + 1); ++tr; }
    int sc = pp;
    f32x4 acc = {0.f, 0.f, 0.f, 0.f};
#pragma unroll
    for (int ks = 0; ks < 2; ++ks)
      acc = __builtin_amdgcn_mfma_f32_16x16x32_bf16(
          ldfrag(Qs, tr * 16 + fr, ks * 32 + fk, 64),
          ldfrag(Rs, sc * 16 + fr, ks * 32 + fk, 64), acc, 0, 0, 0);
    int row0 = (lane >> 4) * 4, col = lane & 15;
    __bf16* gt = Gs + (goffn(tr) + sc) * 256;
#pragma unroll
    for (int rg = 0; rg < 4; ++rg) {
      int r = row0 + rg;
      float v = acc[rg];
      if (tr == sc && col >= r) v = 0.f;
      gt[r * 16 + col] = (__bf16)v;
    }
  }
  __syncthreads();
  // P2: restage Rs <- U
  const __bf16* ug = Ug + (size_t)n * 8192;
  const __bf16* wg = Wgb + (size_t)n * 8192;
#pragma unroll
  for (int it = 0; it < 4; ++it) {
    int u = it * 512 + t;
    int row = u >> 4, c4 = (u & 15) * 4;
    stb4(Rs, row, c4, 64, ((const bf16x4*)ug)[u]);
  }
  __syncthreads();
  // P3: WtT[i][s] = W[s][i] - a*(U M0^T)[s][i]
#pragma unroll
  for (int q = 0; q < 4; ++q) {
    int tile = wid + q * 8;
    int ti = tile >> 2, tj = tile & 3;
    f32x4 acc = {0.f, 0.f, 0.f, 0.f};
#pragma unroll
    for (int ks = 0; ks < 2; ++ks)
      acc = __builtin_amdgcn_mfma_f32_16x16x32_bf16(
          ldfrag(Rs, ti * 16 + fr, ks * 32 + fk, 64),
          ldfrag(M0s, tj * 16 + fr, ks * 32 + fk, 64), acc, 0, 0, 0);
    int row0 = (lane >> 4) * 4, col = lane & 15;
#pragma unroll
    for (int rg = 0; rg < 4; ++rg) {
      int s = ti * 16 + row0 + rg, i = tj * 16 + col;
      float wv = (float)wg[s * 64 + i];
      stb(WtT, i, s, 128, (__bf16)(wv - a * acc[rg]));
    }
  }
  __syncthreads();
  // P4: Y = Q M0^T + G Wt
  __bf16* yg = ybf + ((size_t)(b * 2048 + c * 128)) * 1024 + h * 64;
#pragma unroll
  for (int q = 0; q < 4; ++q) {
    int tile = wid + q * 8;
    int ti = tile >> 2, tj = tile & 3;
    f32x4 acc = {0.f, 0.f, 0.f, 0.f};
#pragma unroll
    for (int ks = 0; ks < 2; ++ks)
      acc = __builtin_amdgcn_mfma_f32_16x16x32_bf16(
          ldfrag(Qs, ti * 16 + fr, ks * 32 + fk, 64),
          ldfrag(M0s, tj * 16 + fr, ks * 32 + fk, 64), acc, 0, 0, 0);
    int goffv = goffn(ti);
    int np = (ti + 2) >> 1;
    for (int ks = 0; ks < np; ++ks) {
      int gtile = goffv + ks * 2 + (fk >> 4);
      bf16x8 af = *(const bf16x8*)(Gs + gtile * 256 + fr * 16 + (fk & 15));
      acc = __builtin_amdgcn_mfma_f32_16x16x32_bf16(
          af, ldfrag(WtT, tj * 16 + fr, ks * 32 + fk, 128), acc, 0, 0, 0);
    }
    int row0 = (lane >> 4) * 4, col = lane & 15;
#pragma unroll
    for (int rg = 0; rg < 4; ++rg) {
      int tt = ti * 16 + row0 + rg, d = tj * 16 + col;
      yg[(size_t)tt * 1024 + d] = (__bf16)acc[rg];
    }
  }
}

extern "C" void kernel_launch(void* const* d_in, const int* in_sizes, int n_in,
                              void* d_out, int out_size, void* d_ws, size_t ws_size,
                              hipStream_t stream) {
  const float* x  = (const float*)d_in[0];
  const float* Wq = (const float*)d_in[1];
  const float* Wk = (const float*)d_in[2];
  const float* Wv = (const float*)d_in[3];
  const float* Wo = (const float*)d_in[4];
  const float* ar = (const float*)d_in[5];
  const float* br = (const float*)d_in[6];

  char* ws = (char*)d_ws;
  __bf16* xb  = (__bf16*)ws;                       // 16.8 MB, reused as ybf
  __bf16* ybf = xb;
  __bf16* wqt = (__bf16*)(ws + (17u << 20));       // 2 MB each
  __bf16* wkt = wqt + (1u << 20);
  __bf16* wvt = wkt + (1u << 20);
  __bf16* wot = wvt + (1u << 20);
  __bf16* qb  = (__bf16*)(ws + (25u << 20));       // 16.8 MB bf16 each
  __bf16* kb  = (__bf16*)(ws + (42u << 20));
  __bf16* vb  = (__bf16*)(ws + (59u << 20));
  __bf16* Ugb = (__bf16*)(ws + (76u << 20));
  __bf16* Wgb = (__bf16*)(ws + (93u << 20));
  float* Aop  = (float*)(ws + (110u << 20));       // 16.8 MB fp32 each
  float* Bop  = (float*)(ws + (127u << 20));
  float* Mst  = (float*)(ws + (144u << 20));       // ..161 MB

  float* yout = (float*)d_out;                     // [8192,1024] f32
  float* Mfin = yout + 8388608;

  cast_f32_bf16<<<8192, 256, 0, stream>>>(x, xb);
  dim3 tg(32, 32);
  transpose_cast<<<tg, 256, 0, stream>>>(Wq, wqt);
  transpose_cast<<<tg, 256, 0, stream>>>(Wk, wkt);
  transpose_cast<<<tg, 256, 0, stream>>>(Wv, wvt);
  transpose_cast<<<tg, 256, 0, stream>>>(Wo, wot);

  dim3 gg(8, 64);
  gemm_bt<<<gg, 256, 0, stream>>>(xb, wqt, nullptr, qb, 1);
  gemm_bt<<<gg, 256, 0, stream>>>(xb, wkt, nullptr, kb, 1);
  gemm_bt<<<gg, 256, 0, stream>>>(xb, wvt, nullptr, vb, 1);

  wy_ab<<<1024, 512, 0, stream>>>(kb, vb, ar, br, Ugb, Wgb, Aop, Bop);
  chunk_scan<<<64, 256, 0, stream>>>(Aop, Bop, Mst, Mfin);
  y_assemble<<<1024, 512, 0, stream>>>(qb, kb, Ugb, Wgb, Mst, ar, ybf);

  gemm_bt<<<gg, 256, 0, stream>>>(ybf, wot, yout, nullptr, 0);
}

// Round 8
// 319.025 us; speedup vs baseline: 1.5901x; 1.4089x over previous
//
#include <hip/hip_runtime.h>
#include <stdint.h>

// Titans-L2 chunked delta-rule forward — WY reformulation, left-looking
// register-resident solve (serial-wave stages, shfl broadcasts, MFMA off-diag).
//   1. cast x -> bf16; transpose+cast Wq/Wk/Wv/Wo -> bf16 [N,K]
//   2. MFMA GEMMs: q,k,v = x@W  (written DIRECTLY as bf16 [B,H,T,D])
//   3. wy_ab (per chunk): normalize k; S_neg = -a*tril(KK^T,-1) bf16 tiles;
//      left-looking substitution: stage w = {MFMA over prior blocks via MT,
//      15-step shfl diag solve, append rows to MT}; MT == U^T/W^T feeds
//      A = I - a*U^T K, B = W^T K MFMAs and the coalesced U/W global write.
//   4. chunk_scan: M_{c+1} = M_c A_c + B_c; emits Mstart + M_final(out)
//   5. y_assemble: G = tril(QK^T,-1); Wt = W - a*(U M0^T);
//      Y = Q M0^T + G Wt; writes y as bf16 [B*T, C]
//   6. final MFMA GEMM y@Wo -> d_out (fp32)
// Dims: B=4 H=16 T=2048 C=1024 D=64 CS=128 nc=16 N=1024 tokens=8192

#define DEV __device__ __forceinline__

typedef __attribute__((ext_vector_type(4))) float f32x4;
typedef __attribute__((ext_vector_type(8))) __bf16 bf16x8;
typedef __attribute__((ext_vector_type(4))) __bf16 bf16x4;

typedef const __attribute__((address_space(1))) uint32_t* gas1_t;
typedef __attribute__((address_space(3))) uint32_t* las3_t;

DEV void gload_lds16(const void* g, void* l) {
  __builtin_amdgcn_global_load_lds((gas1_t)g, (las3_t)l, 16, 0, 0);
}

DEV float sgm(float x) { return 1.f / (1.f + __expf(-x)); }

template <int CTRL>
DEV float dpp_mov(float x) {
  return __builtin_bit_cast(
      float, __builtin_amdgcn_mov_dpp(__builtin_bit_cast(int, x), CTRL, 0xF, 0xF, true));
}
// cyclic rotate-reduce: sum over each 16-lane DPP row
DEV float row16_reduce(float x) {
  x += dpp_mov<0x121>(x);  // row_ror:1
  x += dpp_mov<0x122>(x);  // row_ror:2
  x += dpp_mov<0x124>(x);  // row_ror:4
  x += dpp_mov<0x128>(x);  // row_ror:8
  return x;
}

// ---- swizzled LDS helpers (row-major bf16 tiles; XOR bank swizzle) ----
DEV int swzb(int row, int col, int stride) {  // byte offset
  return ((row * stride + col) << 1) ^ ((row & 7) << 4);
}
DEV bf16x8 ldfrag(const __bf16* B, int row, int col, int stride) {
  return *(const bf16x8*)((const char*)B + swzb(row, col, stride));
}
DEV __bf16 ldsc(const __bf16* B, int row, int col, int stride) {
  return *(const __bf16*)((const char*)B + swzb(row, col, stride));
}
DEV void stb(__bf16* B, int row, int col, int stride, __bf16 v) {
  *(__bf16*)((char*)B + swzb(row, col, stride)) = v;
}
DEV void stb4(__bf16* B, int row, int c4, int stride, bf16x4 v) {
  *(bf16x4*)((char*)B + swzb(row, c4, stride)) = v;
}
// packed-lower tile offsets: row tr holds tiles 0..tr (+1 zero pad for even tr)
DEV int goffn(int tr) {
  int m = tr >> 1;
  return (tr & 1) ? (2 * m * m + 4 * m + 2) : (2 * m * m + 2 * m);
}
DEV int stile(int tr, int sc) { return ((tr * (tr + 1)) / 2 + sc) * 256; }

// ---------------- casts ----------------
__global__ __launch_bounds__(256) void cast_f32_bf16(const float* __restrict__ in,
                                                     __bf16* __restrict__ out) {
  int idx = blockIdx.x * 256 + threadIdx.x;
  float4 v = ((const float4*)in)[idx];
  bf16x4 o;
  o[0] = (__bf16)v.x; o[1] = (__bf16)v.y; o[2] = (__bf16)v.z; o[3] = (__bf16)v.w;
  ((bf16x4*)out)[idx] = o;
}

__global__ __launch_bounds__(256) void transpose_cast(const float* __restrict__ W,
                                                      __bf16* __restrict__ Wt) {
  __shared__ float tile[32][33];
  int tx = threadIdx.x & 31, ty = threadIdx.x >> 5;
  int n0 = blockIdx.x * 32, k0 = blockIdx.y * 32;
#pragma unroll
  for (int u = 0; u < 4; ++u)
    tile[ty + u * 8][tx] = W[(size_t)(k0 + ty + u * 8) * 1024 + n0 + tx];
  __syncthreads();
#pragma unroll
  for (int u = 0; u < 4; ++u)
    Wt[(size_t)(n0 + ty + u * 8) * 1024 + k0 + tx] = (__bf16)tile[tx][ty + u * 8];
}

// ---------------- GEMM: C[M=8192,N=1024] = A[M,K=1024] * Bt[N,K]^T ----------------
// mode 0: fp32 C row-major [M,1024]. mode 1: bf16 scatter to [B,H,T,D]
__global__ __launch_bounds__(256) void gemm_bt(const __bf16* __restrict__ A,
                                               const __bf16* __restrict__ Bt,
                                               float* __restrict__ Cf,
                                               __bf16* __restrict__ Cb, int mode) {
  const int t = threadIdx.x;
  const int wv = t >> 6, lane = t & 63;
  const int bm = blockIdx.y, bn = blockIdx.x;
  const int K = 1024;
  __shared__ __bf16 lA[4096];
  __shared__ __bf16 lB[4096];
  f32x4 acc[4][4];
#pragma unroll
  for (int m = 0; m < 4; ++m)
#pragma unroll
    for (int n = 0; n < 4; ++n) acc[m][n] = 0.f;
  const int wr = wv >> 1, wc = wv & 1;
  const int fr = lane & 15, fk = (lane >> 4) * 8;
  const int e0 = (wv * 128 + lane) * 8;
  const int e1 = (wv * 128 + 64 + lane) * 8;
  const int r0s = e0 >> 5, c0s = e0 & 31;
  const int r1s = e1 >> 5, c1s = e1 & 31;
  for (int k0 = 0; k0 < K; k0 += 32) {
    gload_lds16(A + (size_t)(bm * 128 + r0s) * K + k0 + c0s, lA + wv * 1024);
    gload_lds16(Bt + (size_t)(bn * 128 + r0s) * K + k0 + c0s, lB + wv * 1024);
    gload_lds16(A + (size_t)(bm * 128 + r1s) * K + k0 + c1s, lA + wv * 1024 + 512);
    gload_lds16(Bt + (size_t)(bn * 128 + r1s) * K + k0 + c1s, lB + wv * 1024 + 512);
    __syncthreads();
    bf16x8 af[4], bg[4];
#pragma unroll
    for (int m = 0; m < 4; ++m)
      af[m] = *(const bf16x8*)(lA + (wr * 64 + m * 16 + fr) * 32 + fk);
#pragma unroll
    for (int n = 0; n < 4; ++n)
      bg[n] = *(const bf16x8*)(lB + (wc * 64 + n * 16 + fr) * 32 + fk);
#pragma unroll
    for (int m = 0; m < 4; ++m)
#pragma unroll
      for (int n = 0; n < 4; ++n)
        acc[m][n] = __builtin_amdgcn_mfma_f32_16x16x32_bf16(af[m], bg[n], acc[m][n], 0, 0, 0);
    __syncthreads();
  }
  const int rr = (lane >> 4) * 4, cl = lane & 15;
#pragma unroll
  for (int m = 0; m < 4; ++m) {
#pragma unroll
    for (int n = 0; n < 4; ++n) {
#pragma unroll
      for (int rg = 0; rg < 4; ++rg) {
        int row = bm * 128 + wr * 64 + m * 16 + rr + rg;
        int col = bn * 128 + wc * 64 + n * 16 + cl;
        float val = acc[m][n][rg];
        if (mode == 0) {
          Cf[(size_t)row * 1024 + col] = val;
        } else {
          int b = row >> 11, tk = row & 2047;
          int h = col >> 6, d = col & 63;
          Cb[(((size_t)b * 16 + h) * 2048 + tk) * 64 + d] = (__bf16)val;
        }
      }
    }
  }
}

// ---------------- fused WY solve + A/B (left-looking, register-resident) ----
// LDS 66 KB -> 2 blocks/CU. Wave w owns rows w*16..+15 of U,W in C/D regs.
__global__ __launch_bounds__(512, 4) void wy_ab(const __bf16* __restrict__ kb,
                                                const __bf16* __restrict__ vb,
                                                const float* __restrict__ ar,
                                                const float* __restrict__ br,
                                                __bf16* __restrict__ Ug,
                                                __bf16* __restrict__ Wgb,
                                                float* __restrict__ Aop,
                                                float* __restrict__ Bop) {
  int n = blockIdx.x, h = (n >> 4) & 15;
  float a = sgm(ar[h]) * 0.5f;
  float b = sgm(br[h]) * 0.5f;
  int t = threadIdx.x, wid = t >> 6, lane = t & 63;
  int fr = lane & 15, fkq = lane >> 4, fk = fkq * 8;
  __shared__ __attribute__((aligned(16))) char pool[67584];
  __bf16* Ks  = (__bf16*)pool;            // [128][64] swz; dead after init
  __bf16* MTu = (__bf16*)pool;            // [64][128] swz == U^T (overlays Ks)
  __bf16* KT  = (__bf16*)(pool + 16384);  // [64][128] swz
  __bf16* MTw = (__bf16*)(pool + 32768);  // [64][128] swz == W^T
  __bf16* Sng = (__bf16*)(pool + 49152);  // 36 packed-lower 16x16 bf16 tiles
  const __bf16* kg = kb + (size_t)n * 8192;
  const __bf16* vg = vb + (size_t)n * 8192;
  // stage: normalize k -> Ks + KT
#pragma unroll
  for (int it = 0; it < 4; ++it) {
    int u = it * 512 + t;
    int row = u >> 4, c4 = (u & 15) * 4;
    bf16x4 kh = ((const bf16x4*)kg)[u];
    float kf[4];
#pragma unroll
    for (int e = 0; e < 4; ++e) kf[e] = (float)kh[e];
    float ssq = kf[0] * kf[0] + kf[1] * kf[1] + kf[2] * kf[2] + kf[3] * kf[3];
    ssq = row16_reduce(ssq);
    float inv = 1.f / fmaxf(sqrtf(ssq), 1e-12f);
    bf16x4 kn;
#pragma unroll
    for (int e = 0; e < 4; ++e) kn[e] = (__bf16)(kf[e] * inv);
    stb4(Ks, row, c4, 64, kn);
#pragma unroll
    for (int e = 0; e < 4; ++e) stb(KT, c4 + e, row, 128, kn[e]);
  }
  __syncthreads();
  // S_neg = -(a * tril(KK^T)) packed-lower bf16 (diag tiles: col>=row -> 0)
  for (int p = wid; p < 36; p += 8) {
    int tr = 0, pp = p;
    while (pp > tr) { pp -= (tr + 1); ++tr; }
    int sc = pp;
    f32x4 acc = {0.f, 0.f, 0.f, 0.f};
#pragma unroll
    for (int ks = 0; ks < 2; ++ks)
      acc = __builtin_amdgcn_mfma_f32_16x16x32_bf16(
          ldfrag(Ks, tr * 16 + fr, ks * 32 + fk, 64),
          ldfrag(Ks, sc * 16 + fr, ks * 32 + fk, 64), acc, 0, 0, 0);
    __bf16* dst = Sng + stile(tr, sc);
#pragma unroll
    for (int rg = 0; rg < 4; ++rg) {
      int r = fkq * 4 + rg;
      float v = -a * acc[rg];
      if (tr == sc && fr >= r) v = 0.f;
      dst[r * 16 + fr] = (__bf16)v;
    }
  }
  // U,W init in C/D-layout registers (Ks reads complete before MT overlays it)
  f32x4 U[4], W[4];
#pragma unroll
  for (int ct = 0; ct < 4; ++ct) {
#pragma unroll
    for (int rg = 0; rg < 4; ++rg) {
      int row = wid * 16 + fkq * 4 + rg, col = ct * 16 + fr;
      U[ct][rg] = (float)ldsc(Ks, row, col, 64);
      W[ct][rg] = b * (float)vg[row * 64 + col];
    }
  }
  __syncthreads();
  // left-looking serial-wave stages
  for (int w = 0; w < 8; ++w) {
    if (wid == w) {
      // off-diagonal: full K=32 pairs of prior s-blocks
      for (int m = 0; m < (w >> 1); ++m) {
        bf16x8 af = *(const bf16x8*)(Sng + stile(w, 2 * m) + (fk >> 4) * 256 +
                                     fr * 16 + (fk & 8));
#pragma unroll
        for (int ct = 0; ct < 4; ++ct) {
          bf16x8 bu = ldfrag(MTu, ct * 16 + fr, m * 32 + fk, 128);
          bf16x8 bw = ldfrag(MTw, ct * 16 + fr, m * 32 + fk, 128);
          U[ct] = __builtin_amdgcn_mfma_f32_16x16x32_bf16(af, bu, U[ct], 0, 0, 0);
          W[ct] = __builtin_amdgcn_mfma_f32_16x16x32_bf16(af, bw, W[ct], 0, 0, 0);
        }
      }
      if (w & 1) {  // odd tail: s-block w-1 alone; k>=16 zero on BOTH operands
        bf16x8 zz;
#pragma unroll
        for (int e = 0; e < 8; ++e) zz[e] = (__bf16)0.f;
        bf16x8 af = zz;
        if (fk < 16) af = *(const bf16x8*)(Sng + stile(w, w - 1) + fr * 16 + fk);
#pragma unroll
        for (int ct = 0; ct < 4; ++ct) {
          bf16x8 bu = zz, bw = zz;
          if (fk < 16) {
            bu = ldfrag(MTu, ct * 16 + fr, (w - 1) * 16 + fk, 128);
            bw = ldfrag(MTw, ct * 16 + fr, (w - 1) * 16 + fk, 128);
          }
          U[ct] = __builtin_amdgcn_mfma_f32_16x16x32_bf16(af, bu, U[ct], 0, 0, 0);
          W[ct] = __builtin_amdgcn_mfma_f32_16x16x32_bf16(af, bw, W[ct], 0, 0, 0);
        }
      }
      // diagonal 15-step solve via shfl row broadcasts (pure registers)
      const __bf16* Sd = Sng + stile(w, w);
#pragma unroll
      for (int s = 0; s < 15; ++s) {
        const int sq = s >> 2, sr = s & 3;
        float bu_c[4], bw_c[4];
#pragma unroll
        for (int ct = 0; ct < 4; ++ct) bu_c[ct] = __shfl(U[ct][sr], sq * 16 + fr, 64);
#pragma unroll
        for (int ct = 0; ct < 4; ++ct) bw_c[ct] = __shfl(W[ct][sr], sq * 16 + fr, 64);
        float sv[4];
#pragma unroll
        for (int rg = 0; rg < 4; ++rg) sv[rg] = (float)Sd[(fkq * 4 + rg) * 16 + s];
#pragma unroll
        for (int ct = 0; ct < 4; ++ct)
#pragma unroll
          for (int rg = 0; rg < 4; ++rg)
            if (fkq * 4 + rg > s) {
              U[ct][rg] += sv[rg] * bu_c[ct];
              W[ct][rg] += sv[rg] * bw_c[ct];
            }
      }
      // append my solved rows to MT (bf16)
#pragma unroll
      for (int ct = 0; ct < 4; ++ct) {
        bf16x4 uu, ww;
#pragma unroll
        for (int rg = 0; rg < 4; ++rg) {
          uu[rg] = (__bf16)U[ct][rg];
          ww[rg] = (__bf16)W[ct][rg];
        }
        stb4(MTu, ct * 16 + fr, w * 16 + fkq * 4, 128, uu);
        stb4(MTw, ct * 16 + fr, w * 16 + fkq * 4, 128, ww);
      }
    }
    __syncthreads();
  }
  // coalesced global bf16 write of U,W in [t][d] layout
  __bf16* ugo = Ug + (size_t)n * 8192;
  __bf16* wgo = Wgb + (size_t)n * 8192;
#pragma unroll
  for (int it = 0; it < 4; ++it) {
    int e = it * 512 + t;
    int d = e & 63, t4 = e >> 6;
    bf16x4 uu = *(const bf16x4*)((const char*)MTu + swzb(d, t4 * 4, 128));
    bf16x4 ww = *(const bf16x4*)((const char*)MTw + swzb(d, t4 * 4, 128));
#pragma unroll
    for (int j = 0; j < 4; ++j) {
      ugo[(t4 * 4 + j) * 64 + d] = uu[j];
      wgo[(t4 * 4 + j) * 64 + d] = ww[j];
    }
  }
  // A = I - a U^T K, B = W^T K  (MTu == U^T, MTw == W^T)
#pragma unroll
  for (int q = 0; q < 4; ++q) {
    int tile = wid + q * 8;  // 0-15 -> A, 16-31 -> B
    int mat = tile >> 4;
    int ti = (tile >> 2) & 3, tj = tile & 3;
    const __bf16* Ah = mat ? MTw : MTu;
    f32x4 acc = {0.f, 0.f, 0.f, 0.f};
#pragma unroll
    for (int ks = 0; ks < 4; ++ks)
      acc = __builtin_amdgcn_mfma_f32_16x16x32_bf16(
          ldfrag(Ah, ti * 16 + fr, ks * 32 + fk, 128),
          ldfrag(KT, tj * 16 + fr, ks * 32 + fk, 128), acc, 0, 0, 0);
    float* dst = (mat ? Bop : Aop) + (size_t)n * 4096;
#pragma unroll
    for (int rg = 0; rg < 4; ++rg) {
      int i = ti * 16 + fkq * 4 + rg, j = tj * 16 + fr;
      float v = mat ? acc[rg] : ((i == j ? 1.f : 0.f) - a * acc[rg]);
      dst[i * 64 + j] = v;
    }
  }
}

// ---------------- inter-chunk scan (unchanged) ----------------
__global__ __launch_bounds__(256) void chunk_scan(const float* __restrict__ Aop,
                                                  const float* __restrict__ Bop,
                                                  float* __restrict__ Mstart,
                                                  float* __restrict__ Mfinal) {
  int bh = blockIdx.x;
  int t = threadIdx.x, i = t >> 2, qd = t & 3;
  float M[16] __attribute__((aligned(16)));
#pragma unroll
  for (int j = 0; j < 16; ++j) M[j] = 0.f;
  __shared__ float As[4096];
  for (int c = 0; c < 16; ++c) {
    size_t cb = ((size_t)bh * 16 + c) * 4096;
#pragma unroll
    for (int u = 0; u < 4; ++u)
      *(float4*)(Mstart + cb + i * 64 + qd * 16 + u * 4) = *(const float4*)(&M[u * 4]);
    __syncthreads();
    for (int u = t; u < 1024; u += 256)
      ((float4*)As)[u] = ((const float4*)(Aop + cb))[u];
    __syncthreads();
    float acc[16] __attribute__((aligned(16)));
#pragma unroll
    for (int j = 0; j < 16; ++j) acc[j] = 0.f;
#pragma unroll
    for (int l = 0; l < 64; ++l) {
      float mil = __shfl(M[l & 15], ((t >> 2) & 15) * 4 + (l >> 4), 64);
      const float* arow = As + l * 64 + qd * 16;
#pragma unroll
      for (int j = 0; j < 16; ++j) acc[j] += mil * arow[j];
    }
#pragma unroll
    for (int u = 0; u < 4; ++u) {
      float4 bv = *(const float4*)(Bop + cb + i * 64 + qd * 16 + u * 4);
      acc[u * 4 + 0] += bv.x; acc[u * 4 + 1] += bv.y;
      acc[u * 4 + 2] += bv.z; acc[u * 4 + 3] += bv.w;
    }
#pragma unroll
    for (int j = 0; j < 16; ++j) M[j] = acc[j];
  }
#pragma unroll
  for (int u = 0; u < 4; ++u)
    *(float4*)(Mfinal + (size_t)bh * 4096 + i * 64 + qd * 16 + u * 4) =
        *(const float4*)(&M[u * 4]);
}

// ---------------- Y assembly (plain bf16, unchanged from R6) ----------------
__global__ __launch_bounds__(512, 4) void y_assemble(const __bf16* __restrict__ qb,
                                                     const __bf16* __restrict__ kb,
                                                     const __bf16* __restrict__ Ug,
                                                     const __bf16* __restrict__ Wgb,
                                                     const float* __restrict__ Mst,
                                                     const float* __restrict__ ar,
                                                     __bf16* __restrict__ ybf) {
  int n = blockIdx.x, h = (n >> 4) & 15, b = n >> 8, c = n & 15;
  float a = sgm(ar[h]) * 0.5f;
  int t = threadIdx.x, wid = t >> 6, lane = t & 63;
  int fr = lane & 15, fk = (lane >> 4) * 8;
  __shared__ __bf16 Qs[8192];    // [128][64] swz
  __shared__ __bf16 Rs[8192];    // [128][64] swz: K then U
  __shared__ __bf16 M0s[4096];   // [64][64] swz
  __shared__ __bf16 Gs[10240];   // 40 packed 16x16 tiles
  __shared__ __bf16 WtT[8192];   // [64][128] swz
  const __bf16* qg = qb + (size_t)n * 8192;
  const __bf16* kg = kb + (size_t)n * 8192;
  const float* mg = Mst + (size_t)n * 4096;
#pragma unroll
  for (int it = 0; it < 4; ++it) {
    int u = it * 512 + t;
    int row = u >> 4, c4 = (u & 15) * 4;
    stb4(Qs, row, c4, 64, ((const bf16x4*)qg)[u]);
    bf16x4 kh = ((const bf16x4*)kg)[u];
    float kf[4];
#pragma unroll
    for (int e = 0; e < 4; ++e) kf[e] = (float)kh[e];
    float ssq = kf[0] * kf[0] + kf[1] * kf[1] + kf[2] * kf[2] + kf[3] * kf[3];
    ssq = row16_reduce(ssq);
    float inv = 1.f / fmaxf(sqrtf(ssq), 1e-12f);
    bf16x4 kn;
#pragma unroll
    for (int e = 0; e < 4; ++e) kn[e] = (__bf16)(kf[e] * inv);
    stb4(Rs, row, c4, 64, kn);
  }
#pragma unroll
  for (int it = 0; it < 2; ++it) {
    int u = it * 512 + t;
    int row = u >> 4, c4 = (u & 15) * 4;
    float4 mv = ((const float4*)mg)[u];
    bf16x4 mb;
    mb[0] = (__bf16)mv.x; mb[1] = (__bf16)mv.y;
    mb[2] = (__bf16)mv.z; mb[3] = (__bf16)mv.w;
    stb4(M0s, row, c4, 64, mb);
  }
#pragma unroll
  for (int pz = 0; pz < 2; ++pz) {
    int e = pz * 512 + t;
    int m = e >> 8, idx = e & 255;
    Gs[(2 * m * m + 4 * m + 1) * 256 + idx] = (__bf16)0.f;
  }
  __syncthreads();
  // P1: G = tril(Q K^T, -1), packed-lower bf16
  for (int p = wid; p < 36; p += 8) {
    int tr = 0, pp = p;
    while (pp > tr) { pp -= (tr + 1); ++tr; }
    int sc = pp;
    f32x4 acc = {0.f, 0.f, 0.f, 0.f};
#pragma unroll
    for (int ks = 0; ks < 2; ++ks)
      acc = __builtin_amdgcn_mfma_f32_16x16x32_bf16(
          ldfrag(Qs, tr * 16 + fr, ks * 32 + fk, 64),
          ldfrag(Rs, sc * 16 + fr, ks * 32 + fk, 64), acc, 0, 0, 0);
    int row0 = (lane >> 4) * 4, col = lane & 15;
    __bf16* gt = Gs + (goffn(tr) + sc) * 256;
#pragma unroll
    for (int rg = 0; rg < 4; ++rg) {
      int r = row0 + rg;
      float v = acc[rg];
      if (tr == sc && col >= r) v = 0.f;
      gt[r * 16 + col] = (__bf16)v;
    }
  }
  __syncthreads();
  // P2: restage Rs <- U
  const __bf16* ug = Ug + (size_t)n * 8192;
  const __bf16* wg = Wgb + (size_t)n * 8192;
#pragma unroll
  for (int it = 0; it < 4; ++it) {
    int u = it * 512 + t;
    int row = u >> 4, c4 = (u & 15) * 4;
    stb4(Rs, row, c4, 64, ((const bf16x4*)ug)[u]);
  }
  __syncthreads();
  // P3: WtT[i][s] = W[s][i] - a*(U M0^T)[s][i]
#pragma unroll
  for (int q = 0; q < 4; ++q) {
    int tile = wid + q * 8;
    int ti = tile >> 2, tj = tile & 3;
    f32x4 acc = {0.f, 0.f, 0.f, 0.f};
#pragma unroll
    for (int ks = 0; ks < 2; ++ks)
      acc = __builtin_amdgcn_mfma_f32_16x16x32_bf16(
          ldfrag(Rs, ti * 16 + fr, ks * 32 + fk, 64),
          ldfrag(M0s, tj * 16 + fr, ks * 32 + fk, 64), acc, 0, 0, 0);
    int row0 = (lane >> 4) * 4, col = lane & 15;
#pragma unroll
    for (int rg = 0; rg < 4; ++rg) {
      int s = ti * 16 + row0 + rg, i = tj * 16 + col;
      float wv = (float)wg[s * 64 + i];
      stb(WtT, i, s, 128, (__bf16)(wv - a * acc[rg]));
    }
  }
  __syncthreads();
  // P4: Y = Q M0^T + G Wt
  __bf16* yg = ybf + ((size_t)(b * 2048 + c * 128)) * 1024 + h * 64;
#pragma unroll
  for (int q = 0; q < 4; ++q) {
    int tile = wid + q * 8;
    int ti = tile >> 2, tj = tile & 3;
    f32x4 acc = {0.f, 0.f, 0.f, 0.f};
#pragma unroll
    for (int ks = 0; ks < 2; ++ks)
      acc = __builtin_amdgcn_mfma_f32_16x16x32_bf16(
          ldfrag(Qs, ti * 16 + fr, ks * 32 + fk, 64),
          ldfrag(M0s, tj * 16 + fr, ks * 32 + fk, 64), acc, 0, 0, 0);
    int goffv = goffn(ti);
    int np = (ti + 2) >> 1;
    for (int ks = 0; ks < np; ++ks) {
      int gtile = goffv + ks * 2 + (fk >> 4);
      bf16x8 af = *(const bf16x8*)(Gs + gtile * 256 + fr * 16 + (fk & 15));
      acc = __builtin_amdgcn_mfma_f32_16x16x32_bf16(
          af, ldfrag(WtT, tj * 16 + fr, ks * 32 + fk, 128), acc, 0, 0, 0);
    }
    int row0 = (lane >> 4) * 4, col = lane & 15;
#pragma unroll
    for (int rg = 0; rg < 4; ++rg) {
      int tt = ti * 16 + row0 + rg, d = tj * 16 + col;
      yg[(size_t)tt * 1024 + d] = (__bf16)acc[rg];
    }
  }
}

extern "C" void kernel_launch(void* const* d_in, const int* in_sizes, int n_in,
                              void* d_out, int out_size, void* d_ws, size_t ws_size,
                              hipStream_t stream) {
  const float* x  = (const float*)d_in[0];
  const float* Wq = (const float*)d_in[1];
  const float* Wk = (const float*)d_in[2];
  const float* Wv = (const float*)d_in[3];
  const float* Wo = (const float*)d_in[4];
  const float* ar = (const float*)d_in[5];
  const float* br = (const float*)d_in[6];

  char* ws = (char*)d_ws;
  __bf16* xb  = (__bf16*)ws;                       // 16.8 MB, reused as ybf
  __bf16* ybf = xb;
  __bf16* wqt = (__bf16*)(ws + (17u << 20));       // 2 MB each
  __bf16* wkt = wqt + (1u << 20);
  __bf16* wvt = wkt + (1u << 20);
  __bf16* wot = wvt + (1u << 20);
  __bf16* qb  = (__bf16*)(ws + (25u << 20));       // 16.8 MB bf16 each
  __bf16* kb  = (__bf16*)(ws + (42u << 20));
  __bf16* vb  = (__bf16*)(ws + (59u << 20));
  __bf16* Ugb = (__bf16*)(ws + (76u << 20));
  __bf16* Wgb = (__bf16*)(ws + (93u << 20));
  float* Aop  = (float*)(ws + (110u << 20));       // 16.8 MB fp32 each
  float* Bop  = (float*)(ws + (127u << 20));
  float* Mst  = (float*)(ws + (144u << 20));       // ..161 MB

  float* yout = (float*)d_out;                     // [8192,1024] f32
  float* Mfin = yout + 8388608;

  cast_f32_bf16<<<8192, 256, 0, stream>>>(x, xb);
  dim3 tg(32, 32);
  transpose_cast<<<tg, 256, 0, stream>>>(Wq, wqt);
  transpose_cast<<<tg, 256, 0, stream>>>(Wk, wkt);
  transpose_cast<<<tg, 256, 0, stream>>>(Wv, wvt);
  transpose_cast<<<tg, 256, 0, stream>>>(Wo, wot);

  dim3 gg(8, 64);
  gemm_bt<<<gg, 256, 0, stream>>>(xb, wqt, nullptr, qb, 1);
  gemm_bt<<<gg, 256, 0, stream>>>(xb, wkt, nullptr, kb, 1);
  gemm_bt<<<gg, 256, 0, stream>>>(xb, wvt, nullptr, vb, 1);

  wy_ab<<<1024, 512, 0, stream>>>(kb, vb, ar, br, Ugb, Wgb, Aop, Bop);
  chunk_scan<<<64, 256, 0, stream>>>(Aop, Bop, Mst, Mfin);
  y_assemble<<<1024, 512, 0, stream>>>(qb, kb, Ugb, Wgb, Mst, ar, ybf);

  gemm_bt<<<gg, 256, 0, stream>>>(ybf, wot, yout, nullptr, 0);
}

// Round 9
// 255.356 us; speedup vs baseline: 1.9866x; 1.2493x over previous
//
#include <hip/hip_runtime.h>
#include <stdint.h>

// Titans-L2 chunked delta-rule forward — WY reformulation, MFMA everywhere.
//   1. cast x -> bf16; transpose+cast Wq/Wk/Wv/Wo -> bf16 [N,K]
//   2. MFMA GEMMs: q,k,v = x@W  (written DIRECTLY as bf16 [B,H,T,D])
//   3. wy_ab (per chunk): normalize k; S_neg = -a*tril(KK^T,-1) bf16 tiles;
//      left-looking substitution (serial-wave stages, shfl diag, MFMA off-diag);
//      emits U,W bf16; A^T = I - a*K^T U as PRE-SWIZZLED bf16; B = W^T K fp32.
//   4. chunk_scan (MFMA): per (b,h), M_{c+1} = M_c A_c + B_c with M in fp32
//      C-regs bounced via hi/lo bf16 LDS; A^T staged by global_load_lds into
//      linear LDS (pre-swizzled source == swizzled read); Mstart -> bf16;
//      M_final -> fp32 (output 1).
//   5. y_assemble: G = tril(QK^T,-1); Wt = W - a*(U M0^T);
//      Y = Q M0^T + G Wt; writes y as bf16 [B*T, C]
//   6. final MFMA GEMM y@Wo -> d_out (fp32)
// Dims: B=4 H=16 T=2048 C=1024 D=64 CS=128 nc=16 N=1024 tokens=8192

#define DEV __device__ __forceinline__

typedef __attribute__((ext_vector_type(4))) float f32x4;
typedef __attribute__((ext_vector_type(8))) __bf16 bf16x8;
typedef __attribute__((ext_vector_type(4))) __bf16 bf16x4;

typedef const __attribute__((address_space(1))) uint32_t* gas1_t;
typedef __attribute__((address_space(3))) uint32_t* las3_t;

DEV void gload_lds16(const void* g, void* l) {
  __builtin_amdgcn_global_load_lds((gas1_t)g, (las3_t)l, 16, 0, 0);
}

DEV float sgm(float x) { return 1.f / (1.f + __expf(-x)); }

template <int CTRL>
DEV float dpp_mov(float x) {
  return __builtin_bit_cast(
      float, __builtin_amdgcn_mov_dpp(__builtin_bit_cast(int, x), CTRL, 0xF, 0xF, true));
}
// cyclic rotate-reduce: sum over each 16-lane DPP row
DEV float row16_reduce(float x) {
  x += dpp_mov<0x121>(x);  // row_ror:1
  x += dpp_mov<0x122>(x);  // row_ror:2
  x += dpp_mov<0x124>(x);  // row_ror:4
  x += dpp_mov<0x128>(x);  // row_ror:8
  return x;
}

// ---- swizzled LDS helpers (row-major bf16 tiles; XOR bank swizzle) ----
DEV int swzb(int row, int col, int stride) {  // byte offset
  return ((row * stride + col) << 1) ^ ((row & 7) << 4);
}
DEV bf16x8 ldfrag(const __bf16* B, int row, int col, int stride) {
  return *(const bf16x8*)((const char*)B + swzb(row, col, stride));
}
DEV __bf16 ldsc(const __bf16* B, int row, int col, int stride) {
  return *(const __bf16*)((const char*)B + swzb(row, col, stride));
}
DEV void stb(__bf16* B, int row, int col, int stride, __bf16 v) {
  *(__bf16*)((char*)B + swzb(row, col, stride)) = v;
}
DEV void stb4(__bf16* B, int row, int c4, int stride, bf16x4 v) {
  *(bf16x4*)((char*)B + swzb(row, c4, stride)) = v;
}
// packed-lower tile offsets: row tr holds tiles 0..tr (+1 zero pad for even tr)
DEV int goffn(int tr) {
  int m = tr >> 1;
  return (tr & 1) ? (2 * m * m + 4 * m + 2) : (2 * m * m + 2 * m);
}
DEV int stile(int tr, int sc) { return ((tr * (tr + 1)) / 2 + sc) * 256; }

// ---------------- casts ----------------
__global__ __launch_bounds__(256) void cast_f32_bf16(const float* __restrict__ in,
                                                     __bf16* __restrict__ out) {
  int idx = blockIdx.x * 256 + threadIdx.x;
  float4 v = ((const float4*)in)[idx];
  bf16x4 o;
  o[0] = (__bf16)v.x; o[1] = (__bf16)v.y; o[2] = (__bf16)v.z; o[3] = (__bf16)v.w;
  ((bf16x4*)out)[idx] = o;
}

__global__ __launch_bounds__(256) void transpose_cast(const float* __restrict__ W,
                                                      __bf16* __restrict__ Wt) {
  __shared__ float tile[32][33];
  int tx = threadIdx.x & 31, ty = threadIdx.x >> 5;
  int n0 = blockIdx.x * 32, k0 = blockIdx.y * 32;
#pragma unroll
  for (int u = 0; u < 4; ++u)
    tile[ty + u * 8][tx] = W[(size_t)(k0 + ty + u * 8) * 1024 + n0 + tx];
  __syncthreads();
#pragma unroll
  for (int u = 0; u < 4; ++u)
    Wt[(size_t)(n0 + ty + u * 8) * 1024 + k0 + tx] = (__bf16)tile[tx][ty + u * 8];
}

// ---------------- GEMM: C[M=8192,N=1024] = A[M,K=1024] * Bt[N,K]^T ----------------
// mode 0: fp32 C row-major [M,1024]. mode 1: bf16 scatter to [B,H,T,D]
__global__ __launch_bounds__(256) void gemm_bt(const __bf16* __restrict__ A,
                                               const __bf16* __restrict__ Bt,
                                               float* __restrict__ Cf,
                                               __bf16* __restrict__ Cb, int mode) {
  const int t = threadIdx.x;
  const int wv = t >> 6, lane = t & 63;
  const int bm = blockIdx.y, bn = blockIdx.x;
  const int K = 1024;
  __shared__ __bf16 lA[4096];
  __shared__ __bf16 lB[4096];
  f32x4 acc[4][4];
#pragma unroll
  for (int m = 0; m < 4; ++m)
#pragma unroll
    for (int n = 0; n < 4; ++n) acc[m][n] = 0.f;
  const int wr = wv >> 1, wc = wv & 1;
  const int fr = lane & 15, fk = (lane >> 4) * 8;
  const int e0 = (wv * 128 + lane) * 8;
  const int e1 = (wv * 128 + 64 + lane) * 8;
  const int r0s = e0 >> 5, c0s = e0 & 31;
  const int r1s = e1 >> 5, c1s = e1 & 31;
  for (int k0 = 0; k0 < K; k0 += 32) {
    gload_lds16(A + (size_t)(bm * 128 + r0s) * K + k0 + c0s, lA + wv * 1024);
    gload_lds16(Bt + (size_t)(bn * 128 + r0s) * K + k0 + c0s, lB + wv * 1024);
    gload_lds16(A + (size_t)(bm * 128 + r1s) * K + k0 + c1s, lA + wv * 1024 + 512);
    gload_lds16(Bt + (size_t)(bn * 128 + r1s) * K + k0 + c1s, lB + wv * 1024 + 512);
    __syncthreads();
    bf16x8 af[4], bg[4];
#pragma unroll
    for (int m = 0; m < 4; ++m)
      af[m] = *(const bf16x8*)(lA + (wr * 64 + m * 16 + fr) * 32 + fk);
#pragma unroll
    for (int n = 0; n < 4; ++n)
      bg[n] = *(const bf16x8*)(lB + (wc * 64 + n * 16 + fr) * 32 + fk);
#pragma unroll
    for (int m = 0; m < 4; ++m)
#pragma unroll
      for (int n = 0; n < 4; ++n)
        acc[m][n] = __builtin_amdgcn_mfma_f32_16x16x32_bf16(af[m], bg[n], acc[m][n], 0, 0, 0);
    __syncthreads();
  }
  const int rr = (lane >> 4) * 4, cl = lane & 15;
#pragma unroll
  for (int m = 0; m < 4; ++m) {
#pragma unroll
    for (int n = 0; n < 4; ++n) {
#pragma unroll
      for (int rg = 0; rg < 4; ++rg) {
        int row = bm * 128 + wr * 64 + m * 16 + rr + rg;
        int col = bn * 128 + wc * 64 + n * 16 + cl;
        float val = acc[m][n][rg];
        if (mode == 0) {
          Cf[(size_t)row * 1024 + col] = val;
        } else {
          int b = row >> 11, tk = row & 2047;
          int h = col >> 6, d = col & 63;
          Cb[(((size_t)b * 16 + h) * 2048 + tk) * 64 + d] = (__bf16)val;
        }
      }
    }
  }
}

// ---------------- fused WY solve + A/B (left-looking, register-resident) ----
// LDS 66 KB -> 2 blocks/CU. Wave w owns rows w*16..+15 of U,W in C/D regs.
// Emits: U,W bf16 [t][d]; AT = (I - a*U^T K)^T bf16 PRE-SWIZZLED; B = W^T K fp32.
__global__ __launch_bounds__(512, 4) void wy_ab(const __bf16* __restrict__ kb,
                                                const __bf16* __restrict__ vb,
                                                const float* __restrict__ ar,
                                                const float* __restrict__ br,
                                                __bf16* __restrict__ Ug,
                                                __bf16* __restrict__ Wgb,
                                                __bf16* __restrict__ ATg,
                                                float* __restrict__ Bop) {
  int n = blockIdx.x, h = (n >> 4) & 15;
  float a = sgm(ar[h]) * 0.5f;
  float b = sgm(br[h]) * 0.5f;
  int t = threadIdx.x, wid = t >> 6, lane = t & 63;
  int fr = lane & 15, fkq = lane >> 4, fk = fkq * 8;
  __shared__ __attribute__((aligned(16))) char pool[67584];
  __bf16* Ks  = (__bf16*)pool;            // [128][64] swz; dead after init
  __bf16* MTu = (__bf16*)pool;            // [64][128] swz == U^T (overlays Ks)
  __bf16* KT  = (__bf16*)(pool + 16384);  // [64][128] swz
  __bf16* MTw = (__bf16*)(pool + 32768);  // [64][128] swz == W^T
  __bf16* Sng = (__bf16*)(pool + 49152);  // 36 packed-lower 16x16 bf16 tiles
  const __bf16* kg = kb + (size_t)n * 8192;
  const __bf16* vg = vb + (size_t)n * 8192;
  // stage: normalize k -> Ks + KT
#pragma unroll
  for (int it = 0; it < 4; ++it) {
    int u = it * 512 + t;
    int row = u >> 4, c4 = (u & 15) * 4;
    bf16x4 kh = ((const bf16x4*)kg)[u];
    float kf[4];
#pragma unroll
    for (int e = 0; e < 4; ++e) kf[e] = (float)kh[e];
    float ssq = kf[0] * kf[0] + kf[1] * kf[1] + kf[2] * kf[2] + kf[3] * kf[3];
    ssq = row16_reduce(ssq);
    float inv = 1.f / fmaxf(sqrtf(ssq), 1e-12f);
    bf16x4 kn;
#pragma unroll
    for (int e = 0; e < 4; ++e) kn[e] = (__bf16)(kf[e] * inv);
    stb4(Ks, row, c4, 64, kn);
#pragma unroll
    for (int e = 0; e < 4; ++e) stb(KT, c4 + e, row, 128, kn[e]);
  }
  __syncthreads();
  // S_neg = -(a * tril(KK^T)) packed-lower bf16 (diag tiles: col>=row -> 0)
  for (int p = wid; p < 36; p += 8) {
    int tr = 0, pp = p;
    while (pp > tr) { pp -= (tr + 1); ++tr; }
    int sc = pp;
    f32x4 acc = {0.f, 0.f, 0.f, 0.f};
#pragma unroll
    for (int ks = 0; ks < 2; ++ks)
      acc = __builtin_amdgcn_mfma_f32_16x16x32_bf16(
          ldfrag(Ks, tr * 16 + fr, ks * 32 + fk, 64),
          ldfrag(Ks, sc * 16 + fr, ks * 32 + fk, 64), acc, 0, 0, 0);
    __bf16* dst = Sng + stile(tr, sc);
#pragma unroll
    for (int rg = 0; rg < 4; ++rg) {
      int r = fkq * 4 + rg;
      float v = -a * acc[rg];
      if (tr == sc && fr >= r) v = 0.f;
      dst[r * 16 + fr] = (__bf16)v;
    }
  }
  // U,W init in C/D-layout registers (Ks reads complete before MT overlays it)
  f32x4 U[4], W[4];
#pragma unroll
  for (int ct = 0; ct < 4; ++ct) {
#pragma unroll
    for (int rg = 0; rg < 4; ++rg) {
      int row = wid * 16 + fkq * 4 + rg, col = ct * 16 + fr;
      U[ct][rg] = (float)ldsc(Ks, row, col, 64);
      W[ct][rg] = b * (float)vg[row * 64 + col];
    }
  }
  __syncthreads();
  // left-looking serial-wave stages
  for (int w = 0; w < 8; ++w) {
    if (wid == w) {
      // off-diagonal: full K=32 pairs of prior s-blocks
      for (int m = 0; m < (w >> 1); ++m) {
        bf16x8 af = *(const bf16x8*)(Sng + stile(w, 2 * m) + (fk >> 4) * 256 +
                                     fr * 16 + (fk & 8));
#pragma unroll
        for (int ct = 0; ct < 4; ++ct) {
          bf16x8 bu = ldfrag(MTu, ct * 16 + fr, m * 32 + fk, 128);
          bf16x8 bw = ldfrag(MTw, ct * 16 + fr, m * 32 + fk, 128);
          U[ct] = __builtin_amdgcn_mfma_f32_16x16x32_bf16(af, bu, U[ct], 0, 0, 0);
          W[ct] = __builtin_amdgcn_mfma_f32_16x16x32_bf16(af, bw, W[ct], 0, 0, 0);
        }
      }
      if (w & 1) {  // odd tail: s-block w-1 alone; k>=16 zero on BOTH operands
        bf16x8 zz;
#pragma unroll
        for (int e = 0; e < 8; ++e) zz[e] = (__bf16)0.f;
        bf16x8 af = zz;
        if (fk < 16) af = *(const bf16x8*)(Sng + stile(w, w - 1) + fr * 16 + fk);
#pragma unroll
        for (int ct = 0; ct < 4; ++ct) {
          bf16x8 bu = zz, bw = zz;
          if (fk < 16) {
            bu = ldfrag(MTu, ct * 16 + fr, (w - 1) * 16 + fk, 128);
            bw = ldfrag(MTw, ct * 16 + fr, (w - 1) * 16 + fk, 128);
          }
          U[ct] = __builtin_amdgcn_mfma_f32_16x16x32_bf16(af, bu, U[ct], 0, 0, 0);
          W[ct] = __builtin_amdgcn_mfma_f32_16x16x32_bf16(af, bw, W[ct], 0, 0, 0);
        }
      }
      // diagonal 15-step solve via shfl row broadcasts (pure registers)
      const __bf16* Sd = Sng + stile(w, w);
#pragma unroll
      for (int s = 0; s < 15; ++s) {
        const int sq = s >> 2, sr = s & 3;
        float bu_c[4], bw_c[4];
#pragma unroll
        for (int ct = 0; ct < 4; ++ct) bu_c[ct] = __shfl(U[ct][sr], sq * 16 + fr, 64);
#pragma unroll
        for (int ct = 0; ct < 4; ++ct) bw_c[ct] = __shfl(W[ct][sr], sq * 16 + fr, 64);
        float sv[4];
#pragma unroll
        for (int rg = 0; rg < 4; ++rg) sv[rg] = (float)Sd[(fkq * 4 + rg) * 16 + s];
#pragma unroll
        for (int ct = 0; ct < 4; ++ct)
#pragma unroll
          for (int rg = 0; rg < 4; ++rg)
            if (fkq * 4 + rg > s) {
              U[ct][rg] += sv[rg] * bu_c[ct];
              W[ct][rg] += sv[rg] * bw_c[ct];
            }
      }
      // append my solved rows to MT (bf16)
#pragma unroll
      for (int ct = 0; ct < 4; ++ct) {
        bf16x4 uu, ww;
#pragma unroll
        for (int rg = 0; rg < 4; ++rg) {
          uu[rg] = (__bf16)U[ct][rg];
          ww[rg] = (__bf16)W[ct][rg];
        }
        stb4(MTu, ct * 16 + fr, w * 16 + fkq * 4, 128, uu);
        stb4(MTw, ct * 16 + fr, w * 16 + fkq * 4, 128, ww);
      }
    }
    __syncthreads();
  }
  // coalesced global bf16 write of U,W in [t][d] layout
  __bf16* ugo = Ug + (size_t)n * 8192;
  __bf16* wgo = Wgb + (size_t)n * 8192;
#pragma unroll
  for (int it = 0; it < 4; ++it) {
    int e = it * 512 + t;
    int d = e & 63, t4 = e >> 6;
    bf16x4 uu = *(const bf16x4*)((const char*)MTu + swzb(d, t4 * 4, 128));
    bf16x4 ww = *(const bf16x4*)((const char*)MTw + swzb(d, t4 * 4, 128));
#pragma unroll
    for (int j = 0; j < 4; ++j) {
      ugo[(t4 * 4 + j) * 64 + d] = uu[j];
      wgo[(t4 * 4 + j) * 64 + d] = ww[j];
    }
  }
  // AT = I - a*(K^T U)  (pre-swizzled bf16), B = W^T K (fp32)
#pragma unroll
  for (int q = 0; q < 4; ++q) {
    int tile = wid + q * 8;  // 0-15 -> AT, 16-31 -> B
    int mat = tile >> 4;
    int ti = (tile >> 2) & 3, tj = tile & 3;
    f32x4 acc = {0.f, 0.f, 0.f, 0.f};
    if (mat == 0) {
#pragma unroll
      for (int ks = 0; ks < 4; ++ks)
        acc = __builtin_amdgcn_mfma_f32_16x16x32_bf16(
            ldfrag(KT, ti * 16 + fr, ks * 32 + fk, 128),
            ldfrag(MTu, tj * 16 + fr, ks * 32 + fk, 128), acc, 0, 0, 0);
      char* dst = (char*)(ATg + (size_t)n * 4096);
#pragma unroll
      for (int rg = 0; rg < 4; ++rg) {
        int i = ti * 16 + fkq * 4 + rg, j = tj * 16 + fr;
        float v = (i == j ? 1.f : 0.f) - a * acc[rg];
        *(__bf16*)(dst + swzb(i, j, 64)) = (__bf16)v;
      }
    } else {
#pragma unroll
      for (int ks = 0; ks < 4; ++ks)
        acc = __builtin_amdgcn_mfma_f32_16x16x32_bf16(
            ldfrag(MTw, ti * 16 + fr, ks * 32 + fk, 128),
            ldfrag(KT, tj * 16 + fr, ks * 32 + fk, 128), acc, 0, 0, 0);
      float* dst = Bop + (size_t)n * 4096;
#pragma unroll
      for (int rg = 0; rg < 4; ++rg)
        dst[(ti * 16 + fkq * 4 + rg) * 64 + tj * 16 + fr] = acc[rg];
    }
  }
}

// ---------------- inter-chunk scan (MFMA) ----------------
// 64 blocks (one per (b,h)), 8 waves. Wave w owns M tiles (ti=w&3, tj=(w>>2)*2+{0,1}).
// Per step: Mstart[c] <- M (bf16); Mh/Ml <- M; acc = B + (Mh+Ml)·AT^T via MFMA.
__global__ __launch_bounds__(512) void chunk_scan(const __bf16* __restrict__ ATg,
                                                  const float* __restrict__ Bop,
                                                  __bf16* __restrict__ Mst,
                                                  float* __restrict__ Mfinal) {
  int bh = blockIdx.x;
  int t = threadIdx.x, wid = t >> 6, lane = t & 63;
  int fr = lane & 15, fkq = lane >> 4, fk = fkq * 8;
  int ti = wid & 3, tj0 = (wid >> 2) << 1;
  __shared__ __bf16 Mh[4096];    // [64][64] swz
  __shared__ __bf16 Ml[4096];    // [64][64] swz
  __shared__ __bf16 At[2][4096]; // [64][64], pre-swizzled via linear gload_lds
  f32x4 acc[2];
  acc[0] = 0.f;
  acc[1] = 0.f;
  // prefetch AT chunk 0 (8 KB: one 16B load per thread)
  gload_lds16(ATg + (size_t)bh * 16 * 4096 + t * 8, At[0] + t * 8);
  for (int c = 0; c < 16; ++c) {
    int cur = c & 1;
    if (c < 15)
      gload_lds16(ATg + ((size_t)(bh * 16 + c + 1)) * 4096 + t * 8,
                  At[cur ^ 1] + t * 8);
    // Mstart[c] = M (bf16); stage M hi/lo into LDS
    __bf16* mstc = Mst + ((size_t)(bh * 16 + c)) * 4096;
#pragma unroll
    for (int p = 0; p < 2; ++p) {
      int tj = tj0 + p;
#pragma unroll
      for (int rg = 0; rg < 4; ++rg) {
        int row = ti * 16 + fkq * 4 + rg, col = tj * 16 + fr;
        float v = acc[p][rg];
        __bf16 hi = (__bf16)v;
        mstc[row * 64 + col] = hi;
        stb(Mh, row, col, 64, hi);
        stb(Ml, row, col, 64, (__bf16)(v - (float)hi));
      }
    }
    __syncthreads();  // Mh/Ml visible; At[cur] loads drained
    size_t bb = ((size_t)(bh * 16 + c)) * 4096;
#pragma unroll
    for (int p = 0; p < 2; ++p) {
      int tj = tj0 + p;
      f32x4 na;
#pragma unroll
      for (int rg = 0; rg < 4; ++rg)
        na[rg] = Bop[bb + (ti * 16 + fkq * 4 + rg) * 64 + tj * 16 + fr];
#pragma unroll
      for (int ks = 0; ks < 2; ++ks) {
        bf16x8 bfrag = ldfrag(At[cur], tj * 16 + fr, ks * 32 + fk, 64);
        bf16x8 ah = ldfrag(Mh, ti * 16 + fr, ks * 32 + fk, 64);
        bf16x8 al = ldfrag(Ml, ti * 16 + fr, ks * 32 + fk, 64);
        na = __builtin_amdgcn_mfma_f32_16x16x32_bf16(ah, bfrag, na, 0, 0, 0);
        na = __builtin_amdgcn_mfma_f32_16x16x32_bf16(al, bfrag, na, 0, 0, 0);
      }
      acc[p] = na;
    }
    __syncthreads();  // all reads of Mh/Ml/At[cur] done before next overwrite
  }
  // M_final (fp32 output)
#pragma unroll
  for (int p = 0; p < 2; ++p) {
    int tj = tj0 + p;
#pragma unroll
    for (int rg = 0; rg < 4; ++rg)
      Mfinal[(size_t)bh * 4096 + (ti * 16 + fkq * 4 + rg) * 64 + tj * 16 + fr] =
          acc[p][rg];
  }
}

// ---------------- Y assembly (plain bf16) ----------------
__global__ __launch_bounds__(512, 4) void y_assemble(const __bf16* __restrict__ qb,
                                                     const __bf16* __restrict__ kb,
                                                     const __bf16* __restrict__ Ug,
                                                     const __bf16* __restrict__ Wgb,
                                                     const __bf16* __restrict__ Mst,
                                                     const float* __restrict__ ar,
                                                     __bf16* __restrict__ ybf) {
  int n = blockIdx.x, h = (n >> 4) & 15, b = n >> 8, c = n & 15;
  float a = sgm(ar[h]) * 0.5f;
  int t = threadIdx.x, wid = t >> 6, lane = t & 63;
  int fr = lane & 15, fk = (lane >> 4) * 8;
  __shared__ __bf16 Qs[8192];    // [128][64] swz
  __shared__ __bf16 Rs[8192];    // [128][64] swz: K then U
  __shared__ __bf16 M0s[4096];   // [64][64] swz
  __shared__ __bf16 Gs[10240];   // 40 packed 16x16 tiles
  __shared__ __bf16 WtT[8192];   // [64][128] swz
  const __bf16* qg = qb + (size_t)n * 8192;
  const __bf16* kg = kb + (size_t)n * 8192;
  const __bf16* mg = Mst + (size_t)n * 4096;
#pragma unroll
  for (int it = 0; it < 4; ++it) {
    int u = it * 512 + t;
    int row = u >> 4, c4 = (u & 15) * 4;
    stb4(Qs, row, c4, 64, ((const bf16x4*)qg)[u]);
    bf16x4 kh = ((const bf16x4*)kg)[u];
    float kf[4];
#pragma unroll
    for (int e = 0; e < 4; ++e) kf[e] = (float)kh[e];
    float ssq = kf[0] * kf[0] + kf[1] * kf[1] + kf[2] * kf[2] + kf[3] * kf[3];
    ssq = row16_reduce(ssq);
    float inv = 1.f / fmaxf(sqrtf(ssq), 1e-12f);
    bf16x4 kn;
#pragma unroll
    for (int e = 0; e < 4; ++e) kn[e] = (__bf16)(kf[e] * inv);
    stb4(Rs, row, c4, 64, kn);
  }
#pragma unroll
  for (int it = 0; it < 2; ++it) {
    int u = it * 512 + t;
    int row = u >> 4, c4 = (u & 15) * 4;
    stb4(M0s, row, c4, 64, ((const bf16x4*)mg)[u]);
  }
#pragma unroll
  for (int pz = 0; pz < 2; ++pz) {
    int e = pz * 512 + t;
    int m = e >> 8, idx = e & 255;
    Gs[(2 * m * m + 4 * m + 1) * 256 + idx] = (__bf16)0.f;
  }
  __syncthreads();
  // P1: G = tril(Q K^T, -1), packed-lower bf16
  for (int p = wid; p < 36; p += 8) {
    int tr = 0, pp = p;
    while (pp > tr) { pp -= (tr + 1); ++tr; }
    int sc = pp;
    f32x4 acc = {0.f, 0.f, 0.f, 0.f};
#pragma unroll
    for (int ks = 0; ks < 2; ++ks)
      acc = __builtin_amdgcn_mfma_f32_16x16x32_bf16(
          ldfrag(Qs, tr * 16 + fr, ks * 32 + fk, 64),
          ldfrag(Rs, sc * 16 + fr, ks * 32 + fk, 64), acc, 0, 0, 0);
    int row0 = (lane >> 4) * 4, col = lane & 15;
    __bf16* gt = Gs + (goffn(tr) + sc) * 256;
#pragma unroll
    for (int rg = 0; rg < 4; ++rg) {
      int r = row0 + rg;
      float v = acc[rg];
      if (tr == sc && col >= r) v = 0.f;
      gt[r * 16 + col] = (__bf16)v;
    }
  }
  __syncthreads();
  // P2: restage Rs <- U
  const __bf16* ug = Ug + (size_t)n * 8192;
  const __bf16* wg = Wgb + (size_t)n * 8192;
#pragma unroll
  for (int it = 0; it < 4; ++it) {
    int u = it * 512 + t;
    int row = u >> 4, c4 = (u & 15) * 4;
    stb4(Rs, row, c4, 64, ((const bf16x4*)ug)[u]);
  }
  __syncthreads();
  // P3: WtT[i][s] = W[s][i] - a*(U M0^T)[s][i]
#pragma unroll
  for (int q = 0; q < 4; ++q) {
    int tile = wid + q * 8;
    int ti = tile >> 2, tj = tile & 3;
    f32x4 acc = {0.f, 0.f, 0.f, 0.f};
#pragma unroll
    for (int ks = 0; ks < 2; ++ks)
      acc = __builtin_amdgcn_mfma_f32_16x16x32_bf16(
          ldfrag(Rs, ti * 16 + fr, ks * 32 + fk, 64),
          ldfrag(M0s, tj * 16 + fr, ks * 32 + fk, 64), acc, 0, 0, 0);
    int row0 = (lane >> 4) * 4, col = lane & 15;
#pragma unroll
    for (int rg = 0; rg < 4; ++rg) {
      int s = ti * 16 + row0 + rg, i = tj * 16 + col;
      float wv = (float)wg[s * 64 + i];
      stb(WtT, i, s, 128, (__bf16)(wv - a * acc[rg]));
    }
  }
  __syncthreads();
  // P4: Y = Q M0^T + G Wt
  __bf16* yg = ybf + ((size_t)(b * 2048 + c * 128)) * 1024 + h * 64;
#pragma unroll
  for (int q = 0; q < 4; ++q) {
    int tile = wid + q * 8;
    int ti = tile >> 2, tj = tile & 3;
    f32x4 acc = {0.f, 0.f, 0.f, 0.f};
#pragma unroll
    for (int ks = 0; ks < 2; ++ks)
      acc = __builtin_amdgcn_mfma_f32_16x16x32_bf16(
          ldfrag(Qs, ti * 16 + fr, ks * 32 + fk, 64),
          ldfrag(M0s, tj * 16 + fr, ks * 32 + fk, 64), acc, 0, 0, 0);
    int goffv = goffn(ti);
    int np = (ti + 2) >> 1;
    for (int ks = 0; ks < np; ++ks) {
      int gtile = goffv + ks * 2 + (fk >> 4);
      bf16x8 af = *(const bf16x8*)(Gs + gtile * 256 + fr * 16 + (fk & 15));
      acc = __builtin_amdgcn_mfma_f32_16x16x32_bf16(
          af, ldfrag(WtT, tj * 16 + fr, ks * 32 + fk, 128), acc, 0, 0, 0);
    }
    int row0 = (lane >> 4) * 4, col = lane & 15;
#pragma unroll
    for (int rg = 0; rg < 4; ++rg) {
      int tt = ti * 16 + row0 + rg, d = tj * 16 + col;
      yg[(size_t)tt * 1024 + d] = (__bf16)acc[rg];
    }
  }
}

extern "C" void kernel_launch(void* const* d_in, const int* in_sizes, int n_in,
                              void* d_out, int out_size, void* d_ws, size_t ws_size,
                              hipStream_t stream) {
  const float* x  = (const float*)d_in[0];
  const float* Wq = (const float*)d_in[1];
  const float* Wk = (const float*)d_in[2];
  const float* Wv = (const float*)d_in[3];
  const float* Wo = (const float*)d_in[4];
  const float* ar = (const float*)d_in[5];
  const float* br = (const float*)d_in[6];

  char* ws = (char*)d_ws;
  __bf16* xb  = (__bf16*)ws;                       // 16.8 MB, reused as ybf
  __bf16* ybf = xb;
  __bf16* wqt = (__bf16*)(ws + (17u << 20));       // 2 MB each
  __bf16* wkt = wqt + (1u << 20);
  __bf16* wvt = wkt + (1u << 20);
  __bf16* wot = wvt + (1u << 20);
  __bf16* qb  = (__bf16*)(ws + (25u << 20));       // 16.8 MB bf16 each
  __bf16* kb  = (__bf16*)(ws + (42u << 20));
  __bf16* vb  = (__bf16*)(ws + (59u << 20));
  __bf16* Ugb = (__bf16*)(ws + (76u << 20));
  __bf16* Wgb = (__bf16*)(ws + (93u << 20));
  __bf16* ATg = (__bf16*)(ws + (110u << 20));      // 8.4 MB bf16 (pre-swizzled)
  float* Bop  = (float*)(ws + (127u << 20));       // 16.8 MB fp32
  __bf16* Mst = (__bf16*)(ws + (144u << 20));      // 8.4 MB bf16

  float* yout = (float*)d_out;                     // [8192,1024] f32
  float* Mfin = yout + 8388608;

  cast_f32_bf16<<<8192, 256, 0, stream>>>(x, xb);
  dim3 tg(32, 32);
  transpose_cast<<<tg, 256, 0, stream>>>(Wq, wqt);
  transpose_cast<<<tg, 256, 0, stream>>>(Wk, wkt);
  transpose_cast<<<tg, 256, 0, stream>>>(Wv, wvt);
  transpose_cast<<<tg, 256, 0, stream>>>(Wo, wot);

  dim3 gg(8, 64);
  gemm_bt<<<gg, 256, 0, stream>>>(xb, wqt, nullptr, qb, 1);
  gemm_bt<<<gg, 256, 0, stream>>>(xb, wkt, nullptr, kb, 1);
  gemm_bt<<<gg, 256, 0, stream>>>(xb, wvt, nullptr, vb, 1);

  wy_ab<<<1024, 512, 0, stream>>>(kb, vb, ar, br, Ugb, Wgb, ATg, Bop);
  chunk_scan<<<64, 512, 0, stream>>>(ATg, Bop, Mst, Mfin);
  y_assemble<<<1024, 512, 0, stream>>>(qb, kb, Ugb, Wgb, Mst, ar, ybf);

  gemm_bt<<<gg, 256, 0, stream>>>(ybf, wot, yout, nullptr, 0);
}

// Round 10
// 254.553 us; speedup vs baseline: 1.9929x; 1.0032x over previous
//
#include <hip/hip_runtime.h>
#include <stdint.h>

// Titans-L2 chunked delta-rule forward — WY reformulation, MFMA everywhere.
//   1. cast x -> bf16; transpose+cast Wq/Wk/Wv/Wo -> bf16 [N,K]
//   2. MFMA GEMMs: q,k,v = x@W  (written DIRECTLY as bf16 [B,H,T,D])
//   3. wy_ab (per chunk): normalize k; S_neg = -a*tril(KK^T,-1) bf16 tiles;
//      RIGHT-LOOKING substitution: stage bb = {wave bb shfl diag solve + MT
//      write; barrier; waves w>bb apply rank-16 MFMA update in parallel};
//      U,W written to global straight from registers (no LDS bounce);
//      emits A^T = I - a*K^T U PRE-SWIZZLED bf16; B = W^T K fp32.
//   4. chunk_scan (MFMA): per (b,h), M_{c+1} = M_c A_c + B_c with M in fp32
//      C-regs bounced via hi/lo bf16 LDS; A^T staged by global_load_lds into
//      linear LDS (pre-swizzled source == swizzled read); Mstart -> bf16;
//      M_final -> fp32 (output 1).
//   5. y_assemble: G = tril(QK^T,-1); Wt = W - a*(U M0^T);
//      Y = Q M0^T + G Wt; writes y as bf16 [B*T, C]
//   6. final MFMA GEMM y@Wo -> d_out (fp32)
// Dims: B=4 H=16 T=2048 C=1024 D=64 CS=128 nc=16 N=1024 tokens=8192

#define DEV __device__ __forceinline__

typedef __attribute__((ext_vector_type(4))) float f32x4;
typedef __attribute__((ext_vector_type(8))) __bf16 bf16x8;
typedef __attribute__((ext_vector_type(4))) __bf16 bf16x4;

typedef const __attribute__((address_space(1))) uint32_t* gas1_t;
typedef __attribute__((address_space(3))) uint32_t* las3_t;

DEV void gload_lds16(const void* g, void* l) {
  __builtin_amdgcn_global_load_lds((gas1_t)g, (las3_t)l, 16, 0, 0);
}

DEV float sgm(float x) { return 1.f / (1.f + __expf(-x)); }

template <int CTRL>
DEV float dpp_mov(float x) {
  return __builtin_bit_cast(
      float, __builtin_amdgcn_mov_dpp(__builtin_bit_cast(int, x), CTRL, 0xF, 0xF, true));
}
// cyclic rotate-reduce: sum over each 16-lane DPP row
DEV float row16_reduce(float x) {
  x += dpp_mov<0x121>(x);  // row_ror:1
  x += dpp_mov<0x122>(x);  // row_ror:2
  x += dpp_mov<0x124>(x);  // row_ror:4
  x += dpp_mov<0x128>(x);  // row_ror:8
  return x;
}

// ---- swizzled LDS helpers (row-major bf16 tiles; XOR bank swizzle) ----
DEV int swzb(int row, int col, int stride) {  // byte offset
  return ((row * stride + col) << 1) ^ ((row & 7) << 4);
}
DEV bf16x8 ldfrag(const __bf16* B, int row, int col, int stride) {
  return *(const bf16x8*)((const char*)B + swzb(row, col, stride));
}
DEV __bf16 ldsc(const __bf16* B, int row, int col, int stride) {
  return *(const __bf16*)((const char*)B + swzb(row, col, stride));
}
DEV void stb(__bf16* B, int row, int col, int stride, __bf16 v) {
  *(__bf16*)((char*)B + swzb(row, col, stride)) = v;
}
DEV void stb4(__bf16* B, int row, int c4, int stride, bf16x4 v) {
  *(bf16x4*)((char*)B + swzb(row, c4, stride)) = v;
}
// packed-lower tile offsets: row tr holds tiles 0..tr (+1 zero pad for even tr)
DEV int goffn(int tr) {
  int m = tr >> 1;
  return (tr & 1) ? (2 * m * m + 4 * m + 2) : (2 * m * m + 2 * m);
}
DEV int stile(int tr, int sc) { return ((tr * (tr + 1)) / 2 + sc) * 256; }

// ---------------- casts ----------------
__global__ __launch_bounds__(256) void cast_f32_bf16(const float* __restrict__ in,
                                                     __bf16* __restrict__ out) {
  int idx = blockIdx.x * 256 + threadIdx.x;
  float4 v = ((const float4*)in)[idx];
  bf16x4 o;
  o[0] = (__bf16)v.x; o[1] = (__bf16)v.y; o[2] = (__bf16)v.z; o[3] = (__bf16)v.w;
  ((bf16x4*)out)[idx] = o;
}

__global__ __launch_bounds__(256) void transpose_cast(const float* __restrict__ W,
                                                      __bf16* __restrict__ Wt) {
  __shared__ float tile[32][33];
  int tx = threadIdx.x & 31, ty = threadIdx.x >> 5;
  int n0 = blockIdx.x * 32, k0 = blockIdx.y * 32;
#pragma unroll
  for (int u = 0; u < 4; ++u)
    tile[ty + u * 8][tx] = W[(size_t)(k0 + ty + u * 8) * 1024 + n0 + tx];
  __syncthreads();
#pragma unroll
  for (int u = 0; u < 4; ++u)
    Wt[(size_t)(n0 + ty + u * 8) * 1024 + k0 + tx] = (__bf16)tile[tx][ty + u * 8];
}

// ---------------- GEMM: C[M=8192,N=1024] = A[M,K=1024] * Bt[N,K]^T ----------------
// mode 0: fp32 C row-major [M,1024]. mode 1: bf16 scatter to [B,H,T,D]
__global__ __launch_bounds__(256) void gemm_bt(const __bf16* __restrict__ A,
                                               const __bf16* __restrict__ Bt,
                                               float* __restrict__ Cf,
                                               __bf16* __restrict__ Cb, int mode) {
  const int t = threadIdx.x;
  const int wv = t >> 6, lane = t & 63;
  const int bm = blockIdx.y, bn = blockIdx.x;
  const int K = 1024;
  __shared__ __bf16 lA[4096];
  __shared__ __bf16 lB[4096];
  f32x4 acc[4][4];
#pragma unroll
  for (int m = 0; m < 4; ++m)
#pragma unroll
    for (int n = 0; n < 4; ++n) acc[m][n] = 0.f;
  const int wr = wv >> 1, wc = wv & 1;
  const int fr = lane & 15, fk = (lane >> 4) * 8;
  const int e0 = (wv * 128 + lane) * 8;
  const int e1 = (wv * 128 + 64 + lane) * 8;
  const int r0s = e0 >> 5, c0s = e0 & 31;
  const int r1s = e1 >> 5, c1s = e1 & 31;
  for (int k0 = 0; k0 < K; k0 += 32) {
    gload_lds16(A + (size_t)(bm * 128 + r0s) * K + k0 + c0s, lA + wv * 1024);
    gload_lds16(Bt + (size_t)(bn * 128 + r0s) * K + k0 + c0s, lB + wv * 1024);
    gload_lds16(A + (size_t)(bm * 128 + r1s) * K + k0 + c1s, lA + wv * 1024 + 512);
    gload_lds16(Bt + (size_t)(bn * 128 + r1s) * K + k0 + c1s, lB + wv * 1024 + 512);
    __syncthreads();
    bf16x8 af[4], bg[4];
#pragma unroll
    for (int m = 0; m < 4; ++m)
      af[m] = *(const bf16x8*)(lA + (wr * 64 + m * 16 + fr) * 32 + fk);
#pragma unroll
    for (int n = 0; n < 4; ++n)
      bg[n] = *(const bf16x8*)(lB + (wc * 64 + n * 16 + fr) * 32 + fk);
#pragma unroll
    for (int m = 0; m < 4; ++m)
#pragma unroll
      for (int n = 0; n < 4; ++n)
        acc[m][n] = __builtin_amdgcn_mfma_f32_16x16x32_bf16(af[m], bg[n], acc[m][n], 0, 0, 0);
    __syncthreads();
  }
  const int rr = (lane >> 4) * 4, cl = lane & 15;
#pragma unroll
  for (int m = 0; m < 4; ++m) {
#pragma unroll
    for (int n = 0; n < 4; ++n) {
#pragma unroll
      for (int rg = 0; rg < 4; ++rg) {
        int row = bm * 128 + wr * 64 + m * 16 + rr + rg;
        int col = bn * 128 + wc * 64 + n * 16 + cl;
        float val = acc[m][n][rg];
        if (mode == 0) {
          Cf[(size_t)row * 1024 + col] = val;
        } else {
          int b = row >> 11, tk = row & 2047;
          int h = col >> 6, d = col & 63;
          Cb[(((size_t)b * 16 + h) * 2048 + tk) * 64 + d] = (__bf16)val;
        }
      }
    }
  }
}

// ---------------- fused WY solve + A/B (right-looking, register-resident) ----
// LDS 66 KB -> 2 blocks/CU. Wave w owns rows w*16..+15 of U,W in C/D regs.
// Emits: U,W bf16 [t][d]; AT = (I - a*U^T K)^T bf16 PRE-SWIZZLED; B = W^T K fp32.
__global__ __launch_bounds__(512, 4) void wy_ab(const __bf16* __restrict__ kb,
                                                const __bf16* __restrict__ vb,
                                                const float* __restrict__ ar,
                                                const float* __restrict__ br,
                                                __bf16* __restrict__ Ug,
                                                __bf16* __restrict__ Wgb,
                                                __bf16* __restrict__ ATg,
                                                float* __restrict__ Bop) {
  int n = blockIdx.x, h = (n >> 4) & 15;
  float a = sgm(ar[h]) * 0.5f;
  float b = sgm(br[h]) * 0.5f;
  int t = threadIdx.x, wid = t >> 6, lane = t & 63;
  int fr = lane & 15, fkq = lane >> 4, fk = fkq * 8;
  __shared__ __attribute__((aligned(16))) char pool[67584];
  __bf16* Ks  = (__bf16*)pool;            // [128][64] swz; dead after init
  __bf16* MTu = (__bf16*)pool;            // [64][128] swz == U^T (overlays Ks)
  __bf16* KT  = (__bf16*)(pool + 16384);  // [64][128] swz
  __bf16* MTw = (__bf16*)(pool + 32768);  // [64][128] swz == W^T
  __bf16* Sng = (__bf16*)(pool + 49152);  // 36 packed-lower 16x16 bf16 tiles
  const __bf16* kg = kb + (size_t)n * 8192;
  const __bf16* vg = vb + (size_t)n * 8192;
  // stage: normalize k -> Ks + KT
#pragma unroll
  for (int it = 0; it < 4; ++it) {
    int u = it * 512 + t;
    int row = u >> 4, c4 = (u & 15) * 4;
    bf16x4 kh = ((const bf16x4*)kg)[u];
    float kf[4];
#pragma unroll
    for (int e = 0; e < 4; ++e) kf[e] = (float)kh[e];
    float ssq = kf[0] * kf[0] + kf[1] * kf[1] + kf[2] * kf[2] + kf[3] * kf[3];
    ssq = row16_reduce(ssq);
    float inv = 1.f / fmaxf(sqrtf(ssq), 1e-12f);
    bf16x4 kn;
#pragma unroll
    for (int e = 0; e < 4; ++e) kn[e] = (__bf16)(kf[e] * inv);
    stb4(Ks, row, c4, 64, kn);
#pragma unroll
    for (int e = 0; e < 4; ++e) stb(KT, c4 + e, row, 128, kn[e]);
  }
  __syncthreads();
  // S_neg = -(a * tril(KK^T)) packed-lower bf16 (diag tiles: col>=row -> 0)
  for (int p = wid; p < 36; p += 8) {
    int tr = 0, pp = p;
    while (pp > tr) { pp -= (tr + 1); ++tr; }
    int sc = pp;
    f32x4 acc = {0.f, 0.f, 0.f, 0.f};
#pragma unroll
    for (int ks = 0; ks < 2; ++ks)
      acc = __builtin_amdgcn_mfma_f32_16x16x32_bf16(
          ldfrag(Ks, tr * 16 + fr, ks * 32 + fk, 64),
          ldfrag(Ks, sc * 16 + fr, ks * 32 + fk, 64), acc, 0, 0, 0);
    __bf16* dst = Sng + stile(tr, sc);
#pragma unroll
    for (int rg = 0; rg < 4; ++rg) {
      int r = fkq * 4 + rg;
      float v = -a * acc[rg];
      if (tr == sc && fr >= r) v = 0.f;
      dst[r * 16 + fr] = (__bf16)v;
    }
  }
  // U,W init in C/D-layout registers (Ks reads complete before MT overlays it)
  f32x4 U[4], W[4];
#pragma unroll
  for (int ct = 0; ct < 4; ++ct) {
#pragma unroll
    for (int rg = 0; rg < 4; ++rg) {
      int row = wid * 16 + fkq * 4 + rg, col = ct * 16 + fr;
      U[ct][rg] = (float)ldsc(Ks, row, col, 64);
      W[ct][rg] = b * (float)vg[row * 64 + col];
    }
  }
  __syncthreads();
  // right-looking substitution: stage bb = {wave bb solves + writes MT;
  // barrier; waves w>bb apply rank-16 MFMA update in parallel}
  bf16x8 zz;
#pragma unroll
  for (int e = 0; e < 8; ++e) zz[e] = (__bf16)0.f;
  for (int bb = 0; bb < 8; ++bb) {
    if (wid == bb) {
      // diagonal 15-step solve via shfl row broadcasts (pure registers)
      const __bf16* Sd = Sng + stile(bb, bb);
#pragma unroll
      for (int s = 0; s < 15; ++s) {
        const int sq = s >> 2, sr = s & 3;
        float bu_c[4], bw_c[4];
#pragma unroll
        for (int ct = 0; ct < 4; ++ct) bu_c[ct] = __shfl(U[ct][sr], sq * 16 + fr, 64);
#pragma unroll
        for (int ct = 0; ct < 4; ++ct) bw_c[ct] = __shfl(W[ct][sr], sq * 16 + fr, 64);
        float sv[4];
#pragma unroll
        for (int rg = 0; rg < 4; ++rg) sv[rg] = (float)Sd[(fkq * 4 + rg) * 16 + s];
#pragma unroll
        for (int ct = 0; ct < 4; ++ct)
#pragma unroll
          for (int rg = 0; rg < 4; ++rg)
            if (fkq * 4 + rg > s) {
              U[ct][rg] += sv[rg] * bu_c[ct];
              W[ct][rg] += sv[rg] * bw_c[ct];
            }
      }
      // append my solved rows to MT (bf16)
#pragma unroll
      for (int ct = 0; ct < 4; ++ct) {
        bf16x4 uu, ww;
#pragma unroll
        for (int rg = 0; rg < 4; ++rg) {
          uu[rg] = (__bf16)U[ct][rg];
          ww[rg] = (__bf16)W[ct][rg];
        }
        stb4(MTu, ct * 16 + fr, bb * 16 + fkq * 4, 128, uu);
        stb4(MTw, ct * 16 + fr, bb * 16 + fkq * 4, 128, ww);
      }
    }
    __syncthreads();
    if (wid > bb) {
      // rank-16 update via K=16 zero-padded MFMA (zeros on BOTH operands k>=16)
      bf16x8 af = zz;
      if (fk < 16) af = *(const bf16x8*)(Sng + stile(wid, bb) + fr * 16 + fk);
#pragma unroll
      for (int ct = 0; ct < 4; ++ct) {
        bf16x8 bu = zz, bw = zz;
        if (fk < 16) {
          bu = ldfrag(MTu, ct * 16 + fr, bb * 16 + fk, 128);
          bw = ldfrag(MTw, ct * 16 + fr, bb * 16 + fk, 128);
        }
        U[ct] = __builtin_amdgcn_mfma_f32_16x16x32_bf16(af, bu, U[ct], 0, 0, 0);
        W[ct] = __builtin_amdgcn_mfma_f32_16x16x32_bf16(af, bw, W[ct], 0, 0, 0);
      }
    }
  }
  // global bf16 write of U,W in [t][d] layout, straight from registers
  __bf16* ugo = Ug + (size_t)n * 8192;
  __bf16* wgo = Wgb + (size_t)n * 8192;
#pragma unroll
  for (int ct = 0; ct < 4; ++ct)
#pragma unroll
    for (int rg = 0; rg < 4; ++rg) {
      int row = wid * 16 + fkq * 4 + rg, col = ct * 16 + fr;
      ugo[row * 64 + col] = (__bf16)U[ct][rg];
      wgo[row * 64 + col] = (__bf16)W[ct][rg];
    }
  // AT = I - a*(K^T U)  (pre-swizzled bf16), B = W^T K (fp32)
#pragma unroll
  for (int q = 0; q < 4; ++q) {
    int tile = wid + q * 8;  // 0-15 -> AT, 16-31 -> B
    int mat = tile >> 4;
    int ti = (tile >> 2) & 3, tj = tile & 3;
    f32x4 acc = {0.f, 0.f, 0.f, 0.f};
    if (mat == 0) {
#pragma unroll
      for (int ks = 0; ks < 4; ++ks)
        acc = __builtin_amdgcn_mfma_f32_16x16x32_bf16(
            ldfrag(KT, ti * 16 + fr, ks * 32 + fk, 128),
            ldfrag(MTu, tj * 16 + fr, ks * 32 + fk, 128), acc, 0, 0, 0);
      char* dst = (char*)(ATg + (size_t)n * 4096);
#pragma unroll
      for (int rg = 0; rg < 4; ++rg) {
        int i = ti * 16 + fkq * 4 + rg, j = tj * 16 + fr;
        float v = (i == j ? 1.f : 0.f) - a * acc[rg];
        *(__bf16*)(dst + swzb(i, j, 64)) = (__bf16)v;
      }
    } else {
#pragma unroll
      for (int ks = 0; ks < 4; ++ks)
        acc = __builtin_amdgcn_mfma_f32_16x16x32_bf16(
            ldfrag(MTw, ti * 16 + fr, ks * 32 + fk, 128),
            ldfrag(KT, tj * 16 + fr, ks * 32 + fk, 128), acc, 0, 0, 0);
      float* dst = Bop + (size_t)n * 4096;
#pragma unroll
      for (int rg = 0; rg < 4; ++rg)
        dst[(ti * 16 + fkq * 4 + rg) * 64 + tj * 16 + fr] = acc[rg];
    }
  }
}

// ---------------- inter-chunk scan (MFMA) ----------------
// 64 blocks (one per (b,h)), 8 waves. Wave w owns M tiles (ti=w&3, tj=(w>>2)*2+{0,1}).
// Per step: Mstart[c] <- M (bf16); Mh/Ml <- M; acc = B + (Mh+Ml)·AT^T via MFMA.
__global__ __launch_bounds__(512) void chunk_scan(const __bf16* __restrict__ ATg,
                                                  const float* __restrict__ Bop,
                                                  __bf16* __restrict__ Mst,
                                                  float* __restrict__ Mfinal) {
  int bh = blockIdx.x;
  int t = threadIdx.x, wid = t >> 6, lane = t & 63;
  int fr = lane & 15, fkq = lane >> 4, fk = fkq * 8;
  int ti = wid & 3, tj0 = (wid >> 2) << 1;
  __shared__ __bf16 Mh[4096];    // [64][64] swz
  __shared__ __bf16 Ml[4096];    // [64][64] swz
  __shared__ __bf16 At[2][4096]; // [64][64], pre-swizzled via linear gload_lds
  f32x4 acc[2];
  acc[0] = 0.f;
  acc[1] = 0.f;
  // prefetch AT chunk 0 (8 KB: one 16B load per thread)
  gload_lds16(ATg + (size_t)bh * 16 * 4096 + t * 8, At[0] + t * 8);
  for (int c = 0; c < 16; ++c) {
    int cur = c & 1;
    if (c < 15)
      gload_lds16(ATg + ((size_t)(bh * 16 + c + 1)) * 4096 + t * 8,
                  At[cur ^ 1] + t * 8);
    // Mstart[c] = M (bf16); stage M hi/lo into LDS
    __bf16* mstc = Mst + ((size_t)(bh * 16 + c)) * 4096;
#pragma unroll
    for (int p = 0; p < 2; ++p) {
      int tj = tj0 + p;
#pragma unroll
      for (int rg = 0; rg < 4; ++rg) {
        int row = ti * 16 + fkq * 4 + rg, col = tj * 16 + fr;
        float v = acc[p][rg];
        __bf16 hi = (__bf16)v;
        mstc[row * 64 + col] = hi;
        stb(Mh, row, col, 64, hi);
        stb(Ml, row, col, 64, (__bf16)(v - (float)hi));
      }
    }
    __syncthreads();  // Mh/Ml visible; At[cur] loads drained
    size_t bb = ((size_t)(bh * 16 + c)) * 4096;
#pragma unroll
    for (int p = 0; p < 2; ++p) {
      int tj = tj0 + p;
      f32x4 na;
#pragma unroll
      for (int rg = 0; rg < 4; ++rg)
        na[rg] = Bop[bb + (ti * 16 + fkq * 4 + rg) * 64 + tj * 16 + fr];
#pragma unroll
      for (int ks = 0; ks < 2; ++ks) {
        bf16x8 bfrag = ldfrag(At[cur], tj * 16 + fr, ks * 32 + fk, 64);
        bf16x8 ah = ldfrag(Mh, ti * 16 + fr, ks * 32 + fk, 64);
        bf16x8 al = ldfrag(Ml, ti * 16 + fr, ks * 32 + fk, 64);
        na = __builtin_amdgcn_mfma_f32_16x16x32_bf16(ah, bfrag, na, 0, 0, 0);
        na = __builtin_amdgcn_mfma_f32_16x16x32_bf16(al, bfrag, na, 0, 0, 0);
      }
      acc[p] = na;
    }
    __syncthreads();  // all reads of Mh/Ml/At[cur] done before next overwrite
  }
  // M_final (fp32 output)
#pragma unroll
  for (int p = 0; p < 2; ++p) {
    int tj = tj0 + p;
#pragma unroll
    for (int rg = 0; rg < 4; ++rg)
      Mfinal[(size_t)bh * 4096 + (ti * 16 + fkq * 4 + rg) * 64 + tj * 16 + fr] =
          acc[p][rg];
  }
}

// ---------------- Y assembly (plain bf16) ----------------
__global__ __launch_bounds__(512, 4) void y_assemble(const __bf16* __restrict__ qb,
                                                     const __bf16* __restrict__ kb,
                                                     const __bf16* __restrict__ Ug,
                                                     const __bf16* __restrict__ Wgb,
                                                     const __bf16* __restrict__ Mst,
                                                     const float* __restrict__ ar,
                                                     __bf16* __restrict__ ybf) {
  int n = blockIdx.x, h = (n >> 4) & 15, b = n >> 8, c = n & 15;
  float a = sgm(ar[h]) * 0.5f;
  int t = threadIdx.x, wid = t >> 6, lane = t & 63;
  int fr = lane & 15, fk = (lane >> 4) * 8;
  __shared__ __bf16 Qs[8192];    // [128][64] swz
  __shared__ __bf16 Rs[8192];    // [128][64] swz: K then U
  __shared__ __bf16 M0s[4096];   // [64][64] swz
  __shared__ __bf16 Gs[10240];   // 40 packed 16x16 tiles
  __shared__ __bf16 WtT[8192];   // [64][128] swz
  const __bf16* qg = qb + (size_t)n * 8192;
  const __bf16* kg = kb + (size_t)n * 8192;
  const __bf16* mg = Mst + (size_t)n * 4096;
#pragma unroll
  for (int it = 0; it < 4; ++it) {
    int u = it * 512 + t;
    int row = u >> 4, c4 = (u & 15) * 4;
    stb4(Qs, row, c4, 64, ((const bf16x4*)qg)[u]);
    bf16x4 kh = ((const bf16x4*)kg)[u];
    float kf[4];
#pragma unroll
    for (int e = 0; e < 4; ++e) kf[e] = (float)kh[e];
    float ssq = kf[0] * kf[0] + kf[1] * kf[1] + kf[2] * kf[2] + kf[3] * kf[3];
    ssq = row16_reduce(ssq);
    float inv = 1.f / fmaxf(sqrtf(ssq), 1e-12f);
    bf16x4 kn;
#pragma unroll
    for (int e = 0; e < 4; ++e) kn[e] = (__bf16)(kf[e] * inv);
    stb4(Rs, row, c4, 64, kn);
  }
#pragma unroll
  for (int it = 0; it < 2; ++it) {
    int u = it * 512 + t;
    int row = u >> 4, c4 = (u & 15) * 4;
    stb4(M0s, row, c4, 64, ((const bf16x4*)mg)[u]);
  }
#pragma unroll
  for (int pz = 0; pz < 2; ++pz) {
    int e = pz * 512 + t;
    int m = e >> 8, idx = e & 255;
    Gs[(2 * m * m + 4 * m + 1) * 256 + idx] = (__bf16)0.f;
  }
  __syncthreads();
  // P1: G = tril(Q K^T, -1), packed-lower bf16
  for (int p = wid; p < 36; p += 8) {
    int tr = 0, pp = p;
    while (pp > tr) { pp -= (tr + 1); ++tr; }
    int sc = pp;
    f32x4 acc = {0.f, 0.f, 0.f, 0.f};
#pragma unroll
    for (int ks = 0; ks < 2; ++ks)
      acc = __builtin_amdgcn_mfma_f32_16x16x32_bf16(
          ldfrag(Qs, tr * 16 + fr, ks * 32 + fk, 64),
          ldfrag(Rs, sc * 16 + fr, ks * 32 + fk, 64), acc, 0, 0, 0);
    int row0 = (lane >> 4) * 4, col = lane & 15;
    __bf16* gt = Gs + (goffn(tr) + sc) * 256;
#pragma unroll
    for (int rg = 0; rg < 4; ++rg) {
      int r = row0 + rg;
      float v = acc[rg];
      if (tr == sc && col >= r) v = 0.f;
      gt[r * 16 + col] = (__bf16)v;
    }
  }
  __syncthreads();
  // P2: restage Rs <- U
  const __bf16* ug = Ug + (size_t)n * 8192;
  const __bf16* wg = Wgb + (size_t)n * 8192;
#pragma unroll
  for (int it = 0; it < 4; ++it) {
    int u = it * 512 + t;
    int row = u >> 4, c4 = (u & 15) * 4;
    stb4(Rs, row, c4, 64, ((const bf16x4*)ug)[u]);
  }
  __syncthreads();
  // P3: WtT[i][s] = W[s][i] - a*(U M0^T)[s][i]
#pragma unroll
  for (int q = 0; q < 4; ++q) {
    int tile = wid + q * 8;
    int ti = tile >> 2, tj = tile & 3;
    f32x4 acc = {0.f, 0.f, 0.f, 0.f};
#pragma unroll
    for (int ks = 0; ks < 2; ++ks)
      acc = __builtin_amdgcn_mfma_f32_16x16x32_bf16(
          ldfrag(Rs, ti * 16 + fr, ks * 32 + fk, 64),
          ldfrag(M0s, tj * 16 + fr, ks * 32 + fk, 64), acc, 0, 0, 0);
    int row0 = (lane >> 4) * 4, col = lane & 15;
#pragma unroll
    for (int rg = 0; rg < 4; ++rg) {
      int s = ti * 16 + row0 + rg, i = tj * 16 + col;
      float wv = (float)wg[s * 64 + i];
      stb(WtT, i, s, 128, (__bf16)(wv - a * acc[rg]));
    }
  }
  __syncthreads();
  // P4: Y = Q M0^T + G Wt
  __bf16* yg = ybf + ((size_t)(b * 2048 + c * 128)) * 1024 + h * 64;
#pragma unroll
  for (int q = 0; q < 4; ++q) {
    int tile = wid + q * 8;
    int ti = tile >> 2, tj = tile & 3;
    f32x4 acc = {0.f, 0.f, 0.f, 0.f};
#pragma unroll
    for (int ks = 0; ks < 2; ++ks)
      acc = __builtin_amdgcn_mfma_f32_16x16x32_bf16(
          ldfrag(Qs, ti * 16 + fr, ks * 32 + fk, 64),
          ldfrag(M0s, tj * 16 + fr, ks * 32 + fk, 64), acc, 0, 0, 0);
    int goffv = goffn(ti);
    int np = (ti + 2) >> 1;
    for (int ks = 0; ks < np; ++ks) {
      int gtile = goffv + ks * 2 + (fk >> 4);
      bf16x8 af = *(const bf16x8*)(Gs + gtile * 256 + fr * 16 + (fk & 15));
      acc = __builtin_amdgcn_mfma_f32_16x16x32_bf16(
          af, ldfrag(WtT, tj * 16 + fr, ks * 32 + fk, 128), acc, 0, 0, 0);
    }
    int row0 = (lane >> 4) * 4, col = lane & 15;
#pragma unroll
    for (int rg = 0; rg < 4; ++rg) {
      int tt = ti * 16 + row0 + rg, d = tj * 16 + col;
      yg[(size_t)tt * 1024 + d] = (__bf16)acc[rg];
    }
  }
}

extern "C" void kernel_launch(void* const* d_in, const int* in_sizes, int n_in,
                              void* d_out, int out_size, void* d_ws, size_t ws_size,
                              hipStream_t stream) {
  const float* x  = (const float*)d_in[0];
  const float* Wq = (const float*)d_in[1];
  const float* Wk = (const float*)d_in[2];
  const float* Wv = (const float*)d_in[3];
  const float* Wo = (const float*)d_in[4];
  const float* ar = (const float*)d_in[5];
  const float* br = (const float*)d_in[6];

  char* ws = (char*)d_ws;
  __bf16* xb  = (__bf16*)ws;                       // 16.8 MB, reused as ybf
  __bf16* ybf = xb;
  __bf16* wqt = (__bf16*)(ws + (17u << 20));       // 2 MB each
  __bf16* wkt = wqt + (1u << 20);
  __bf16* wvt = wkt + (1u << 20);
  __bf16* wot = wvt + (1u << 20);
  __bf16* qb  = (__bf16*)(ws + (25u << 20));       // 16.8 MB bf16 each
  __bf16* kb  = (__bf16*)(ws + (42u << 20));
  __bf16* vb  = (__bf16*)(ws + (59u << 20));
  __bf16* Ugb = (__bf16*)(ws + (76u << 20));
  __bf16* Wgb = (__bf16*)(ws + (93u << 20));
  __bf16* ATg = (__bf16*)(ws + (110u << 20));      // 8.4 MB bf16 (pre-swizzled)
  float* Bop  = (float*)(ws + (127u << 20));       // 16.8 MB fp32
  __bf16* Mst = (__bf16*)(ws + (144u << 20));      // 8.4 MB bf16

  float* yout = (float*)d_out;                     // [8192,1024] f32
  float* Mfin = yout + 8388608;

  cast_f32_bf16<<<8192, 256, 0, stream>>>(x, xb);
  dim3 tg(32, 32);
  transpose_cast<<<tg, 256, 0, stream>>>(Wq, wqt);
  transpose_cast<<<tg, 256, 0, stream>>>(Wk, wkt);
  transpose_cast<<<tg, 256, 0, stream>>>(Wv, wvt);
  transpose_cast<<<tg, 256, 0, stream>>>(Wo, wot);

  dim3 gg(8, 64);
  gemm_bt<<<gg, 256, 0, stream>>>(xb, wqt, nullptr, qb, 1);
  gemm_bt<<<gg, 256, 0, stream>>>(xb, wkt, nullptr, kb, 1);
  gemm_bt<<<gg, 256, 0, stream>>>(xb, wvt, nullptr, vb, 1);

  wy_ab<<<1024, 512, 0, stream>>>(kb, vb, ar, br, Ugb, Wgb, ATg, Bop);
  chunk_scan<<<64, 512, 0, stream>>>(ATg, Bop, Mst, Mfin);
  y_assemble<<<1024, 512, 0, stream>>>(qb, kb, Ugb, Wgb, Mst, ar, ybf);

  gemm_bt<<<gg, 256, 0, stream>>>(ybf, wot, yout, nullptr, 0);
}

// Round 11
// 223.260 us; speedup vs baseline: 2.2722x; 1.1402x over previous
//
#include <hip/hip_runtime.h>
#include <stdint.h>

// Titans-L2 chunked delta-rule forward — WY reformulation, MFMA everywhere.
//   1. cast x -> bf16; transpose+cast Wq/Wk/Wv/Wo -> bf16 [N,K]
//   2. MFMA GEMMs: q,k,v = x@W  (written DIRECTLY as bf16 [B,H,T,D])
//   3. wy_ab (per chunk): normalize k; S_neg = -a*tril(KK^T,-1) bf16 tiles;
//      PARALLEL Neumann-doubling diag inverses: inv(I-N)=(I+N)(I+N^2)(I+N^4)(I+N^8)
//      (6 MFMAs/wave, all 8 waves concurrent; inv overwrites Sng diag slots);
//      right-looking substitution: stage bb = {wave bb: stage rhs -> MT,
//      x = inv*rhs via MFMA, rewrite; barrier; waves>bb rank-16 MFMA update};
//      KT built late over dead Sng from register-held k; U,W stored from regs;
//      emits A^T = I - a*K^T U PRE-SWIZZLED bf16; B = W^T K fp32.
//   4. chunk_scan (MFMA): per (b,h), M_{c+1} = M_c A_c + B_c, M hi/lo bf16 LDS.
//   5. y_assemble: G = tril(QK^T,-1); Wt = W - a*(U M0^T); Y = Q M0^T + G Wt.
//   6. final MFMA GEMM y@Wo -> d_out (fp32)
// Dims: B=4 H=16 T=2048 C=1024 D=64 CS=128 nc=16 N=1024 tokens=8192

#define DEV __device__ __forceinline__

typedef __attribute__((ext_vector_type(4))) float f32x4;
typedef __attribute__((ext_vector_type(8))) __bf16 bf16x8;
typedef __attribute__((ext_vector_type(4))) __bf16 bf16x4;

typedef const __attribute__((address_space(1))) uint32_t* gas1_t;
typedef __attribute__((address_space(3))) uint32_t* las3_t;

DEV void gload_lds16(const void* g, void* l) {
  __builtin_amdgcn_global_load_lds((gas1_t)g, (las3_t)l, 16, 0, 0);
}

DEV float sgm(float x) { return 1.f / (1.f + __expf(-x)); }

template <int CTRL>
DEV float dpp_mov(float x) {
  return __builtin_bit_cast(
      float, __builtin_amdgcn_mov_dpp(__builtin_bit_cast(int, x), CTRL, 0xF, 0xF, true));
}
// cyclic rotate-reduce: sum over each 16-lane DPP row
DEV float row16_reduce(float x) {
  x += dpp_mov<0x121>(x);  // row_ror:1
  x += dpp_mov<0x122>(x);  // row_ror:2
  x += dpp_mov<0x124>(x);  // row_ror:4
  x += dpp_mov<0x128>(x);  // row_ror:8
  return x;
}

// ---- swizzled LDS helpers (row-major bf16 tiles; XOR bank swizzle) ----
DEV int swzb(int row, int col, int stride) {  // byte offset
  return ((row * stride + col) << 1) ^ ((row & 7) << 4);
}
DEV bf16x8 ldfrag(const __bf16* B, int row, int col, int stride) {
  return *(const bf16x8*)((const char*)B + swzb(row, col, stride));
}
DEV __bf16 ldsc(const __bf16* B, int row, int col, int stride) {
  return *(const __bf16*)((const char*)B + swzb(row, col, stride));
}
DEV void stb(__bf16* B, int row, int col, int stride, __bf16 v) {
  *(__bf16*)((char*)B + swzb(row, col, stride)) = v;
}
DEV void stb4(__bf16* B, int row, int c4, int stride, bf16x4 v) {
  *(bf16x4*)((char*)B + swzb(row, c4, stride)) = v;
}
// packed-lower tile offsets: row tr holds tiles 0..tr (+1 zero pad for even tr)
DEV int goffn(int tr) {
  int m = tr >> 1;
  return (tr & 1) ? (2 * m * m + 4 * m + 2) : (2 * m * m + 2 * m);
}
DEV int stile(int tr, int sc) { return ((tr * (tr + 1)) / 2 + sc) * 256; }

// ---------------- casts ----------------
__global__ __launch_bounds__(256) void cast_f32_bf16(const float* __restrict__ in,
                                                     __bf16* __restrict__ out) {
  int idx = blockIdx.x * 256 + threadIdx.x;
  float4 v = ((const float4*)in)[idx];
  bf16x4 o;
  o[0] = (__bf16)v.x; o[1] = (__bf16)v.y; o[2] = (__bf16)v.z; o[3] = (__bf16)v.w;
  ((bf16x4*)out)[idx] = o;
}

__global__ __launch_bounds__(256) void transpose_cast(const float* __restrict__ W,
                                                      __bf16* __restrict__ Wt) {
  __shared__ float tile[32][33];
  int tx = threadIdx.x & 31, ty = threadIdx.x >> 5;
  int n0 = blockIdx.x * 32, k0 = blockIdx.y * 32;
#pragma unroll
  for (int u = 0; u < 4; ++u)
    tile[ty + u * 8][tx] = W[(size_t)(k0 + ty + u * 8) * 1024 + n0 + tx];
  __syncthreads();
#pragma unroll
  for (int u = 0; u < 4; ++u)
    Wt[(size_t)(n0 + ty + u * 8) * 1024 + k0 + tx] = (__bf16)tile[tx][ty + u * 8];
}

// ---------------- GEMM: C[M=8192,N=1024] = A[M,K=1024] * Bt[N,K]^T ----------------
// mode 0: fp32 C row-major [M,1024]. mode 1: bf16 scatter to [B,H,T,D]
__global__ __launch_bounds__(256) void gemm_bt(const __bf16* __restrict__ A,
                                               const __bf16* __restrict__ Bt,
                                               float* __restrict__ Cf,
                                               __bf16* __restrict__ Cb, int mode) {
  const int t = threadIdx.x;
  const int wv = t >> 6, lane = t & 63;
  const int bm = blockIdx.y, bn = blockIdx.x;
  const int K = 1024;
  __shared__ __bf16 lA[4096];
  __shared__ __bf16 lB[4096];
  f32x4 acc[4][4];
#pragma unroll
  for (int m = 0; m < 4; ++m)
#pragma unroll
    for (int n = 0; n < 4; ++n) acc[m][n] = 0.f;
  const int wr = wv >> 1, wc = wv & 1;
  const int fr = lane & 15, fk = (lane >> 4) * 8;
  const int e0 = (wv * 128 + lane) * 8;
  const int e1 = (wv * 128 + 64 + lane) * 8;
  const int r0s = e0 >> 5, c0s = e0 & 31;
  const int r1s = e1 >> 5, c1s = e1 & 31;
  for (int k0 = 0; k0 < K; k0 += 32) {
    gload_lds16(A + (size_t)(bm * 128 + r0s) * K + k0 + c0s, lA + wv * 1024);
    gload_lds16(Bt + (size_t)(bn * 128 + r0s) * K + k0 + c0s, lB + wv * 1024);
    gload_lds16(A + (size_t)(bm * 128 + r1s) * K + k0 + c1s, lA + wv * 1024 + 512);
    gload_lds16(Bt + (size_t)(bn * 128 + r1s) * K + k0 + c1s, lB + wv * 1024 + 512);
    __syncthreads();
    bf16x8 af[4], bg[4];
#pragma unroll
    for (int m = 0; m < 4; ++m)
      af[m] = *(const bf16x8*)(lA + (wr * 64 + m * 16 + fr) * 32 + fk);
#pragma unroll
    for (int n = 0; n < 4; ++n)
      bg[n] = *(const bf16x8*)(lB + (wc * 64 + n * 16 + fr) * 32 + fk);
#pragma unroll
    for (int m = 0; m < 4; ++m)
#pragma unroll
      for (int n = 0; n < 4; ++n)
        acc[m][n] = __builtin_amdgcn_mfma_f32_16x16x32_bf16(af[m], bg[n], acc[m][n], 0, 0, 0);
    __syncthreads();
  }
  const int rr = (lane >> 4) * 4, cl = lane & 15;
#pragma unroll
  for (int m = 0; m < 4; ++m) {
#pragma unroll
    for (int n = 0; n < 4; ++n) {
#pragma unroll
      for (int rg = 0; rg < 4; ++rg) {
        int row = bm * 128 + wr * 64 + m * 16 + rr + rg;
        int col = bn * 128 + wc * 64 + n * 16 + cl;
        float val = acc[m][n][rg];
        if (mode == 0) {
          Cf[(size_t)row * 1024 + col] = val;
        } else {
          int b = row >> 11, tk = row & 2047;
          int h = col >> 6, d = col & 63;
          Cb[(((size_t)b * 16 + h) * 2048 + tk) * 64 + d] = (__bf16)val;
        }
      }
    }
  }
}

// ---------------- fused WY solve + A/B (doubling inverse, register-resident) ----
// LDS 51.2 KB -> 3 blocks/CU. Wave w owns rows w*16..+15 of U,W in C/D regs.
__global__ __launch_bounds__(512, 6) void wy_ab(const __bf16* __restrict__ kb,
                                                const __bf16* __restrict__ vb,
                                                const float* __restrict__ ar,
                                                const float* __restrict__ br,
                                                __bf16* __restrict__ Ug,
                                                __bf16* __restrict__ Wgb,
                                                __bf16* __restrict__ ATg,
                                                float* __restrict__ Bop) {
  int n = blockIdx.x, h = (n >> 4) & 15;
  float a = sgm(ar[h]) * 0.5f;
  float b = sgm(br[h]) * 0.5f;
  int t = threadIdx.x, wid = t >> 6, lane = t & 63;
  int fr = lane & 15, fkq = lane >> 4, fk = fkq * 8;
  __shared__ __attribute__((aligned(16))) char pool[51200];
  __bf16* Ks  = (__bf16*)pool;            // [128][64] swz; dead after U-init
  __bf16* MTu = (__bf16*)pool;            // [64][128] swz == U^T (overlays Ks)
  __bf16* MTw = (__bf16*)(pool + 16384);  // [64][128] swz == W^T
  __bf16* Sng = (__bf16*)(pool + 32768);  // 36 tiles; diag slots -> inv
  __bf16* KT  = (__bf16*)(pool + 32768);  // [64][128] swz (built late over Sng)
  const __bf16* kg = kb + (size_t)n * 8192;
  const __bf16* vg = vb + (size_t)n * 8192;
  bf16x8 zz;
#pragma unroll
  for (int e = 0; e < 8; ++e) zz[e] = (__bf16)0.f;
  f32x4 c0 = {0.f, 0.f, 0.f, 0.f};
  // stage: normalize k -> Ks (values kept in kreg for the late KT build)
  bf16x4 kreg[4];
#pragma unroll
  for (int it = 0; it < 4; ++it) {
    int u = it * 512 + t;
    int row = u >> 4, c4 = (u & 15) * 4;
    bf16x4 kh = ((const bf16x4*)kg)[u];
    float kf[4];
#pragma unroll
    for (int e = 0; e < 4; ++e) kf[e] = (float)kh[e];
    float ssq = kf[0] * kf[0] + kf[1] * kf[1] + kf[2] * kf[2] + kf[3] * kf[3];
    ssq = row16_reduce(ssq);
    float inv = 1.f / fmaxf(sqrtf(ssq), 1e-12f);
    bf16x4 kn;
#pragma unroll
    for (int e = 0; e < 4; ++e) kn[e] = (__bf16)(kf[e] * inv);
    kreg[it] = kn;
    stb4(Ks, row, c4, 64, kn);
  }
  __syncthreads();
  // S_neg = -(a * tril(KK^T)) packed-lower bf16 (diag tiles: col>=row -> 0)
  for (int p = wid; p < 36; p += 8) {
    int tr = 0, pp = p;
    while (pp > tr) { pp -= (tr + 1); ++tr; }
    int sc = pp;
    f32x4 acc = {0.f, 0.f, 0.f, 0.f};
#pragma unroll
    for (int ks = 0; ks < 2; ++ks)
      acc = __builtin_amdgcn_mfma_f32_16x16x32_bf16(
          ldfrag(Ks, tr * 16 + fr, ks * 32 + fk, 64),
          ldfrag(Ks, sc * 16 + fr, ks * 32 + fk, 64), acc, 0, 0, 0);
    __bf16* dst = Sng + stile(tr, sc);
#pragma unroll
    for (int rg = 0; rg < 4; ++rg) {
      int r = fkq * 4 + rg;
      float v = -a * acc[rg];
      if (tr == sc && fr >= r) v = 0.f;
      dst[r * 16 + fr] = (__bf16)v;
    }
  }
  // U,W init in C/D-layout registers (Ks reads complete before overlays)
  f32x4 U[4], W[4];
#pragma unroll
  for (int ct = 0; ct < 4; ++ct) {
#pragma unroll
    for (int rg = 0; rg < 4; ++rg) {
      int row = wid * 16 + fkq * 4 + rg, col = ct * 16 + fr;
      U[ct][rg] = (float)ldsc(Ks, row, col, 64);
      W[ct][rg] = b * (float)vg[row * 64 + col];
    }
  }
  __syncthreads();
  // ---- parallel diag inverse: inv(I-N) = (I+N)(I+N^2)(I+N^4)(I+N^8) ----
  // scratch overlays MTu/MTw space (dead until substitution)
  {
    __bf16* scr  = ((__bf16*)pool) + wid * 2048;  // 4KB per wave
    __bf16* tNT  = scr;
    __bf16* tN2R = scr + 256;
    __bf16* tN2T = scr + 512;
    __bf16* tN4R = scr + 768;
    __bf16* tN4T = scr + 1024;
    __bf16* tN8T = scr + 1280;
    __bf16* tPR  = scr + 1536;
    __bf16* Nd = Sng + stile(wid, wid);
    float nv[4];
#pragma unroll
    for (int rg = 0; rg < 4; ++rg) {
      nv[rg] = (float)Nd[(fkq * 4 + rg) * 16 + fr];
      tNT[fr * 16 + fkq * 4 + rg] = (__bf16)nv[rg];
    }
    asm volatile("s_waitcnt lgkmcnt(0)" ::: "memory");
    bf16x8 af = (fk < 16) ? *(const bf16x8*)(Nd + fr * 16 + fk) : zz;
    bf16x8 bop = (fk < 16) ? *(const bf16x8*)(tNT + fr * 16 + fk) : zz;
    f32x4 X = __builtin_amdgcn_mfma_f32_16x16x32_bf16(af, bop, c0, 0, 0, 0);  // N^2
#pragma unroll
    for (int rg = 0; rg < 4; ++rg) {
      __bf16 v = (__bf16)X[rg];
      tN2R[(fkq * 4 + rg) * 16 + fr] = v;
      tN2T[fr * 16 + fkq * 4 + rg] = v;
    }
    asm volatile("s_waitcnt lgkmcnt(0)" ::: "memory");
    af = (fk < 16) ? *(const bf16x8*)(tN2R + fr * 16 + fk) : zz;
    bop = (fk < 16) ? *(const bf16x8*)(tN2T + fr * 16 + fk) : zz;
    X = __builtin_amdgcn_mfma_f32_16x16x32_bf16(af, bop, c0, 0, 0, 0);        // N^4
#pragma unroll
    for (int rg = 0; rg < 4; ++rg) {
      __bf16 v = (__bf16)X[rg];
      tN4R[(fkq * 4 + rg) * 16 + fr] = v;
      tN4T[fr * 16 + fkq * 4 + rg] = v;
    }
    asm volatile("s_waitcnt lgkmcnt(0)" ::: "memory");
    af = (fk < 16) ? *(const bf16x8*)(tN4R + fr * 16 + fk) : zz;
    bop = (fk < 16) ? *(const bf16x8*)(tN4T + fr * 16 + fk) : zz;
    X = __builtin_amdgcn_mfma_f32_16x16x32_bf16(af, bop, c0, 0, 0, 0);        // N^8
#pragma unroll
    for (int rg = 0; rg < 4; ++rg)
      tN8T[fr * 16 + fkq * 4 + rg] = (__bf16)X[rg];
    // P = I + N, then P *= (I+N^2), (I+N^4), (I+N^8) via C-init MFMA
    f32x4 P;
#pragma unroll
    for (int rg = 0; rg < 4; ++rg)
      P[rg] = ((fkq * 4 + rg) == fr ? 1.f : 0.f) + nv[rg];
#pragma unroll
    for (int d = 0; d < 3; ++d) {
      const __bf16* tB = (d == 0) ? tN2T : (d == 1) ? tN4T : tN8T;
#pragma unroll
      for (int rg = 0; rg < 4; ++rg)
        tPR[(fkq * 4 + rg) * 16 + fr] = (__bf16)P[rg];
      asm volatile("s_waitcnt lgkmcnt(0)" ::: "memory");
      af = (fk < 16) ? *(const bf16x8*)(tPR + fr * 16 + fk) : zz;
      bop = (fk < 16) ? *(const bf16x8*)(tB + fr * 16 + fk) : zz;
      P = __builtin_amdgcn_mfma_f32_16x16x32_bf16(af, bop, P, 0, 0, 0);
    }
#pragma unroll
    for (int rg = 0; rg < 4; ++rg)
      Nd[(fkq * 4 + rg) * 16 + fr] = (__bf16)P[rg];  // inv -> diag slot
  }
  __syncthreads();
  // right-looking substitution: stage bb = {wave bb: stage rhs, x = inv*rhs,
  // rewrite; barrier; waves>bb rank-16 MFMA update}
  for (int bb = 0; bb < 8; ++bb) {
    if (wid == bb) {
#pragma unroll
      for (int ct = 0; ct < 4; ++ct) {
        bf16x4 uu, ww;
#pragma unroll
        for (int rg = 0; rg < 4; ++rg) {
          uu[rg] = (__bf16)U[ct][rg];
          ww[rg] = (__bf16)W[ct][rg];
        }
        stb4(MTu, ct * 16 + fr, bb * 16 + fkq * 4, 128, uu);
        stb4(MTw, ct * 16 + fr, bb * 16 + fkq * 4, 128, ww);
      }
      asm volatile("s_waitcnt lgkmcnt(0)" ::: "memory");
      const __bf16* invT = Sng + stile(bb, bb);
      bf16x8 afv = (fk < 16) ? *(const bf16x8*)(invT + fr * 16 + fk) : zz;
#pragma unroll
      for (int ct = 0; ct < 4; ++ct) {
        bf16x8 bu = (fk < 16) ? ldfrag(MTu, ct * 16 + fr, bb * 16 + fk, 128) : zz;
        bf16x8 bw = (fk < 16) ? ldfrag(MTw, ct * 16 + fr, bb * 16 + fk, 128) : zz;
        U[ct] = __builtin_amdgcn_mfma_f32_16x16x32_bf16(afv, bu, c0, 0, 0, 0);
        W[ct] = __builtin_amdgcn_mfma_f32_16x16x32_bf16(afv, bw, c0, 0, 0, 0);
      }
#pragma unroll
      for (int ct = 0; ct < 4; ++ct) {
        bf16x4 uu, ww;
#pragma unroll
        for (int rg = 0; rg < 4; ++rg) {
          uu[rg] = (__bf16)U[ct][rg];
          ww[rg] = (__bf16)W[ct][rg];
        }
        stb4(MTu, ct * 16 + fr, bb * 16 + fkq * 4, 128, uu);
        stb4(MTw, ct * 16 + fr, bb * 16 + fkq * 4, 128, ww);
      }
    }
    __syncthreads();
    if (wid > bb) {
      bf16x8 af = zz;
      if (fk < 16) af = *(const bf16x8*)(Sng + stile(wid, bb) + fr * 16 + fk);
#pragma unroll
      for (int ct = 0; ct < 4; ++ct) {
        bf16x8 bu = zz, bw = zz;
        if (fk < 16) {
          bu = ldfrag(MTu, ct * 16 + fr, bb * 16 + fk, 128);
          bw = ldfrag(MTw, ct * 16 + fr, bb * 16 + fk, 128);
        }
        U[ct] = __builtin_amdgcn_mfma_f32_16x16x32_bf16(af, bu, U[ct], 0, 0, 0);
        W[ct] = __builtin_amdgcn_mfma_f32_16x16x32_bf16(af, bw, W[ct], 0, 0, 0);
      }
    }
  }
  // build KT over Sng (dead after last stage barrier) from register-held k
#pragma unroll
  for (int it = 0; it < 4; ++it) {
    int u = it * 512 + t;
    int row = u >> 4, c4 = (u & 15) * 4;
#pragma unroll
    for (int e = 0; e < 4; ++e) stb(KT, c4 + e, row, 128, kreg[it][e]);
  }
  // global bf16 write of U,W in [t][d] layout, straight from registers
  __bf16* ugo = Ug + (size_t)n * 8192;
  __bf16* wgo = Wgb + (size_t)n * 8192;
#pragma unroll
  for (int ct = 0; ct < 4; ++ct)
#pragma unroll
    for (int rg = 0; rg < 4; ++rg) {
      int row = wid * 16 + fkq * 4 + rg, col = ct * 16 + fr;
      ugo[row * 64 + col] = (__bf16)U[ct][rg];
      wgo[row * 64 + col] = (__bf16)W[ct][rg];
    }
  __syncthreads();
  // AT = I - a*(K^T U)  (pre-swizzled bf16), B = W^T K (fp32)
#pragma unroll
  for (int q = 0; q < 4; ++q) {
    int tile = wid + q * 8;  // 0-15 -> AT, 16-31 -> B
    int mat = tile >> 4;
    int ti = (tile >> 2) & 3, tj = tile & 3;
    f32x4 acc = {0.f, 0.f, 0.f, 0.f};
    if (mat == 0) {
#pragma unroll
      for (int ks = 0; ks < 4; ++ks)
        acc = __builtin_amdgcn_mfma_f32_16x16x32_bf16(
            ldfrag(KT, ti * 16 + fr, ks * 32 + fk, 128),
            ldfrag(MTu, tj * 16 + fr, ks * 32 + fk, 128), acc, 0, 0, 0);
      char* dst = (char*)(ATg + (size_t)n * 4096);
#pragma unroll
      for (int rg = 0; rg < 4; ++rg) {
        int i = ti * 16 + fkq * 4 + rg, j = tj * 16 + fr;
        float v = (i == j ? 1.f : 0.f) - a * acc[rg];
        *(__bf16*)(dst + swzb(i, j, 64)) = (__bf16)v;
      }
    } else {
#pragma unroll
      for (int ks = 0; ks < 4; ++ks)
        acc = __builtin_amdgcn_mfma_f32_16x16x32_bf16(
            ldfrag(MTw, ti * 16 + fr, ks * 32 + fk, 128),
            ldfrag(KT, tj * 16 + fr, ks * 32 + fk, 128), acc, 0, 0, 0);
      float* dst = Bop + (size_t)n * 4096;
#pragma unroll
      for (int rg = 0; rg < 4; ++rg)
        dst[(ti * 16 + fkq * 4 + rg) * 64 + tj * 16 + fr] = acc[rg];
    }
  }
}

// ---------------- inter-chunk scan (MFMA) ----------------
__global__ __launch_bounds__(512) void chunk_scan(const __bf16* __restrict__ ATg,
                                                  const float* __restrict__ Bop,
                                                  __bf16* __restrict__ Mst,
                                                  float* __restrict__ Mfinal) {
  int bh = blockIdx.x;
  int t = threadIdx.x, wid = t >> 6, lane = t & 63;
  int fr = lane & 15, fkq = lane >> 4, fk = fkq * 8;
  int ti = wid & 3, tj0 = (wid >> 2) << 1;
  __shared__ __bf16 Mh[4096];    // [64][64] swz
  __shared__ __bf16 Ml[4096];    // [64][64] swz
  __shared__ __bf16 At[2][4096]; // [64][64], pre-swizzled via linear gload_lds
  f32x4 acc[2];
  acc[0] = 0.f;
  acc[1] = 0.f;
  gload_lds16(ATg + (size_t)bh * 16 * 4096 + t * 8, At[0] + t * 8);
  for (int c = 0; c < 16; ++c) {
    int cur = c & 1;
    if (c < 15)
      gload_lds16(ATg + ((size_t)(bh * 16 + c + 1)) * 4096 + t * 8,
                  At[cur ^ 1] + t * 8);
    __bf16* mstc = Mst + ((size_t)(bh * 16 + c)) * 4096;
#pragma unroll
    for (int p = 0; p < 2; ++p) {
      int tj = tj0 + p;
#pragma unroll
      for (int rg = 0; rg < 4; ++rg) {
        int row = ti * 16 + fkq * 4 + rg, col = tj * 16 + fr;
        float v = acc[p][rg];
        __bf16 hi = (__bf16)v;
        mstc[row * 64 + col] = hi;
        stb(Mh, row, col, 64, hi);
        stb(Ml, row, col, 64, (__bf16)(v - (float)hi));
      }
    }
    __syncthreads();
    size_t bb = ((size_t)(bh * 16 + c)) * 4096;
#pragma unroll
    for (int p = 0; p < 2; ++p) {
      int tj = tj0 + p;
      f32x4 na;
#pragma unroll
      for (int rg = 0; rg < 4; ++rg)
        na[rg] = Bop[bb + (ti * 16 + fkq * 4 + rg) * 64 + tj * 16 + fr];
#pragma unroll
      for (int ks = 0; ks < 2; ++ks) {
        bf16x8 bfrag = ldfrag(At[cur], tj * 16 + fr, ks * 32 + fk, 64);
        bf16x8 ah = ldfrag(Mh, ti * 16 + fr, ks * 32 + fk, 64);
        bf16x8 al = ldfrag(Ml, ti * 16 + fr, ks * 32 + fk, 64);
        na = __builtin_amdgcn_mfma_f32_16x16x32_bf16(ah, bfrag, na, 0, 0, 0);
        na = __builtin_amdgcn_mfma_f32_16x16x32_bf16(al, bfrag, na, 0, 0, 0);
      }
      acc[p] = na;
    }
    __syncthreads();
  }
#pragma unroll
  for (int p = 0; p < 2; ++p) {
    int tj = tj0 + p;
#pragma unroll
    for (int rg = 0; rg < 4; ++rg)
      Mfinal[(size_t)bh * 4096 + (ti * 16 + fkq * 4 + rg) * 64 + tj * 16 + fr] =
          acc[p][rg];
  }
}

// ---------------- Y assembly (plain bf16) ----------------
__global__ __launch_bounds__(512, 4) void y_assemble(const __bf16* __restrict__ qb,
                                                     const __bf16* __restrict__ kb,
                                                     const __bf16* __restrict__ Ug,
                                                     const __bf16* __restrict__ Wgb,
                                                     const __bf16* __restrict__ Mst,
                                                     const float* __restrict__ ar,
                                                     __bf16* __restrict__ ybf) {
  int n = blockIdx.x, h = (n >> 4) & 15, b = n >> 8, c = n & 15;
  float a = sgm(ar[h]) * 0.5f;
  int t = threadIdx.x, wid = t >> 6, lane = t & 63;
  int fr = lane & 15, fk = (lane >> 4) * 8;
  __shared__ __bf16 Qs[8192];    // [128][64] swz
  __shared__ __bf16 Rs[8192];    // [128][64] swz: K then U
  __shared__ __bf16 M0s[4096];   // [64][64] swz
  __shared__ __bf16 Gs[10240];   // 40 packed 16x16 tiles
  __shared__ __bf16 WtT[8192];   // [64][128] swz
  const __bf16* qg = qb + (size_t)n * 8192;
  const __bf16* kg = kb + (size_t)n * 8192;
  const __bf16* mg = Mst + (size_t)n * 4096;
#pragma unroll
  for (int it = 0; it < 4; ++it) {
    int u = it * 512 + t;
    int row = u >> 4, c4 = (u & 15) * 4;
    stb4(Qs, row, c4, 64, ((const bf16x4*)qg)[u]);
    bf16x4 kh = ((const bf16x4*)kg)[u];
    float kf[4];
#pragma unroll
    for (int e = 0; e < 4; ++e) kf[e] = (float)kh[e];
    float ssq = kf[0] * kf[0] + kf[1] * kf[1] + kf[2] * kf[2] + kf[3] * kf[3];
    ssq = row16_reduce(ssq);
    float inv = 1.f / fmaxf(sqrtf(ssq), 1e-12f);
    bf16x4 kn;
#pragma unroll
    for (int e = 0; e < 4; ++e) kn[e] = (__bf16)(kf[e] * inv);
    stb4(Rs, row, c4, 64, kn);
  }
#pragma unroll
  for (int it = 0; it < 2; ++it) {
    int u = it * 512 + t;
    int row = u >> 4, c4 = (u & 15) * 4;
    stb4(M0s, row, c4, 64, ((const bf16x4*)mg)[u]);
  }
#pragma unroll
  for (int pz = 0; pz < 2; ++pz) {
    int e = pz * 512 + t;
    int m = e >> 8, idx = e & 255;
    Gs[(2 * m * m + 4 * m + 1) * 256 + idx] = (__bf16)0.f;
  }
  __syncthreads();
  // P1: G = tril(Q K^T, -1), packed-lower bf16
  for (int p = wid; p < 36; p += 8) {
    int tr = 0, pp = p;
    while (pp > tr) { pp -= (tr + 1); ++tr; }
    int sc = pp;
    f32x4 acc = {0.f, 0.f, 0.f, 0.f};
#pragma unroll
    for (int ks = 0; ks < 2; ++ks)
      acc = __builtin_amdgcn_mfma_f32_16x16x32_bf16(
          ldfrag(Qs, tr * 16 + fr, ks * 32 + fk, 64),
          ldfrag(Rs, sc * 16 + fr, ks * 32 + fk, 64), acc, 0, 0, 0);
    int row0 = (lane >> 4) * 4, col = lane & 15;
    __bf16* gt = Gs + (goffn(tr) + sc) * 256;
#pragma unroll
    for (int rg = 0; rg < 4; ++rg) {
      int r = row0 + rg;
      float v = acc[rg];
      if (tr == sc && col >= r) v = 0.f;
      gt[r * 16 + col] = (__bf16)v;
    }
  }
  __syncthreads();
  // P2: restage Rs <- U
  const __bf16* ug = Ug + (size_t)n * 8192;
  const __bf16* wg = Wgb + (size_t)n * 8192;
#pragma unroll
  for (int it = 0; it < 4; ++it) {
    int u = it * 512 + t;
    int row = u >> 4, c4 = (u & 15) * 4;
    stb4(Rs, row, c4, 64, ((const bf16x4*)ug)[u]);
  }
  __syncthreads();
  // P3: WtT[i][s] = W[s][i] - a*(U M0^T)[s][i]
#pragma unroll
  for (int q = 0; q < 4; ++q) {
    int tile = wid + q * 8;
    int ti = tile >> 2, tj = tile & 3;
    f32x4 acc = {0.f, 0.f, 0.f, 0.f};
#pragma unroll
    for (int ks = 0; ks < 2; ++ks)
      acc = __builtin_amdgcn_mfma_f32_16x16x32_bf16(
          ldfrag(Rs, ti * 16 + fr, ks * 32 + fk, 64),
          ldfrag(M0s, tj * 16 + fr, ks * 32 + fk, 64), acc, 0, 0, 0);
    int row0 = (lane >> 4) * 4, col = lane & 15;
#pragma unroll
    for (int rg = 0; rg < 4; ++rg) {
      int s = ti * 16 + row0 + rg, i = tj * 16 + col;
      float wv = (float)wg[s * 64 + i];
      stb(WtT, i, s, 128, (__bf16)(wv - a * acc[rg]));
    }
  }
  __syncthreads();
  // P4: Y = Q M0^T + G Wt
  __bf16* yg = ybf + ((size_t)(b * 2048 + c * 128)) * 1024 + h * 64;
#pragma unroll
  for (int q = 0; q < 4; ++q) {
    int tile = wid + q * 8;
    int ti = tile >> 2, tj = tile & 3;
    f32x4 acc = {0.f, 0.f, 0.f, 0.f};
#pragma unroll
    for (int ks = 0; ks < 2; ++ks)
      acc = __builtin_amdgcn_mfma_f32_16x16x32_bf16(
          ldfrag(Qs, ti * 16 + fr, ks * 32 + fk, 64),
          ldfrag(M0s, tj * 16 + fr, ks * 32 + fk, 64), acc, 0, 0, 0);
    int goffv = goffn(ti);
    int np = (ti + 2) >> 1;
    for (int ks = 0; ks < np; ++ks) {
      int gtile = goffv + ks * 2 + (fk >> 4);
      bf16x8 af = *(const bf16x8*)(Gs + gtile * 256 + fr * 16 + (fk & 15));
      acc = __builtin_amdgcn_mfma_f32_16x16x32_bf16(
          af, ldfrag(WtT, tj * 16 + fr, ks * 32 + fk, 128), acc, 0, 0, 0);
    }
    int row0 = (lane >> 4) * 4, col = lane & 15;
#pragma unroll
    for (int rg = 0; rg < 4; ++rg) {
      int tt = ti * 16 + row0 + rg, d = tj * 16 + col;
      yg[(size_t)tt * 1024 + d] = (__bf16)acc[rg];
    }
  }
}

extern "C" void kernel_launch(void* const* d_in, const int* in_sizes, int n_in,
                              void* d_out, int out_size, void* d_ws, size_t ws_size,
                              hipStream_t stream) {
  const float* x  = (const float*)d_in[0];
  const float* Wq = (const float*)d_in[1];
  const float* Wk = (const float*)d_in[2];
  const float* Wv = (const float*)d_in[3];
  const float* Wo = (const float*)d_in[4];
  const float* ar = (const float*)d_in[5];
  const float* br = (const float*)d_in[6];

  char* ws = (char*)d_ws;
  __bf16* xb  = (__bf16*)ws;                       // 16.8 MB, reused as ybf
  __bf16* ybf = xb;
  __bf16* wqt = (__bf16*)(ws + (17u << 20));       // 2 MB each
  __bf16* wkt = wqt + (1u << 20);
  __bf16* wvt = wkt + (1u << 20);
  __bf16* wot = wvt + (1u << 20);
  __bf16* qb  = (__bf16*)(ws + (25u << 20));       // 16.8 MB bf16 each
  __bf16* kb  = (__bf16*)(ws + (42u << 20));
  __bf16* vb  = (__bf16*)(ws + (59u << 20));
  __bf16* Ugb = (__bf16*)(ws + (76u << 20));
  __bf16* Wgb = (__bf16*)(ws + (93u << 20));
  __bf16* ATg = (__bf16*)(ws + (110u << 20));      // 8.4 MB bf16 (pre-swizzled)
  float* Bop  = (float*)(ws + (127u << 20));       // 16.8 MB fp32
  __bf16* Mst = (__bf16*)(ws + (144u << 20));      // 8.4 MB bf16

  float* yout = (float*)d_out;                     // [8192,1024] f32
  float* Mfin = yout + 8388608;

  cast_f32_bf16<<<8192, 256, 0, stream>>>(x, xb);
  dim3 tg(32, 32);
  transpose_cast<<<tg, 256, 0, stream>>>(Wq, wqt);
  transpose_cast<<<tg, 256, 0, stream>>>(Wk, wkt);
  transpose_cast<<<tg, 256, 0, stream>>>(Wv, wvt);
  transpose_cast<<<tg, 256, 0, stream>>>(Wo, wot);

  dim3 gg(8, 64);
  gemm_bt<<<gg, 256, 0, stream>>>(xb, wqt, nullptr, qb, 1);
  gemm_bt<<<gg, 256, 0, stream>>>(xb, wkt, nullptr, kb, 1);
  gemm_bt<<<gg, 256, 0, stream>>>(xb, wvt, nullptr, vb, 1);

  wy_ab<<<1024, 512, 0, stream>>>(kb, vb, ar, br, Ugb, Wgb, ATg, Bop);
  chunk_scan<<<64, 512, 0, stream>>>(ATg, Bop, Mst, Mfin);
  y_assemble<<<1024, 512, 0, stream>>>(qb, kb, Ugb, Wgb, Mst, ar, ybf);

  gemm_bt<<<gg, 256, 0, stream>>>(ybf, wot, yout, nullptr, 0);
}

// Round 12
// 212.894 us; speedup vs baseline: 2.3829x; 1.0487x over previous
//
#include <hip/hip_runtime.h>
#include <stdint.h>

// Titans-L2 chunked delta-rule forward — WY reformulation, MFMA everywhere.
//   1. cast x -> bf16; transpose+cast Wq/Wk/Wv into PACKED wqkvt [3072][1024];
//      Wo -> wot
//   2. ONE fused MFMA GEMM: [q|k|v] = x@[Wq|Wk|Wv] (bf16 scatter to 3 buffers)
//   3. wy_ab (per chunk): normalize k; S_neg = -a*tril(KK^T,-1) bf16 tiles;
//      PARALLEL Neumann-doubling diag inverses; right-looking substitution
//      (wave bb: inv*rhs via MFMA; waves>bb rank-16 MFMA updates);
//      emits U,W bf16; A^T pre-swizzled bf16; B = W^T K bf16.
//   4. chunk_scan (MFMA): per (b,h), M_{c+1} = M_c A_c + B_c, M hi/lo bf16 LDS.
//   5. y_assemble: G = tril(QK^T,-1); Wt = W - a*(U M0^T); Y = Q M0^T + G Wt.
//   6. final MFMA GEMM y@Wo -> d_out (fp32)
// Dims: B=4 H=16 T=2048 C=1024 D=64 CS=128 nc=16 N=1024 tokens=8192

#define DEV __device__ __forceinline__

typedef __attribute__((ext_vector_type(4))) float f32x4;
typedef __attribute__((ext_vector_type(8))) __bf16 bf16x8;
typedef __attribute__((ext_vector_type(4))) __bf16 bf16x4;

typedef const __attribute__((address_space(1))) uint32_t* gas1_t;
typedef __attribute__((address_space(3))) uint32_t* las3_t;

DEV void gload_lds16(const void* g, void* l) {
  __builtin_amdgcn_global_load_lds((gas1_t)g, (las3_t)l, 16, 0, 0);
}

DEV float sgm(float x) { return 1.f / (1.f + __expf(-x)); }

template <int CTRL>
DEV float dpp_mov(float x) {
  return __builtin_bit_cast(
      float, __builtin_amdgcn_mov_dpp(__builtin_bit_cast(int, x), CTRL, 0xF, 0xF, true));
}
// cyclic rotate-reduce: sum over each 16-lane DPP row
DEV float row16_reduce(float x) {
  x += dpp_mov<0x121>(x);  // row_ror:1
  x += dpp_mov<0x122>(x);  // row_ror:2
  x += dpp_mov<0x124>(x);  // row_ror:4
  x += dpp_mov<0x128>(x);  // row_ror:8
  return x;
}

// ---- swizzled LDS helpers (row-major bf16 tiles; XOR bank swizzle) ----
DEV int swzb(int row, int col, int stride) {  // byte offset
  return ((row * stride + col) << 1) ^ ((row & 7) << 4);
}
DEV bf16x8 ldfrag(const __bf16* B, int row, int col, int stride) {
  return *(const bf16x8*)((const char*)B + swzb(row, col, stride));
}
DEV __bf16 ldsc(const __bf16* B, int row, int col, int stride) {
  return *(const __bf16*)((const char*)B + swzb(row, col, stride));
}
DEV void stb(__bf16* B, int row, int col, int stride, __bf16 v) {
  *(__bf16*)((char*)B + swzb(row, col, stride)) = v;
}
DEV void stb4(__bf16* B, int row, int c4, int stride, bf16x4 v) {
  *(bf16x4*)((char*)B + swzb(row, c4, stride)) = v;
}
// packed-lower tile offsets: row tr holds tiles 0..tr (+1 zero pad for even tr)
DEV int goffn(int tr) {
  int m = tr >> 1;
  return (tr & 1) ? (2 * m * m + 4 * m + 2) : (2 * m * m + 2 * m);
}
DEV int stile(int tr, int sc) { return ((tr * (tr + 1)) / 2 + sc) * 256; }

// ---------------- casts ----------------
__global__ __launch_bounds__(256) void cast_f32_bf16(const float* __restrict__ in,
                                                     __bf16* __restrict__ out) {
  int idx = blockIdx.x * 256 + threadIdx.x;
  float4 v = ((const float4*)in)[idx];
  bf16x4 o;
  o[0] = (__bf16)v.x; o[1] = (__bf16)v.y; o[2] = (__bf16)v.z; o[3] = (__bf16)v.w;
  ((bf16x4*)out)[idx] = o;
}

__global__ __launch_bounds__(256) void transpose_cast(const float* __restrict__ W,
                                                      __bf16* __restrict__ Wt) {
  __shared__ float tile[32][33];
  int tx = threadIdx.x & 31, ty = threadIdx.x >> 5;
  int n0 = blockIdx.x * 32, k0 = blockIdx.y * 32;
#pragma unroll
  for (int u = 0; u < 4; ++u)
    tile[ty + u * 8][tx] = W[(size_t)(k0 + ty + u * 8) * 1024 + n0 + tx];
  __syncthreads();
#pragma unroll
  for (int u = 0; u < 4; ++u)
    Wt[(size_t)(n0 + ty + u * 8) * 1024 + k0 + tx] = (__bf16)tile[tx][ty + u * 8];
}

// ---------------- GEMM: C[M=8192,N] = A[M,K=1024] * Bt[N,K]^T ----------------
// mode 0: fp32 C row-major [M,1024] (N=1024).
// mode 1: bf16 scatter to 3 packed [B,H,T,D] buffers (N=3072, col>>10 selects).
__global__ __launch_bounds__(256) void gemm_bt(const __bf16* __restrict__ A,
                                               const __bf16* __restrict__ Bt,
                                               float* __restrict__ Cf,
                                               __bf16* __restrict__ Cb, int mode) {
  const int t = threadIdx.x;
  const int wv = t >> 6, lane = t & 63;
  const int bm = blockIdx.y, bn = blockIdx.x;
  const int K = 1024;
  __shared__ __bf16 lA[4096];
  __shared__ __bf16 lB[4096];
  f32x4 acc[4][4];
#pragma unroll
  for (int m = 0; m < 4; ++m)
#pragma unroll
    for (int n = 0; n < 4; ++n) acc[m][n] = 0.f;
  const int wr = wv >> 1, wc = wv & 1;
  const int fr = lane & 15, fk = (lane >> 4) * 8;
  const int e0 = (wv * 128 + lane) * 8;
  const int e1 = (wv * 128 + 64 + lane) * 8;
  const int r0s = e0 >> 5, c0s = e0 & 31;
  const int r1s = e1 >> 5, c1s = e1 & 31;
  for (int k0 = 0; k0 < K; k0 += 32) {
    gload_lds16(A + (size_t)(bm * 128 + r0s) * K + k0 + c0s, lA + wv * 1024);
    gload_lds16(Bt + (size_t)(bn * 128 + r0s) * K + k0 + c0s, lB + wv * 1024);
    gload_lds16(A + (size_t)(bm * 128 + r1s) * K + k0 + c1s, lA + wv * 1024 + 512);
    gload_lds16(Bt + (size_t)(bn * 128 + r1s) * K + k0 + c1s, lB + wv * 1024 + 512);
    __syncthreads();
    bf16x8 af[4], bg[4];
#pragma unroll
    for (int m = 0; m < 4; ++m)
      af[m] = *(const bf16x8*)(lA + (wr * 64 + m * 16 + fr) * 32 + fk);
#pragma unroll
    for (int n = 0; n < 4; ++n)
      bg[n] = *(const bf16x8*)(lB + (wc * 64 + n * 16 + fr) * 32 + fk);
#pragma unroll
    for (int m = 0; m < 4; ++m)
#pragma unroll
      for (int n = 0; n < 4; ++n)
        acc[m][n] = __builtin_amdgcn_mfma_f32_16x16x32_bf16(af[m], bg[n], acc[m][n], 0, 0, 0);
    __syncthreads();
  }
  const int rr = (lane >> 4) * 4, cl = lane & 15;
#pragma unroll
  for (int m = 0; m < 4; ++m) {
#pragma unroll
    for (int n = 0; n < 4; ++n) {
#pragma unroll
      for (int rg = 0; rg < 4; ++rg) {
        int row = bm * 128 + wr * 64 + m * 16 + rr + rg;
        int col = bn * 128 + wc * 64 + n * 16 + cl;
        float val = acc[m][n][rg];
        if (mode == 0) {
          Cf[(size_t)row * 1024 + col] = val;
        } else {
          int buf = col >> 10, cc = col & 1023;
          int b = row >> 11, tk = row & 2047;
          int h = cc >> 6, d = cc & 63;
          Cb[(size_t)buf * 8388608 + (((size_t)b * 16 + h) * 2048 + tk) * 64 + d] =
              (__bf16)val;
        }
      }
    }
  }
}

// ---------------- fused WY solve + A/B (doubling inverse, register-resident) ----
// LDS 51.2 KB -> 3 blocks/CU. Wave w owns rows w*16..+15 of U,W in C/D regs.
__global__ __launch_bounds__(512, 6) void wy_ab(const __bf16* __restrict__ kb,
                                                const __bf16* __restrict__ vb,
                                                const float* __restrict__ ar,
                                                const float* __restrict__ br,
                                                __bf16* __restrict__ Ug,
                                                __bf16* __restrict__ Wgb,
                                                __bf16* __restrict__ ATg,
                                                __bf16* __restrict__ Bop) {
  int n = blockIdx.x, h = (n >> 4) & 15;
  float a = sgm(ar[h]) * 0.5f;
  float b = sgm(br[h]) * 0.5f;
  int t = threadIdx.x, wid = t >> 6, lane = t & 63;
  int fr = lane & 15, fkq = lane >> 4, fk = fkq * 8;
  __shared__ __attribute__((aligned(16))) char pool[51200];
  __bf16* Ks  = (__bf16*)pool;            // [128][64] swz; dead after U-init
  __bf16* MTu = (__bf16*)pool;            // [64][128] swz == U^T (overlays Ks)
  __bf16* MTw = (__bf16*)(pool + 16384);  // [64][128] swz == W^T
  __bf16* Sng = (__bf16*)(pool + 32768);  // 36 tiles; diag slots -> inv
  __bf16* KT  = (__bf16*)(pool + 32768);  // [64][128] swz (built late over Sng)
  const __bf16* kg = kb + (size_t)n * 8192;
  const __bf16* vg = vb + (size_t)n * 8192;
  bf16x8 zz;
#pragma unroll
  for (int e = 0; e < 8; ++e) zz[e] = (__bf16)0.f;
  f32x4 c0 = {0.f, 0.f, 0.f, 0.f};
  // stage: normalize k -> Ks (values kept in kreg for the late KT build)
  bf16x4 kreg[4];
#pragma unroll
  for (int it = 0; it < 4; ++it) {
    int u = it * 512 + t;
    int row = u >> 4, c4 = (u & 15) * 4;
    bf16x4 kh = ((const bf16x4*)kg)[u];
    float kf[4];
#pragma unroll
    for (int e = 0; e < 4; ++e) kf[e] = (float)kh[e];
    float ssq = kf[0] * kf[0] + kf[1] * kf[1] + kf[2] * kf[2] + kf[3] * kf[3];
    ssq = row16_reduce(ssq);
    float inv = 1.f / fmaxf(sqrtf(ssq), 1e-12f);
    bf16x4 kn;
#pragma unroll
    for (int e = 0; e < 4; ++e) kn[e] = (__bf16)(kf[e] * inv);
    kreg[it] = kn;
    stb4(Ks, row, c4, 64, kn);
  }
  __syncthreads();
  // S_neg = -(a * tril(KK^T)) packed-lower bf16 (diag tiles: col>=row -> 0)
  for (int p = wid; p < 36; p += 8) {
    int tr = 0, pp = p;
    while (pp > tr) { pp -= (tr + 1); ++tr; }
    int sc = pp;
    f32x4 acc = {0.f, 0.f, 0.f, 0.f};
#pragma unroll
    for (int ks = 0; ks < 2; ++ks)
      acc = __builtin_amdgcn_mfma_f32_16x16x32_bf16(
          ldfrag(Ks, tr * 16 + fr, ks * 32 + fk, 64),
          ldfrag(Ks, sc * 16 + fr, ks * 32 + fk, 64), acc, 0, 0, 0);
    __bf16* dst = Sng + stile(tr, sc);
#pragma unroll
    for (int rg = 0; rg < 4; ++rg) {
      int r = fkq * 4 + rg;
      float v = -a * acc[rg];
      if (tr == sc && fr >= r) v = 0.f;
      dst[r * 16 + fr] = (__bf16)v;
    }
  }
  // U,W init in C/D-layout registers (Ks reads complete before overlays)
  f32x4 U[4], W[4];
#pragma unroll
  for (int ct = 0; ct < 4; ++ct) {
#pragma unroll
    for (int rg = 0; rg < 4; ++rg) {
      int row = wid * 16 + fkq * 4 + rg, col = ct * 16 + fr;
      U[ct][rg] = (float)ldsc(Ks, row, col, 64);
      W[ct][rg] = b * (float)vg[row * 64 + col];
    }
  }
  __syncthreads();
  // ---- parallel diag inverse: inv(I-N) = (I+N)(I+N^2)(I+N^4)(I+N^8) ----
  // scratch overlays MTu/MTw space (dead until substitution)
  {
    __bf16* scr  = ((__bf16*)pool) + wid * 2048;  // 4KB per wave
    __bf16* tNT  = scr;
    __bf16* tN2R = scr + 256;
    __bf16* tN2T = scr + 512;
    __bf16* tN4R = scr + 768;
    __bf16* tN4T = scr + 1024;
    __bf16* tN8T = scr + 1280;
    __bf16* tPR  = scr + 1536;
    __bf16* Nd = Sng + stile(wid, wid);
    float nv[4];
#pragma unroll
    for (int rg = 0; rg < 4; ++rg) {
      nv[rg] = (float)Nd[(fkq * 4 + rg) * 16 + fr];
      tNT[fr * 16 + fkq * 4 + rg] = (__bf16)nv[rg];
    }
    asm volatile("s_waitcnt lgkmcnt(0)" ::: "memory");
    bf16x8 af = (fk < 16) ? *(const bf16x8*)(Nd + fr * 16 + fk) : zz;
    bf16x8 bop = (fk < 16) ? *(const bf16x8*)(tNT + fr * 16 + fk) : zz;
    f32x4 X = __builtin_amdgcn_mfma_f32_16x16x32_bf16(af, bop, c0, 0, 0, 0);  // N^2
#pragma unroll
    for (int rg = 0; rg < 4; ++rg) {
      __bf16 v = (__bf16)X[rg];
      tN2R[(fkq * 4 + rg) * 16 + fr] = v;
      tN2T[fr * 16 + fkq * 4 + rg] = v;
    }
    asm volatile("s_waitcnt lgkmcnt(0)" ::: "memory");
    af = (fk < 16) ? *(const bf16x8*)(tN2R + fr * 16 + fk) : zz;
    bop = (fk < 16) ? *(const bf16x8*)(tN2T + fr * 16 + fk) : zz;
    X = __builtin_amdgcn_mfma_f32_16x16x32_bf16(af, bop, c0, 0, 0, 0);        // N^4
#pragma unroll
    for (int rg = 0; rg < 4; ++rg) {
      __bf16 v = (__bf16)X[rg];
      tN4R[(fkq * 4 + rg) * 16 + fr] = v;
      tN4T[fr * 16 + fkq * 4 + rg] = v;
    }
    asm volatile("s_waitcnt lgkmcnt(0)" ::: "memory");
    af = (fk < 16) ? *(const bf16x8*)(tN4R + fr * 16 + fk) : zz;
    bop = (fk < 16) ? *(const bf16x8*)(tN4T + fr * 16 + fk) : zz;
    X = __builtin_amdgcn_mfma_f32_16x16x32_bf16(af, bop, c0, 0, 0, 0);        // N^8
#pragma unroll
    for (int rg = 0; rg < 4; ++rg)
      tN8T[fr * 16 + fkq * 4 + rg] = (__bf16)X[rg];
    // P = I + N, then P *= (I+N^2), (I+N^4), (I+N^8) via C-init MFMA
    f32x4 P;
#pragma unroll
    for (int rg = 0; rg < 4; ++rg)
      P[rg] = ((fkq * 4 + rg) == fr ? 1.f : 0.f) + nv[rg];
#pragma unroll
    for (int d = 0; d < 3; ++d) {
      const __bf16* tB = (d == 0) ? tN2T : (d == 1) ? tN4T : tN8T;
#pragma unroll
      for (int rg = 0; rg < 4; ++rg)
        tPR[(fkq * 4 + rg) * 16 + fr] = (__bf16)P[rg];
      asm volatile("s_waitcnt lgkmcnt(0)" ::: "memory");
      af = (fk < 16) ? *(const bf16x8*)(tPR + fr * 16 + fk) : zz;
      bop = (fk < 16) ? *(const bf16x8*)(tB + fr * 16 + fk) : zz;
      P = __builtin_amdgcn_mfma_f32_16x16x32_bf16(af, bop, P, 0, 0, 0);
    }
#pragma unroll
    for (int rg = 0; rg < 4; ++rg)
      Nd[(fkq * 4 + rg) * 16 + fr] = (__bf16)P[rg];  // inv -> diag slot
  }
  __syncthreads();
  // right-looking substitution: stage bb = {wave bb: stage rhs, x = inv*rhs,
  // rewrite; barrier; waves>bb rank-16 MFMA update}
  for (int bb = 0; bb < 8; ++bb) {
    if (wid == bb) {
#pragma unroll
      for (int ct = 0; ct < 4; ++ct) {
        bf16x4 uu, ww;
#pragma unroll
        for (int rg = 0; rg < 4; ++rg) {
          uu[rg] = (__bf16)U[ct][rg];
          ww[rg] = (__bf16)W[ct][rg];
        }
        stb4(MTu, ct * 16 + fr, bb * 16 + fkq * 4, 128, uu);
        stb4(MTw, ct * 16 + fr, bb * 16 + fkq * 4, 128, ww);
      }
      asm volatile("s_waitcnt lgkmcnt(0)" ::: "memory");
      const __bf16* invT = Sng + stile(bb, bb);
      bf16x8 afv = (fk < 16) ? *(const bf16x8*)(invT + fr * 16 + fk) : zz;
#pragma unroll
      for (int ct = 0; ct < 4; ++ct) {
        bf16x8 bu = (fk < 16) ? ldfrag(MTu, ct * 16 + fr, bb * 16 + fk, 128) : zz;
        bf16x8 bw = (fk < 16) ? ldfrag(MTw, ct * 16 + fr, bb * 16 + fk, 128) : zz;
        U[ct] = __builtin_amdgcn_mfma_f32_16x16x32_bf16(afv, bu, c0, 0, 0, 0);
        W[ct] = __builtin_amdgcn_mfma_f32_16x16x32_bf16(afv, bw, c0, 0, 0, 0);
      }
#pragma unroll
      for (int ct = 0; ct < 4; ++ct) {
        bf16x4 uu, ww;
#pragma unroll
        for (int rg = 0; rg < 4; ++rg) {
          uu[rg] = (__bf16)U[ct][rg];
          ww[rg] = (__bf16)W[ct][rg];
        }
        stb4(MTu, ct * 16 + fr, bb * 16 + fkq * 4, 128, uu);
        stb4(MTw, ct * 16 + fr, bb * 16 + fkq * 4, 128, ww);
      }
    }
    __syncthreads();
    if (wid > bb) {
      bf16x8 af = zz;
      if (fk < 16) af = *(const bf16x8*)(Sng + stile(wid, bb) + fr * 16 + fk);
#pragma unroll
      for (int ct = 0; ct < 4; ++ct) {
        bf16x8 bu = zz, bw = zz;
        if (fk < 16) {
          bu = ldfrag(MTu, ct * 16 + fr, bb * 16 + fk, 128);
          bw = ldfrag(MTw, ct * 16 + fr, bb * 16 + fk, 128);
        }
        U[ct] = __builtin_amdgcn_mfma_f32_16x16x32_bf16(af, bu, U[ct], 0, 0, 0);
        W[ct] = __builtin_amdgcn_mfma_f32_16x16x32_bf16(af, bw, W[ct], 0, 0, 0);
      }
    }
  }
  // build KT over Sng (dead after last stage barrier) from register-held k
#pragma unroll
  for (int it = 0; it < 4; ++it) {
    int u = it * 512 + t;
    int row = u >> 4, c4 = (u & 15) * 4;
#pragma unroll
    for (int e = 0; e < 4; ++e) stb(KT, c4 + e, row, 128, kreg[it][e]);
  }
  // global bf16 write of U,W in [t][d] layout, straight from registers
  __bf16* ugo = Ug + (size_t)n * 8192;
  __bf16* wgo = Wgb + (size_t)n * 8192;
#pragma unroll
  for (int ct = 0; ct < 4; ++ct)
#pragma unroll
    for (int rg = 0; rg < 4; ++rg) {
      int row = wid * 16 + fkq * 4 + rg, col = ct * 16 + fr;
      ugo[row * 64 + col] = (__bf16)U[ct][rg];
      wgo[row * 64 + col] = (__bf16)W[ct][rg];
    }
  __syncthreads();
  // AT = I - a*(K^T U)  (pre-swizzled bf16), B = W^T K (bf16)
#pragma unroll
  for (int q = 0; q < 4; ++q) {
    int tile = wid + q * 8;  // 0-15 -> AT, 16-31 -> B
    int mat = tile >> 4;
    int ti = (tile >> 2) & 3, tj = tile & 3;
    f32x4 acc = {0.f, 0.f, 0.f, 0.f};
    if (mat == 0) {
#pragma unroll
      for (int ks = 0; ks < 4; ++ks)
        acc = __builtin_amdgcn_mfma_f32_16x16x32_bf16(
            ldfrag(KT, ti * 16 + fr, ks * 32 + fk, 128),
            ldfrag(MTu, tj * 16 + fr, ks * 32 + fk, 128), acc, 0, 0, 0);
      char* dst = (char*)(ATg + (size_t)n * 4096);
#pragma unroll
      for (int rg = 0; rg < 4; ++rg) {
        int i = ti * 16 + fkq * 4 + rg, j = tj * 16 + fr;
        float v = (i == j ? 1.f : 0.f) - a * acc[rg];
        *(__bf16*)(dst + swzb(i, j, 64)) = (__bf16)v;
      }
    } else {
#pragma unroll
      for (int ks = 0; ks < 4; ++ks)
        acc = __builtin_amdgcn_mfma_f32_16x16x32_bf16(
            ldfrag(MTw, ti * 16 + fr, ks * 32 + fk, 128),
            ldfrag(KT, tj * 16 + fr, ks * 32 + fk, 128), acc, 0, 0, 0);
      __bf16* dst = Bop + (size_t)n * 4096;
#pragma unroll
      for (int rg = 0; rg < 4; ++rg)
        dst[(ti * 16 + fkq * 4 + rg) * 64 + tj * 16 + fr] = (__bf16)acc[rg];
    }
  }
}

// ---------------- inter-chunk scan (MFMA) ----------------
__global__ __launch_bounds__(512) void chunk_scan(const __bf16* __restrict__ ATg,
                                                  const __bf16* __restrict__ Bop,
                                                  __bf16* __restrict__ Mst,
                                                  float* __restrict__ Mfinal) {
  int bh = blockIdx.x;
  int t = threadIdx.x, wid = t >> 6, lane = t & 63;
  int fr = lane & 15, fkq = lane >> 4, fk = fkq * 8;
  int ti = wid & 3, tj0 = (wid >> 2) << 1;
  __shared__ __bf16 Mh[4096];    // [64][64] swz
  __shared__ __bf16 Ml[4096];    // [64][64] swz
  __shared__ __bf16 At[2][4096]; // [64][64], pre-swizzled via linear gload_lds
  f32x4 acc[2];
  acc[0] = 0.f;
  acc[1] = 0.f;
  gload_lds16(ATg + (size_t)bh * 16 * 4096 + t * 8, At[0] + t * 8);
  for (int c = 0; c < 16; ++c) {
    int cur = c & 1;
    if (c < 15)
      gload_lds16(ATg + ((size_t)(bh * 16 + c + 1)) * 4096 + t * 8,
                  At[cur ^ 1] + t * 8);
    __bf16* mstc = Mst + ((size_t)(bh * 16 + c)) * 4096;
#pragma unroll
    for (int p = 0; p < 2; ++p) {
      int tj = tj0 + p;
#pragma unroll
      for (int rg = 0; rg < 4; ++rg) {
        int row = ti * 16 + fkq * 4 + rg, col = tj * 16 + fr;
        float v = acc[p][rg];
        __bf16 hi = (__bf16)v;
        mstc[row * 64 + col] = hi;
        stb(Mh, row, col, 64, hi);
        stb(Ml, row, col, 64, (__bf16)(v - (float)hi));
      }
    }
    __syncthreads();
    size_t bb = ((size_t)(bh * 16 + c)) * 4096;
#pragma unroll
    for (int p = 0; p < 2; ++p) {
      int tj = tj0 + p;
      f32x4 na;
#pragma unroll
      for (int rg = 0; rg < 4; ++rg)
        na[rg] = (float)Bop[bb + (ti * 16 + fkq * 4 + rg) * 64 + tj * 16 + fr];
#pragma unroll
      for (int ks = 0; ks < 2; ++ks) {
        bf16x8 bfrag = ldfrag(At[cur], tj * 16 + fr, ks * 32 + fk, 64);
        bf16x8 ah = ldfrag(Mh, ti * 16 + fr, ks * 32 + fk, 64);
        bf16x8 al = ldfrag(Ml, ti * 16 + fr, ks * 32 + fk, 64);
        na = __builtin_amdgcn_mfma_f32_16x16x32_bf16(ah, bfrag, na, 0, 0, 0);
        na = __builtin_amdgcn_mfma_f32_16x16x32_bf16(al, bfrag, na, 0, 0, 0);
      }
      acc[p] = na;
    }
    __syncthreads();
  }
#pragma unroll
  for (int p = 0; p < 2; ++p) {
    int tj = tj0 + p;
#pragma unroll
    for (int rg = 0; rg < 4; ++rg)
      Mfinal[(size_t)bh * 4096 + (ti * 16 + fkq * 4 + rg) * 64 + tj * 16 + fr] =
          acc[p][rg];
  }
}

// ---------------- Y assembly (plain bf16) ----------------
__global__ __launch_bounds__(512, 4) void y_assemble(const __bf16* __restrict__ qb,
                                                     const __bf16* __restrict__ kb,
                                                     const __bf16* __restrict__ Ug,
                                                     const __bf16* __restrict__ Wgb,
                                                     const __bf16* __restrict__ Mst,
                                                     const float* __restrict__ ar,
                                                     __bf16* __restrict__ ybf) {
  int n = blockIdx.x, h = (n >> 4) & 15, b = n >> 8, c = n & 15;
  float a = sgm(ar[h]) * 0.5f;
  int t = threadIdx.x, wid = t >> 6, lane = t & 63;
  int fr = lane & 15, fk = (lane >> 4) * 8;
  __shared__ __bf16 Qs[8192];    // [128][64] swz
  __shared__ __bf16 Rs[8192];    // [128][64] swz: K then U
  __shared__ __bf16 M0s[4096];   // [64][64] swz
  __shared__ __bf16 Gs[10240];   // 40 packed 16x16 tiles
  __shared__ __bf16 WtT[8192];   // [64][128] swz
  const __bf16* qg = qb + (size_t)n * 8192;
  const __bf16* kg = kb + (size_t)n * 8192;
  const __bf16* mg = Mst + (size_t)n * 4096;
#pragma unroll
  for (int it = 0; it < 4; ++it) {
    int u = it * 512 + t;
    int row = u >> 4, c4 = (u & 15) * 4;
    stb4(Qs, row, c4, 64, ((const bf16x4*)qg)[u]);
    bf16x4 kh = ((const bf16x4*)kg)[u];
    float kf[4];
#pragma unroll
    for (int e = 0; e < 4; ++e) kf[e] = (float)kh[e];
    float ssq = kf[0] * kf[0] + kf[1] * kf[1] + kf[2] * kf[2] + kf[3] * kf[3];
    ssq = row16_reduce(ssq);
    float inv = 1.f / fmaxf(sqrtf(ssq), 1e-12f);
    bf16x4 kn;
#pragma unroll
    for (int e = 0; e < 4; ++e) kn[e] = (__bf16)(kf[e] * inv);
    stb4(Rs, row, c4, 64, kn);
  }
#pragma unroll
  for (int it = 0; it < 2; ++it) {
    int u = it * 512 + t;
    int row = u >> 4, c4 = (u & 15) * 4;
    stb4(M0s, row, c4, 64, ((const bf16x4*)mg)[u]);
  }
#pragma unroll
  for (int pz = 0; pz < 2; ++pz) {
    int e = pz * 512 + t;
    int m = e >> 8, idx = e & 255;
    Gs[(2 * m * m + 4 * m + 1) * 256 + idx] = (__bf16)0.f;
  }
  __syncthreads();
  // P1: G = tril(Q K^T, -1), packed-lower bf16
  for (int p = wid; p < 36; p += 8) {
    int tr = 0, pp = p;
    while (pp > tr) { pp -= (tr + 1); ++tr; }
    int sc = pp;
    f32x4 acc = {0.f, 0.f, 0.f, 0.f};
#pragma unroll
    for (int ks = 0; ks < 2; ++ks)
      acc = __builtin_amdgcn_mfma_f32_16x16x32_bf16(
          ldfrag(Qs, tr * 16 + fr, ks * 32 + fk, 64),
          ldfrag(Rs, sc * 16 + fr, ks * 32 + fk, 64), acc, 0, 0, 0);
    int row0 = (lane >> 4) * 4, col = lane & 15;
    __bf16* gt = Gs + (goffn(tr) + sc) * 256;
#pragma unroll
    for (int rg = 0; rg < 4; ++rg) {
      int r = row0 + rg;
      float v = acc[rg];
      if (tr == sc && col >= r) v = 0.f;
      gt[r * 16 + col] = (__bf16)v;
    }
  }
  __syncthreads();
  // P2: restage Rs <- U
  const __bf16* ug = Ug + (size_t)n * 8192;
  const __bf16* wg = Wgb + (size_t)n * 8192;
#pragma unroll
  for (int it = 0; it < 4; ++it) {
    int u = it * 512 + t;
    int row = u >> 4, c4 = (u & 15) * 4;
    stb4(Rs, row, c4, 64, ((const bf16x4*)ug)[u]);
  }
  __syncthreads();
  // P3: WtT[i][s] = W[s][i] - a*(U M0^T)[s][i]
#pragma unroll
  for (int q = 0; q < 4; ++q) {
    int tile = wid + q * 8;
    int ti = tile >> 2, tj = tile & 3;
    f32x4 acc = {0.f, 0.f, 0.f, 0.f};
#pragma unroll
    for (int ks = 0; ks < 2; ++ks)
      acc = __builtin_amdgcn_mfma_f32_16x16x32_bf16(
          ldfrag(Rs, ti * 16 + fr, ks * 32 + fk, 64),
          ldfrag(M0s, tj * 16 + fr, ks * 32 + fk, 64), acc, 0, 0, 0);
    int row0 = (lane >> 4) * 4, col = lane & 15;
#pragma unroll
    for (int rg = 0; rg < 4; ++rg) {
      int s = ti * 16 + row0 + rg, i = tj * 16 + col;
      float wv = (float)wg[s * 64 + i];
      stb(WtT, i, s, 128, (__bf16)(wv - a * acc[rg]));
    }
  }
  __syncthreads();
  // P4: Y = Q M0^T + G Wt
  __bf16* yg = ybf + ((size_t)(b * 2048 + c * 128)) * 1024 + h * 64;
#pragma unroll
  for (int q = 0; q < 4; ++q) {
    int tile = wid + q * 8;
    int ti = tile >> 2, tj = tile & 3;
    f32x4 acc = {0.f, 0.f, 0.f, 0.f};
#pragma unroll
    for (int ks = 0; ks < 2; ++ks)
      acc = __builtin_amdgcn_mfma_f32_16x16x32_bf16(
          ldfrag(Qs, ti * 16 + fr, ks * 32 + fk, 64),
          ldfrag(M0s, tj * 16 + fr, ks * 32 + fk, 64), acc, 0, 0, 0);
    int goffv = goffn(ti);
    int np = (ti + 2) >> 1;
    for (int ks = 0; ks < np; ++ks) {
      int gtile = goffv + ks * 2 + (fk >> 4);
      bf16x8 af = *(const bf16x8*)(Gs + gtile * 256 + fr * 16 + (fk & 15));
      acc = __builtin_amdgcn_mfma_f32_16x16x32_bf16(
          af, ldfrag(WtT, tj * 16 + fr, ks * 32 + fk, 128), acc, 0, 0, 0);
    }
    int row0 = (lane >> 4) * 4, col = lane & 15;
#pragma unroll
    for (int rg = 0; rg < 4; ++rg) {
      int tt = ti * 16 + row0 + rg, d = tj * 16 + col;
      yg[(size_t)tt * 1024 + d] = (__bf16)acc[rg];
    }
  }
}

extern "C" void kernel_launch(void* const* d_in, const int* in_sizes, int n_in,
                              void* d_out, int out_size, void* d_ws, size_t ws_size,
                              hipStream_t stream) {
  const float* x  = (const float*)d_in[0];
  const float* Wq = (const float*)d_in[1];
  const float* Wk = (const float*)d_in[2];
  const float* Wv = (const float*)d_in[3];
  const float* Wo = (const float*)d_in[4];
  const float* ar = (const float*)d_in[5];
  const float* br = (const float*)d_in[6];

  char* ws = (char*)d_ws;
  __bf16* xb    = (__bf16*)ws;                     // 16.8 MB, reused as ybf
  __bf16* ybf   = xb;
  __bf16* wqkvt = (__bf16*)(ws + (17u << 20));     // 6 MB packed [3072][1024]
  __bf16* wot   = (__bf16*)(ws + (23u << 20));     // 2 MB
  __bf16* qb    = (__bf16*)(ws + (25u << 20));     // q,k,v contiguous, 8388608 elems each
  __bf16* kb    = qb + 8388608;
  __bf16* vb    = kb + 8388608;                    // ends at ~75.3 MB
  __bf16* Ugb   = (__bf16*)(ws + (76u << 20));
  __bf16* Wgb   = (__bf16*)(ws + (93u << 20));
  __bf16* ATg   = (__bf16*)(ws + (110u << 20));    // 8.4 MB (pre-swizzled)
  __bf16* Bop   = (__bf16*)(ws + (127u << 20));    // 8.4 MB bf16
  __bf16* Mst   = (__bf16*)(ws + (144u << 20));    // 8.4 MB

  float* yout = (float*)d_out;                     // [8192,1024] f32
  float* Mfin = yout + 8388608;

  cast_f32_bf16<<<8192, 256, 0, stream>>>(x, xb);
  dim3 tg(32, 32);
  transpose_cast<<<tg, 256, 0, stream>>>(Wq, wqkvt);
  transpose_cast<<<tg, 256, 0, stream>>>(Wk, wqkvt + (1u << 20));
  transpose_cast<<<tg, 256, 0, stream>>>(Wv, wqkvt + (2u << 20));
  transpose_cast<<<tg, 256, 0, stream>>>(Wo, wot);

  dim3 gqkv(24, 64);
  gemm_bt<<<gqkv, 256, 0, stream>>>(xb, wqkvt, nullptr, qb, 1);

  wy_ab<<<1024, 512, 0, stream>>>(kb, vb, ar, br, Ugb, Wgb, ATg, Bop);
  chunk_scan<<<64, 512, 0, stream>>>(ATg, Bop, Mst, Mfin);
  y_assemble<<<1024, 512, 0, stream>>>(qb, kb, Ugb, Wgb, Mst, ar, ybf);

  dim3 go(8, 64);
  gemm_bt<<<go, 256, 0, stream>>>(ybf, wot, yout, nullptr, 0);
}

// Round 13
// 212.615 us; speedup vs baseline: 2.3860x; 1.0013x over previous
//
#include <hip/hip_runtime.h>
#include <stdint.h>

// Titans-L2 chunked delta-rule forward — WY reformulation, MFMA everywhere.
//   1. cast x -> bf16; transpose+cast Wq/Wk/Wv into PACKED wqkvt [3072][1024];
//      Wo -> wot
//   2. ONE fused MFMA GEMM (256x128 tile, BK=64, 8 waves, dbuf LDS + XOR swz):
//      [q|k|v] = x@[Wq|Wk|Wv] (bf16 scatter to 3 buffers)
//   3. wy_ab (per chunk): normalize k; S_neg = -a*tril(KK^T,-1) bf16 tiles;
//      PARALLEL Neumann-doubling diag inverses; right-looking substitution;
//      emits U,W bf16; A^T pre-swizzled bf16; B = W^T K bf16.
//   4. chunk_scan (MFMA): per (b,h), M_{c+1} = M_c A_c + B_c, M hi/lo bf16 LDS.
//   5. y_assemble: G = tril(QK^T,-1); Wt = W - a*(U M0^T); Y = Q M0^T + G Wt.
//   6. final MFMA GEMM y@Wo -> d_out (fp32)
// Dims: B=4 H=16 T=2048 C=1024 D=64 CS=128 nc=16 N=1024 tokens=8192

#define DEV __device__ __forceinline__

typedef __attribute__((ext_vector_type(4))) float f32x4;
typedef __attribute__((ext_vector_type(8))) __bf16 bf16x8;
typedef __attribute__((ext_vector_type(4))) __bf16 bf16x4;

typedef const __attribute__((address_space(1))) uint32_t* gas1_t;
typedef __attribute__((address_space(3))) uint32_t* las3_t;

DEV void gload_lds16(const void* g, void* l) {
  __builtin_amdgcn_global_load_lds((gas1_t)g, (las3_t)l, 16, 0, 0);
}

DEV float sgm(float x) { return 1.f / (1.f + __expf(-x)); }

template <int CTRL>
DEV float dpp_mov(float x) {
  return __builtin_bit_cast(
      float, __builtin_amdgcn_mov_dpp(__builtin_bit_cast(int, x), CTRL, 0xF, 0xF, true));
}
// cyclic rotate-reduce: sum over each 16-lane DPP row
DEV float row16_reduce(float x) {
  x += dpp_mov<0x121>(x);  // row_ror:1
  x += dpp_mov<0x122>(x);  // row_ror:2
  x += dpp_mov<0x124>(x);  // row_ror:4
  x += dpp_mov<0x128>(x);  // row_ror:8
  return x;
}

// ---- swizzled LDS helpers (row-major bf16 tiles; XOR bank swizzle) ----
DEV int swzb(int row, int col, int stride) {  // byte offset
  return ((row * stride + col) << 1) ^ ((row & 7) << 4);
}
DEV bf16x8 ldfrag(const __bf16* B, int row, int col, int stride) {
  return *(const bf16x8*)((const char*)B + swzb(row, col, stride));
}
DEV __bf16 ldsc(const __bf16* B, int row, int col, int stride) {
  return *(const __bf16*)((const char*)B + swzb(row, col, stride));
}
DEV void stb(__bf16* B, int row, int col, int stride, __bf16 v) {
  *(__bf16*)((char*)B + swzb(row, col, stride)) = v;
}
DEV void stb4(__bf16* B, int row, int c4, int stride, bf16x4 v) {
  *(bf16x4*)((char*)B + swzb(row, c4, stride)) = v;
}
// packed-lower tile offsets: row tr holds tiles 0..tr (+1 zero pad for even tr)
DEV int goffn(int tr) {
  int m = tr >> 1;
  return (tr & 1) ? (2 * m * m + 4 * m + 2) : (2 * m * m + 2 * m);
}
DEV int stile(int tr, int sc) { return ((tr * (tr + 1)) / 2 + sc) * 256; }

// ---------------- casts ----------------
__global__ __launch_bounds__(256) void cast_f32_bf16(const float* __restrict__ in,
                                                     __bf16* __restrict__ out) {
  int idx = blockIdx.x * 256 + threadIdx.x;
  float4 v = ((const float4*)in)[idx];
  bf16x4 o;
  o[0] = (__bf16)v.x; o[1] = (__bf16)v.y; o[2] = (__bf16)v.z; o[3] = (__bf16)v.w;
  ((bf16x4*)out)[idx] = o;
}

__global__ __launch_bounds__(256) void transpose_cast(const float* __restrict__ W,
                                                      __bf16* __restrict__ Wt) {
  __shared__ float tile[32][33];
  int tx = threadIdx.x & 31, ty = threadIdx.x >> 5;
  int n0 = blockIdx.x * 32, k0 = blockIdx.y * 32;
#pragma unroll
  for (int u = 0; u < 4; ++u)
    tile[ty + u * 8][tx] = W[(size_t)(k0 + ty + u * 8) * 1024 + n0 + tx];
  __syncthreads();
#pragma unroll
  for (int u = 0; u < 4; ++u)
    Wt[(size_t)(n0 + ty + u * 8) * 1024 + k0 + tx] = (__bf16)tile[tx][ty + u * 8];
}

// ---------------- GEMM: C[M=8192,N] = A[M,K=1024] * Bt[N,K]^T ----------------
// 256x128 tile, BK=64, 8 waves, double-buffered XOR-swizzled LDS (96 KB),
// stage-next/compute/barrier per K-tile. XCD-aware bijective block remap.
// mode 0: fp32 C row-major [M,1024] (NBN=8).
// mode 1: bf16 scatter to 3 packed [B,H,T,D] buffers (NBN=24, col>>10 selects).
// Staging swizzle: LDS linear granule e (16B) holds logical (row=e>>3,
// col=((e&7)^(row&7))*8) of the tile -> pre-swizzled global source; reads use
// swzb(row,col,64) (involution), conflict-free ds_read_b128.
template <int CALLS>
DEV void stage_tile(const __bf16* __restrict__ G, __bf16* L, int t, int wid, int K) {
#pragma unroll
  for (int it = 0; it < CALLS; ++it) {
    int e = it * 512 + t;
    int row = e >> 3;
    int c0 = ((e & 7) ^ (row & 7)) << 3;
    gload_lds16(G + (size_t)row * K + c0, L + it * 4096 + wid * 512);
  }
}

__global__ __launch_bounds__(512, 2) void gemm_bt(const __bf16* __restrict__ A,
                                                  const __bf16* __restrict__ Bt,
                                                  float* __restrict__ Cf,
                                                  __bf16* __restrict__ Cb,
                                                  int mode, int NBN) {
  const int t = threadIdx.x;
  const int wid = t >> 6, lane = t & 63;
  const int fr = lane & 15, fkq = lane >> 4, fk = fkq * 8;
  const int wr = wid >> 2, wc = wid & 3;
  const int K = 1024;
  // XCD-aware bijective remap (gridDim.x % 8 == 0)
  int nwg = gridDim.x, lin = blockIdx.x;
  int q = nwg >> 3;
  int id2 = (lin & 7) * q + (lin >> 3);
  int bn = id2 % NBN, bm = id2 / NBN;
  __shared__ __bf16 lA[2][16384];  // [256][64] swz, 32KB each
  __shared__ __bf16 lB[2][8192];   // [128][64] swz, 16KB each
  const __bf16* Ab = A + (size_t)(bm * 256) * K;
  const __bf16* Bb = Bt + (size_t)(bn * 128) * K;
  f32x4 acc[8][2];
#pragma unroll
  for (int m = 0; m < 8; ++m) {
    acc[m][0] = 0.f;
    acc[m][1] = 0.f;
  }
  stage_tile<4>(Ab, lA[0], t, wid, K);
  stage_tile<2>(Bb, lB[0], t, wid, K);
  __syncthreads();
  for (int kt = 0; kt < 16; ++kt) {
    int cur = kt & 1;
    if (kt < 15) {
      stage_tile<4>(Ab + (kt + 1) * 64, lA[cur ^ 1], t, wid, K);
      stage_tile<2>(Bb + (kt + 1) * 64, lB[cur ^ 1], t, wid, K);
    }
#pragma unroll
    for (int kk = 0; kk < 2; ++kk) {
      bf16x8 af[8], bg[2];
#pragma unroll
      for (int m = 0; m < 8; ++m)
        af[m] = ldfrag(lA[cur], wr * 128 + m * 16 + fr, kk * 32 + fk, 64);
#pragma unroll
      for (int nn = 0; nn < 2; ++nn)
        bg[nn] = ldfrag(lB[cur], wc * 32 + nn * 16 + fr, kk * 32 + fk, 64);
#pragma unroll
      for (int m = 0; m < 8; ++m)
#pragma unroll
        for (int nn = 0; nn < 2; ++nn)
          acc[m][nn] =
              __builtin_amdgcn_mfma_f32_16x16x32_bf16(af[m], bg[nn], acc[m][nn], 0, 0, 0);
    }
    __syncthreads();  // implicit vmcnt(0)+lgkm drain: next tile staged & reads done
  }
#pragma unroll
  for (int m = 0; m < 8; ++m) {
#pragma unroll
    for (int nn = 0; nn < 2; ++nn) {
#pragma unroll
      for (int rg = 0; rg < 4; ++rg) {
        int row = bm * 256 + wr * 128 + m * 16 + fkq * 4 + rg;
        int col = bn * 128 + wc * 32 + nn * 16 + fr;
        float val = acc[m][nn][rg];
        if (mode == 0) {
          Cf[(size_t)row * 1024 + col] = val;
        } else {
          int buf = col >> 10, cc = col & 1023;
          int b = row >> 11, tk = row & 2047;
          int h = cc >> 6, d = cc & 63;
          Cb[(size_t)buf * 8388608 + (((size_t)b * 16 + h) * 2048 + tk) * 64 + d] =
              (__bf16)val;
        }
      }
    }
  }
}

// ---------------- fused WY solve + A/B (doubling inverse, register-resident) ----
// LDS 51.2 KB -> 3 blocks/CU. Wave w owns rows w*16..+15 of U,W in C/D regs.
__global__ __launch_bounds__(512, 6) void wy_ab(const __bf16* __restrict__ kb,
                                                const __bf16* __restrict__ vb,
                                                const float* __restrict__ ar,
                                                const float* __restrict__ br,
                                                __bf16* __restrict__ Ug,
                                                __bf16* __restrict__ Wgb,
                                                __bf16* __restrict__ ATg,
                                                __bf16* __restrict__ Bop) {
  int n = blockIdx.x, h = (n >> 4) & 15;
  float a = sgm(ar[h]) * 0.5f;
  float b = sgm(br[h]) * 0.5f;
  int t = threadIdx.x, wid = t >> 6, lane = t & 63;
  int fr = lane & 15, fkq = lane >> 4, fk = fkq * 8;
  __shared__ __attribute__((aligned(16))) char pool[51200];
  __bf16* Ks  = (__bf16*)pool;            // [128][64] swz; dead after U-init
  __bf16* MTu = (__bf16*)pool;            // [64][128] swz == U^T (overlays Ks)
  __bf16* MTw = (__bf16*)(pool + 16384);  // [64][128] swz == W^T
  __bf16* Sng = (__bf16*)(pool + 32768);  // 36 tiles; diag slots -> inv
  __bf16* KT  = (__bf16*)(pool + 32768);  // [64][128] swz (built late over Sng)
  const __bf16* kg = kb + (size_t)n * 8192;
  const __bf16* vg = vb + (size_t)n * 8192;
  bf16x8 zz;
#pragma unroll
  for (int e = 0; e < 8; ++e) zz[e] = (__bf16)0.f;
  f32x4 c0 = {0.f, 0.f, 0.f, 0.f};
  // stage: normalize k -> Ks (values kept in kreg for the late KT build)
  bf16x4 kreg[4];
#pragma unroll
  for (int it = 0; it < 4; ++it) {
    int u = it * 512 + t;
    int row = u >> 4, c4 = (u & 15) * 4;
    bf16x4 kh = ((const bf16x4*)kg)[u];
    float kf[4];
#pragma unroll
    for (int e = 0; e < 4; ++e) kf[e] = (float)kh[e];
    float ssq = kf[0] * kf[0] + kf[1] * kf[1] + kf[2] * kf[2] + kf[3] * kf[3];
    ssq = row16_reduce(ssq);
    float inv = 1.f / fmaxf(sqrtf(ssq), 1e-12f);
    bf16x4 kn;
#pragma unroll
    for (int e = 0; e < 4; ++e) kn[e] = (__bf16)(kf[e] * inv);
    kreg[it] = kn;
    stb4(Ks, row, c4, 64, kn);
  }
  __syncthreads();
  // S_neg = -(a * tril(KK^T)) packed-lower bf16 (diag tiles: col>=row -> 0)
  for (int p = wid; p < 36; p += 8) {
    int tr = 0, pp = p;
    while (pp > tr) { pp -= (tr + 1); ++tr; }
    int sc = pp;
    f32x4 acc = {0.f, 0.f, 0.f, 0.f};
#pragma unroll
    for (int ks = 0; ks < 2; ++ks)
      acc = __builtin_amdgcn_mfma_f32_16x16x32_bf16(
          ldfrag(Ks, tr * 16 + fr, ks * 32 + fk, 64),
          ldfrag(Ks, sc * 16 + fr, ks * 32 + fk, 64), acc, 0, 0, 0);
    __bf16* dst = Sng + stile(tr, sc);
#pragma unroll
    for (int rg = 0; rg < 4; ++rg) {
      int r = fkq * 4 + rg;
      float v = -a * acc[rg];
      if (tr == sc && fr >= r) v = 0.f;
      dst[r * 16 + fr] = (__bf16)v;
    }
  }
  // U,W init in C/D-layout registers (Ks reads complete before overlays)
  f32x4 U[4], W[4];
#pragma unroll
  for (int ct = 0; ct < 4; ++ct) {
#pragma unroll
    for (int rg = 0; rg < 4; ++rg) {
      int row = wid * 16 + fkq * 4 + rg, col = ct * 16 + fr;
      U[ct][rg] = (float)ldsc(Ks, row, col, 64);
      W[ct][rg] = b * (float)vg[row * 64 + col];
    }
  }
  __syncthreads();
  // ---- parallel diag inverse: inv(I-N) = (I+N)(I+N^2)(I+N^4)(I+N^8) ----
  {
    __bf16* scr  = ((__bf16*)pool) + wid * 2048;  // 4KB per wave
    __bf16* tNT  = scr;
    __bf16* tN2R = scr + 256;
    __bf16* tN2T = scr + 512;
    __bf16* tN4R = scr + 768;
    __bf16* tN4T = scr + 1024;
    __bf16* tN8T = scr + 1280;
    __bf16* tPR  = scr + 1536;
    __bf16* Nd = Sng + stile(wid, wid);
    float nv[4];
#pragma unroll
    for (int rg = 0; rg < 4; ++rg) {
      nv[rg] = (float)Nd[(fkq * 4 + rg) * 16 + fr];
      tNT[fr * 16 + fkq * 4 + rg] = (__bf16)nv[rg];
    }
    asm volatile("s_waitcnt lgkmcnt(0)" ::: "memory");
    bf16x8 af = (fk < 16) ? *(const bf16x8*)(Nd + fr * 16 + fk) : zz;
    bf16x8 bop = (fk < 16) ? *(const bf16x8*)(tNT + fr * 16 + fk) : zz;
    f32x4 X = __builtin_amdgcn_mfma_f32_16x16x32_bf16(af, bop, c0, 0, 0, 0);  // N^2
#pragma unroll
    for (int rg = 0; rg < 4; ++rg) {
      __bf16 v = (__bf16)X[rg];
      tN2R[(fkq * 4 + rg) * 16 + fr] = v;
      tN2T[fr * 16 + fkq * 4 + rg] = v;
    }
    asm volatile("s_waitcnt lgkmcnt(0)" ::: "memory");
    af = (fk < 16) ? *(const bf16x8*)(tN2R + fr * 16 + fk) : zz;
    bop = (fk < 16) ? *(const bf16x8*)(tN2T + fr * 16 + fk) : zz;
    X = __builtin_amdgcn_mfma_f32_16x16x32_bf16(af, bop, c0, 0, 0, 0);        // N^4
#pragma unroll
    for (int rg = 0; rg < 4; ++rg) {
      __bf16 v = (__bf16)X[rg];
      tN4R[(fkq * 4 + rg) * 16 + fr] = v;
      tN4T[fr * 16 + fkq * 4 + rg] = v;
    }
    asm volatile("s_waitcnt lgkmcnt(0)" ::: "memory");
    af = (fk < 16) ? *(const bf16x8*)(tN4R + fr * 16 + fk) : zz;
    bop = (fk < 16) ? *(const bf16x8*)(tN4T + fr * 16 + fk) : zz;
    X = __builtin_amdgcn_mfma_f32_16x16x32_bf16(af, bop, c0, 0, 0, 0);        // N^8
#pragma unroll
    for (int rg = 0; rg < 4; ++rg)
      tN8T[fr * 16 + fkq * 4 + rg] = (__bf16)X[rg];
    // P = I + N, then P *= (I+N^2), (I+N^4), (I+N^8) via C-init MFMA
    f32x4 P;
#pragma unroll
    for (int rg = 0; rg < 4; ++rg)
      P[rg] = ((fkq * 4 + rg) == fr ? 1.f : 0.f) + nv[rg];
#pragma unroll
    for (int d = 0; d < 3; ++d) {
      const __bf16* tB = (d == 0) ? tN2T : (d == 1) ? tN4T : tN8T;
#pragma unroll
      for (int rg = 0; rg < 4; ++rg)
        tPR[(fkq * 4 + rg) * 16 + fr] = (__bf16)P[rg];
      asm volatile("s_waitcnt lgkmcnt(0)" ::: "memory");
      af = (fk < 16) ? *(const bf16x8*)(tPR + fr * 16 + fk) : zz;
      bop = (fk < 16) ? *(const bf16x8*)(tB + fr * 16 + fk) : zz;
      P = __builtin_amdgcn_mfma_f32_16x16x32_bf16(af, bop, P, 0, 0, 0);
    }
#pragma unroll
    for (int rg = 0; rg < 4; ++rg)
      Nd[(fkq * 4 + rg) * 16 + fr] = (__bf16)P[rg];  // inv -> diag slot
  }
  __syncthreads();
  // right-looking substitution: stage bb = {wave bb: stage rhs, x = inv*rhs,
  // rewrite; barrier; waves>bb rank-16 MFMA update}
  for (int bb = 0; bb < 8; ++bb) {
    if (wid == bb) {
#pragma unroll
      for (int ct = 0; ct < 4; ++ct) {
        bf16x4 uu, ww;
#pragma unroll
        for (int rg = 0; rg < 4; ++rg) {
          uu[rg] = (__bf16)U[ct][rg];
          ww[rg] = (__bf16)W[ct][rg];
        }
        stb4(MTu, ct * 16 + fr, bb * 16 + fkq * 4, 128, uu);
        stb4(MTw, ct * 16 + fr, bb * 16 + fkq * 4, 128, ww);
      }
      asm volatile("s_waitcnt lgkmcnt(0)" ::: "memory");
      const __bf16* invT = Sng + stile(bb, bb);
      bf16x8 afv = (fk < 16) ? *(const bf16x8*)(invT + fr * 16 + fk) : zz;
#pragma unroll
      for (int ct = 0; ct < 4; ++ct) {
        bf16x8 bu = (fk < 16) ? ldfrag(MTu, ct * 16 + fr, bb * 16 + fk, 128) : zz;
        bf16x8 bw = (fk < 16) ? ldfrag(MTw, ct * 16 + fr, bb * 16 + fk, 128) : zz;
        U[ct] = __builtin_amdgcn_mfma_f32_16x16x32_bf16(afv, bu, c0, 0, 0, 0);
        W[ct] = __builtin_amdgcn_mfma_f32_16x16x32_bf16(afv, bw, c0, 0, 0, 0);
      }
#pragma unroll
      for (int ct = 0; ct < 4; ++ct) {
        bf16x4 uu, ww;
#pragma unroll
        for (int rg = 0; rg < 4; ++rg) {
          uu[rg] = (__bf16)U[ct][rg];
          ww[rg] = (__bf16)W[ct][rg];
        }
        stb4(MTu, ct * 16 + fr, bb * 16 + fkq * 4, 128, uu);
        stb4(MTw, ct * 16 + fr, bb * 16 + fkq * 4, 128, ww);
      }
    }
    __syncthreads();
    if (wid > bb) {
      bf16x8 af = zz;
      if (fk < 16) af = *(const bf16x8*)(Sng + stile(wid, bb) + fr * 16 + fk);
#pragma unroll
      for (int ct = 0; ct < 4; ++ct) {
        bf16x8 bu = zz, bw = zz;
        if (fk < 16) {
          bu = ldfrag(MTu, ct * 16 + fr, bb * 16 + fk, 128);
          bw = ldfrag(MTw, ct * 16 + fr, bb * 16 + fk, 128);
        }
        U[ct] = __builtin_amdgcn_mfma_f32_16x16x32_bf16(af, bu, U[ct], 0, 0, 0);
        W[ct] = __builtin_amdgcn_mfma_f32_16x16x32_bf16(af, bw, W[ct], 0, 0, 0);
      }
    }
  }
  // build KT over Sng (dead after last stage barrier) from register-held k
#pragma unroll
  for (int it = 0; it < 4; ++it) {
    int u = it * 512 + t;
    int row = u >> 4, c4 = (u & 15) * 4;
#pragma unroll
    for (int e = 0; e < 4; ++e) stb(KT, c4 + e, row, 128, kreg[it][e]);
  }
  // global bf16 write of U,W in [t][d] layout, straight from registers
  __bf16* ugo = Ug + (size_t)n * 8192;
  __bf16* wgo = Wgb + (size_t)n * 8192;
#pragma unroll
  for (int ct = 0; ct < 4; ++ct)
#pragma unroll
    for (int rg = 0; rg < 4; ++rg) {
      int row = wid * 16 + fkq * 4 + rg, col = ct * 16 + fr;
      ugo[row * 64 + col] = (__bf16)U[ct][rg];
      wgo[row * 64 + col] = (__bf16)W[ct][rg];
    }
  __syncthreads();
  // AT = I - a*(K^T U)  (pre-swizzled bf16), B = W^T K (bf16)
#pragma unroll
  for (int q = 0; q < 4; ++q) {
    int tile = wid + q * 8;  // 0-15 -> AT, 16-31 -> B
    int mat = tile >> 4;
    int ti = (tile >> 2) & 3, tj = tile & 3;
    f32x4 acc = {0.f, 0.f, 0.f, 0.f};
    if (mat == 0) {
#pragma unroll
      for (int ks = 0; ks < 4; ++ks)
        acc = __builtin_amdgcn_mfma_f32_16x16x32_bf16(
            ldfrag(KT, ti * 16 + fr, ks * 32 + fk, 128),
            ldfrag(MTu, tj * 16 + fr, ks * 32 + fk, 128), acc, 0, 0, 0);
      char* dst = (char*)(ATg + (size_t)n * 4096);
#pragma unroll
      for (int rg = 0; rg < 4; ++rg) {
        int i = ti * 16 + fkq * 4 + rg, j = tj * 16 + fr;
        float v = (i == j ? 1.f : 0.f) - a * acc[rg];
        *(__bf16*)(dst + swzb(i, j, 64)) = (__bf16)v;
      }
    } else {
#pragma unroll
      for (int ks = 0; ks < 4; ++ks)
        acc = __builtin_amdgcn_mfma_f32_16x16x32_bf16(
            ldfrag(MTw, ti * 16 + fr, ks * 32 + fk, 128),
            ldfrag(KT, tj * 16 + fr, ks * 32 + fk, 128), acc, 0, 0, 0);
      __bf16* dst = Bop + (size_t)n * 4096;
#pragma unroll
      for (int rg = 0; rg < 4; ++rg)
        dst[(ti * 16 + fkq * 4 + rg) * 64 + tj * 16 + fr] = (__bf16)acc[rg];
    }
  }
}

// ---------------- inter-chunk scan (MFMA) ----------------
__global__ __launch_bounds__(512) void chunk_scan(const __bf16* __restrict__ ATg,
                                                  const __bf16* __restrict__ Bop,
                                                  __bf16* __restrict__ Mst,
                                                  float* __restrict__ Mfinal) {
  int bh = blockIdx.x;
  int t = threadIdx.x, wid = t >> 6, lane = t & 63;
  int fr = lane & 15, fkq = lane >> 4, fk = fkq * 8;
  int ti = wid & 3, tj0 = (wid >> 2) << 1;
  __shared__ __bf16 Mh[4096];    // [64][64] swz
  __shared__ __bf16 Ml[4096];    // [64][64] swz
  __shared__ __bf16 At[2][4096]; // [64][64], pre-swizzled via linear gload_lds
  f32x4 acc[2];
  acc[0] = 0.f;
  acc[1] = 0.f;
  gload_lds16(ATg + (size_t)bh * 16 * 4096 + t * 8, At[0] + t * 8);
  for (int c = 0; c < 16; ++c) {
    int cur = c & 1;
    if (c < 15)
      gload_lds16(ATg + ((size_t)(bh * 16 + c + 1)) * 4096 + t * 8,
                  At[cur ^ 1] + t * 8);
    __bf16* mstc = Mst + ((size_t)(bh * 16 + c)) * 4096;
#pragma unroll
    for (int p = 0; p < 2; ++p) {
      int tj = tj0 + p;
#pragma unroll
      for (int rg = 0; rg < 4; ++rg) {
        int row = ti * 16 + fkq * 4 + rg, col = tj * 16 + fr;
        float v = acc[p][rg];
        __bf16 hi = (__bf16)v;
        mstc[row * 64 + col] = hi;
        stb(Mh, row, col, 64, hi);
        stb(Ml, row, col, 64, (__bf16)(v - (float)hi));
      }
    }
    __syncthreads();
    size_t bb = ((size_t)(bh * 16 + c)) * 4096;
#pragma unroll
    for (int p = 0; p < 2; ++p) {
      int tj = tj0 + p;
      f32x4 na;
#pragma unroll
      for (int rg = 0; rg < 4; ++rg)
        na[rg] = (float)Bop[bb + (ti * 16 + fkq * 4 + rg) * 64 + tj * 16 + fr];
#pragma unroll
      for (int ks = 0; ks < 2; ++ks) {
        bf16x8 bfrag = ldfrag(At[cur], tj * 16 + fr, ks * 32 + fk, 64);
        bf16x8 ah = ldfrag(Mh, ti * 16 + fr, ks * 32 + fk, 64);
        bf16x8 al = ldfrag(Ml, ti * 16 + fr, ks * 32 + fk, 64);
        na = __builtin_amdgcn_mfma_f32_16x16x32_bf16(ah, bfrag, na, 0, 0, 0);
        na = __builtin_amdgcn_mfma_f32_16x16x32_bf16(al, bfrag, na, 0, 0, 0);
      }
      acc[p] = na;
    }
    __syncthreads();
  }
#pragma unroll
  for (int p = 0; p < 2; ++p) {
    int tj = tj0 + p;
#pragma unroll
    for (int rg = 0; rg < 4; ++rg)
      Mfinal[(size_t)bh * 4096 + (ti * 16 + fkq * 4 + rg) * 64 + tj * 16 + fr] =
          acc[p][rg];
  }
}

// ---------------- Y assembly (plain bf16) ----------------
__global__ __launch_bounds__(512, 4) void y_assemble(const __bf16* __restrict__ qb,
                                                     const __bf16* __restrict__ kb,
                                                     const __bf16* __restrict__ Ug,
                                                     const __bf16* __restrict__ Wgb,
                                                     const __bf16* __restrict__ Mst,
                                                     const float* __restrict__ ar,
                                                     __bf16* __restrict__ ybf) {
  int n = blockIdx.x, h = (n >> 4) & 15, b = n >> 8, c = n & 15;
  float a = sgm(ar[h]) * 0.5f;
  int t = threadIdx.x, wid = t >> 6, lane = t & 63;
  int fr = lane & 15, fk = (lane >> 4) * 8;
  __shared__ __bf16 Qs[8192];    // [128][64] swz
  __shared__ __bf16 Rs[8192];    // [128][64] swz: K then U
  __shared__ __bf16 M0s[4096];   // [64][64] swz
  __shared__ __bf16 Gs[10240];   // 40 packed 16x16 tiles
  __shared__ __bf16 WtT[8192];   // [64][128] swz
  const __bf16* qg = qb + (size_t)n * 8192;
  const __bf16* kg = kb + (size_t)n * 8192;
  const __bf16* mg = Mst + (size_t)n * 4096;
#pragma unroll
  for (int it = 0; it < 4; ++it) {
    int u = it * 512 + t;
    int row = u >> 4, c4 = (u & 15) * 4;
    stb4(Qs, row, c4, 64, ((const bf16x4*)qg)[u]);
    bf16x4 kh = ((const bf16x4*)kg)[u];
    float kf[4];
#pragma unroll
    for (int e = 0; e < 4; ++e) kf[e] = (float)kh[e];
    float ssq = kf[0] * kf[0] + kf[1] * kf[1] + kf[2] * kf[2] + kf[3] * kf[3];
    ssq = row16_reduce(ssq);
    float inv = 1.f / fmaxf(sqrtf(ssq), 1e-12f);
    bf16x4 kn;
#pragma unroll
    for (int e = 0; e < 4; ++e) kn[e] = (__bf16)(kf[e] * inv);
    stb4(Rs, row, c4, 64, kn);
  }
#pragma unroll
  for (int it = 0; it < 2; ++it) {
    int u = it * 512 + t;
    int row = u >> 4, c4 = (u & 15) * 4;
    stb4(M0s, row, c4, 64, ((const bf16x4*)mg)[u]);
  }
#pragma unroll
  for (int pz = 0; pz < 2; ++pz) {
    int e = pz * 512 + t;
    int m = e >> 8, idx = e & 255;
    Gs[(2 * m * m + 4 * m + 1) * 256 + idx] = (__bf16)0.f;
  }
  __syncthreads();
  // P1: G = tril(Q K^T, -1), packed-lower bf16
  for (int p = wid; p < 36; p += 8) {
    int tr = 0, pp = p;
    while (pp > tr) { pp -= (tr + 1); ++tr; }
    int sc = pp;
    f32x4 acc = {0.f, 0.f, 0.f, 0.f};
#pragma unroll
    for (int ks = 0; ks < 2; ++ks)
      acc = __builtin_amdgcn_mfma_f32_16x16x32_bf16(
          ldfrag(Qs, tr * 16 + fr, ks * 32 + fk, 64),
          ldfrag(Rs, sc * 16 + fr, ks * 32 + fk, 64), acc, 0, 0, 0);
    int row0 = (lane >> 4) * 4, col = lane & 15;
    __bf16* gt = Gs + (goffn(tr) + sc) * 256;
#pragma unroll
    for (int rg = 0; rg < 4; ++rg) {
      int r = row0 + rg;
      float v = acc[rg];
      if (tr == sc && col >= r) v = 0.f;
      gt[r * 16 + col] = (__bf16)v;
    }
  }
  __syncthreads();
  // P2: restage Rs <- U
  const __bf16* ug = Ug + (size_t)n * 8192;
  const __bf16* wg = Wgb + (size_t)n * 8192;
#pragma unroll
  for (int it = 0; it < 4; ++it) {
    int u = it * 512 + t;
    int row = u >> 4, c4 = (u & 15) * 4;
    stb4(Rs, row, c4, 64, ((const bf16x4*)ug)[u]);
  }
  __syncthreads();
  // P3: WtT[i][s] = W[s][i] - a*(U M0^T)[s][i]
#pragma unroll
  for (int q = 0; q < 4; ++q) {
    int tile = wid + q * 8;
    int ti = tile >> 2, tj = tile & 3;
    f32x4 acc = {0.f, 0.f, 0.f, 0.f};
#pragma unroll
    for (int ks = 0; ks < 2; ++ks)
      acc = __builtin_amdgcn_mfma_f32_16x16x32_bf16(
          ldfrag(Rs, ti * 16 + fr, ks * 32 + fk, 64),
          ldfrag(M0s, tj * 16 + fr, ks * 32 + fk, 64), acc, 0, 0, 0);
    int row0 = (lane >> 4) * 4, col = lane & 15;
#pragma unroll
    for (int rg = 0; rg < 4; ++rg) {
      int s = ti * 16 + row0 + rg, i = tj * 16 + col;
      float wv = (float)wg[s * 64 + i];
      stb(WtT, i, s, 128, (__bf16)(wv - a * acc[rg]));
    }
  }
  __syncthreads();
  // P4: Y = Q M0^T + G Wt
  __bf16* yg = ybf + ((size_t)(b * 2048 + c * 128)) * 1024 + h * 64;
#pragma unroll
  for (int q = 0; q < 4; ++q) {
    int tile = wid + q * 8;
    int ti = tile >> 2, tj = tile & 3;
    f32x4 acc = {0.f, 0.f, 0.f, 0.f};
#pragma unroll
    for (int ks = 0; ks < 2; ++ks)
      acc = __builtin_amdgcn_mfma_f32_16x16x32_bf16(
          ldfrag(Qs, ti * 16 + fr, ks * 32 + fk, 64),
          ldfrag(M0s, tj * 16 + fr, ks * 32 + fk, 64), acc, 0, 0, 0);
    int goffv = goffn(ti);
    int np = (ti + 2) >> 1;
    for (int ks = 0; ks < np; ++ks) {
      int gtile = goffv + ks * 2 + (fk >> 4);
      bf16x8 af = *(const bf16x8*)(Gs + gtile * 256 + fr * 16 + (fk & 15));
      acc = __builtin_amdgcn_mfma_f32_16x16x32_bf16(
          af, ldfrag(WtT, tj * 16 + fr, ks * 32 + fk, 128), acc, 0, 0, 0);
    }
    int row0 = (lane >> 4) * 4, col = lane & 15;
#pragma unroll
    for (int rg = 0; rg < 4; ++rg) {
      int tt = ti * 16 + row0 + rg, d = tj * 16 + col;
      yg[(size_t)tt * 1024 + d] = (__bf16)acc[rg];
    }
  }
}

extern "C" void kernel_launch(void* const* d_in, const int* in_sizes, int n_in,
                              void* d_out, int out_size, void* d_ws, size_t ws_size,
                              hipStream_t stream) {
  const float* x  = (const float*)d_in[0];
  const float* Wq = (const float*)d_in[1];
  const float* Wk = (const float*)d_in[2];
  const float* Wv = (const float*)d_in[3];
  const float* Wo = (const float*)d_in[4];
  const float* ar = (const float*)d_in[5];
  const float* br = (const float*)d_in[6];

  char* ws = (char*)d_ws;
  __bf16* xb    = (__bf16*)ws;                     // 16.8 MB, reused as ybf
  __bf16* ybf   = xb;
  __bf16* wqkvt = (__bf16*)(ws + (17u << 20));     // 6 MB packed [3072][1024]
  __bf16* wot   = (__bf16*)(ws + (23u << 20));     // 2 MB
  __bf16* qb    = (__bf16*)(ws + (25u << 20));     // q,k,v contiguous, 8388608 elems each
  __bf16* kb    = qb + 8388608;
  __bf16* vb    = kb + 8388608;                    // ends at ~75.3 MB
  __bf16* Ugb   = (__bf16*)(ws + (76u << 20));
  __bf16* Wgb   = (__bf16*)(ws + (93u << 20));
  __bf16* ATg   = (__bf16*)(ws + (110u << 20));    // 8.4 MB (pre-swizzled)
  __bf16* Bop   = (__bf16*)(ws + (127u << 20));    // 8.4 MB bf16
  __bf16* Mst   = (__bf16*)(ws + (144u << 20));    // 8.4 MB

  float* yout = (float*)d_out;                     // [8192,1024] f32
  float* Mfin = yout + 8388608;

  cast_f32_bf16<<<8192, 256, 0, stream>>>(x, xb);
  dim3 tg(32, 32);
  transpose_cast<<<tg, 256, 0, stream>>>(Wq, wqkvt);
  transpose_cast<<<tg, 256, 0, stream>>>(Wk, wqkvt + (1u << 20));
  transpose_cast<<<tg, 256, 0, stream>>>(Wv, wqkvt + (2u << 20));
  transpose_cast<<<tg, 256, 0, stream>>>(Wo, wot);

  // fused QKV GEMM: M=8192, N=3072 -> grid 32*24 = 768 (3.0 rounds of 256 CUs)
  gemm_bt<<<768, 512, 0, stream>>>(xb, wqkvt, nullptr, qb, 1, 24);

  wy_ab<<<1024, 512, 0, stream>>>(kb, vb, ar, br, Ugb, Wgb, ATg, Bop);
  chunk_scan<<<64, 512, 0, stream>>>(ATg, Bop, Mst, Mfin);
  y_assemble<<<1024, 512, 0, stream>>>(qb, kb, Ugb, Wgb, Mst, ar, ybf);

  // final GEMM: M=8192, N=1024 -> grid 32*8 = 256 (1.0 rounds)
  gemm_bt<<<256, 512, 0, stream>>>(ybf, wot, yout, nullptr, 0, 8);
}

// Round 14
// 200.405 us; speedup vs baseline: 2.5314x; 1.0609x over previous
//
#include <hip/hip_runtime.h>
#include <stdint.h>

// Titans-L2 chunked delta-rule forward — WY reformulation, MFMA everywhere.
//   1. cast x -> bf16; transpose+cast Wq/Wk/Wv into PACKED wqkvt [3072][1024];
//      Wo -> wot
//   2. ONE fused MFMA GEMM (256x128 tile, BK=64, 8 waves, dbuf XOR-swz LDS,
//      COUNTED-vmcnt pipeline: loads stay in flight across raw s_barriers):
//      [q|k|v] = x@[Wq|Wk|Wv] (bf16 scatter to 3 buffers)
//   3. wy_ab (per chunk): normalize k; S_neg = -a*tril(KK^T,-1) bf16 tiles;
//      PARALLEL Neumann-doubling diag inverses; right-looking substitution;
//      emits U,W bf16; A^T pre-swizzled bf16; B = W^T K bf16.
//   4. chunk_scan (MFMA): per (b,h), M_{c+1} = M_c A_c + B_c, M hi/lo bf16 LDS.
//   5. y_assemble: G = tril(QK^T,-1); Wt = W - a*(U M0^T); Y = Q M0^T + G Wt.
//   6. final MFMA GEMM y@Wo -> d_out (fp32)
// Dims: B=4 H=16 T=2048 C=1024 D=64 CS=128 nc=16 N=1024 tokens=8192

#define DEV __device__ __forceinline__

typedef __attribute__((ext_vector_type(4))) float f32x4;
typedef __attribute__((ext_vector_type(8))) __bf16 bf16x8;
typedef __attribute__((ext_vector_type(4))) __bf16 bf16x4;

typedef const __attribute__((address_space(1))) uint32_t* gas1_t;
typedef __attribute__((address_space(3))) uint32_t* las3_t;

DEV void gload_lds16(const void* g, void* l) {
  __builtin_amdgcn_global_load_lds((gas1_t)g, (las3_t)l, 16, 0, 0);
}

DEV float sgm(float x) { return 1.f / (1.f + __expf(-x)); }

template <int CTRL>
DEV float dpp_mov(float x) {
  return __builtin_bit_cast(
      float, __builtin_amdgcn_mov_dpp(__builtin_bit_cast(int, x), CTRL, 0xF, 0xF, true));
}
// cyclic rotate-reduce: sum over each 16-lane DPP row
DEV float row16_reduce(float x) {
  x += dpp_mov<0x121>(x);  // row_ror:1
  x += dpp_mov<0x122>(x);  // row_ror:2
  x += dpp_mov<0x124>(x);  // row_ror:4
  x += dpp_mov<0x128>(x);  // row_ror:8
  return x;
}

// ---- swizzled LDS helpers (row-major bf16 tiles; XOR bank swizzle) ----
DEV int swzb(int row, int col, int stride) {  // byte offset
  return ((row * stride + col) << 1) ^ ((row & 7) << 4);
}
DEV bf16x8 ldfrag(const __bf16* B, int row, int col, int stride) {
  return *(const bf16x8*)((const char*)B + swzb(row, col, stride));
}
DEV __bf16 ldsc(const __bf16* B, int row, int col, int stride) {
  return *(const __bf16*)((const char*)B + swzb(row, col, stride));
}
DEV void stb(__bf16* B, int row, int col, int stride, __bf16 v) {
  *(__bf16*)((char*)B + swzb(row, col, stride)) = v;
}
DEV void stb4(__bf16* B, int row, int c4, int stride, bf16x4 v) {
  *(bf16x4*)((char*)B + swzb(row, c4, stride)) = v;
}
// packed-lower tile offsets: row tr holds tiles 0..tr (+1 zero pad for even tr)
DEV int goffn(int tr) {
  int m = tr >> 1;
  return (tr & 1) ? (2 * m * m + 4 * m + 2) : (2 * m * m + 2 * m);
}
DEV int stile(int tr, int sc) { return ((tr * (tr + 1)) / 2 + sc) * 256; }

// ---------------- casts ----------------
__global__ __launch_bounds__(256) void cast_f32_bf16(const float* __restrict__ in,
                                                     __bf16* __restrict__ out) {
  int idx = blockIdx.x * 256 + threadIdx.x;
  float4 v = ((const float4*)in)[idx];
  bf16x4 o;
  o[0] = (__bf16)v.x; o[1] = (__bf16)v.y; o[2] = (__bf16)v.z; o[3] = (__bf16)v.w;
  ((bf16x4*)out)[idx] = o;
}

__global__ __launch_bounds__(256) void transpose_cast(const float* __restrict__ W,
                                                      __bf16* __restrict__ Wt) {
  __shared__ float tile[32][33];
  int tx = threadIdx.x & 31, ty = threadIdx.x >> 5;
  int n0 = blockIdx.x * 32, k0 = blockIdx.y * 32;
#pragma unroll
  for (int u = 0; u < 4; ++u)
    tile[ty + u * 8][tx] = W[(size_t)(k0 + ty + u * 8) * 1024 + n0 + tx];
  __syncthreads();
#pragma unroll
  for (int u = 0; u < 4; ++u)
    Wt[(size_t)(n0 + ty + u * 8) * 1024 + k0 + tx] = (__bf16)tile[tx][ty + u * 8];
}

// ---------------- GEMM: C[M=8192,N] = A[M,K=1024] * Bt[N,K]^T ----------------
// 256x128 tile, BK=64, 8 waves, double-buffered XOR-swizzled LDS (96 KB),
// COUNTED-vmcnt pipeline (T4): raw s_barrier pair per K-tile, vmcnt(6) keeps
// next-tile loads in flight. XCD-aware bijective block remap.
// mode 0: fp32 C row-major [M,1024] (NBN=8).
// mode 1: bf16 scatter to 3 packed [B,H,T,D] buffers (NBN=24, col>>10 selects).
template <int CALLS>
DEV void stage_tile(const __bf16* __restrict__ G, __bf16* L, int t, int wid, int K) {
#pragma unroll
  for (int it = 0; it < CALLS; ++it) {
    int e = it * 512 + t;
    int row = e >> 3;
    int c0 = ((e & 7) ^ (row & 7)) << 3;
    gload_lds16(G + (size_t)row * K + c0, L + it * 4096 + wid * 512);
  }
}

__global__ __launch_bounds__(512, 2) void gemm_bt(const __bf16* __restrict__ A,
                                                  const __bf16* __restrict__ Bt,
                                                  float* __restrict__ Cf,
                                                  __bf16* __restrict__ Cb,
                                                  int mode, int NBN) {
  const int t = threadIdx.x;
  const int wid = t >> 6, lane = t & 63;
  const int fr = lane & 15, fkq = lane >> 4, fk = fkq * 8;
  const int wr = wid >> 2, wc = wid & 3;
  const int K = 1024;
  // XCD-aware bijective remap (gridDim.x % 8 == 0)
  int nwg = gridDim.x, lin = blockIdx.x;
  int q = nwg >> 3;
  int id2 = (lin & 7) * q + (lin >> 3);
  int bn = id2 % NBN, bm = id2 / NBN;
  __shared__ __bf16 lA[2][16384];  // [256][64] swz, 32KB each
  __shared__ __bf16 lB[2][8192];   // [128][64] swz, 16KB each
  const __bf16* Ab = A + (size_t)(bm * 256) * K;
  const __bf16* Bb = Bt + (size_t)(bn * 128) * K;
  f32x4 acc[8][2];
#pragma unroll
  for (int m = 0; m < 8; ++m) {
    acc[m][0] = 0.f;
    acc[m][1] = 0.f;
  }
  // prologue: stage tile 0 (6 vmem instructions per thread/wave)
  stage_tile<4>(Ab, lA[0], t, wid, K);
  stage_tile<2>(Bb, lB[0], t, wid, K);
  for (int kt = 0; kt < 16; ++kt) {
    int cur = kt & 1;
    // barrier 1: all waves finished reading buf cur^1 (as tile kt-1's cur)
    asm volatile("s_barrier" ::: "memory");
    if (kt < 15) {
      stage_tile<4>(Ab + (kt + 1) * 64, lA[cur ^ 1], t, wid, K);
      stage_tile<2>(Bb + (kt + 1) * 64, lB[cur ^ 1], t, wid, K);
      // wait tile kt's 6 loads (older); tile kt+1's 6 stay in flight
      asm volatile("s_waitcnt vmcnt(6)" ::: "memory");
    } else {
      asm volatile("s_waitcnt vmcnt(0)" ::: "memory");
    }
    // barrier 2: every wave's tile-kt loads have landed
    asm volatile("s_barrier" ::: "memory");
#pragma unroll
    for (int kk = 0; kk < 2; ++kk) {
      bf16x8 af[8], bg[2];
#pragma unroll
      for (int m = 0; m < 8; ++m)
        af[m] = ldfrag(lA[cur], wr * 128 + m * 16 + fr, kk * 32 + fk, 64);
#pragma unroll
      for (int nn = 0; nn < 2; ++nn)
        bg[nn] = ldfrag(lB[cur], wc * 32 + nn * 16 + fr, kk * 32 + fk, 64);
#pragma unroll
      for (int m = 0; m < 8; ++m)
#pragma unroll
        for (int nn = 0; nn < 2; ++nn)
          acc[m][nn] =
              __builtin_amdgcn_mfma_f32_16x16x32_bf16(af[m], bg[nn], acc[m][nn], 0, 0, 0);
    }
  }
#pragma unroll
  for (int m = 0; m < 8; ++m) {
#pragma unroll
    for (int nn = 0; nn < 2; ++nn) {
#pragma unroll
      for (int rg = 0; rg < 4; ++rg) {
        int row = bm * 256 + wr * 128 + m * 16 + fkq * 4 + rg;
        int col = bn * 128 + wc * 32 + nn * 16 + fr;
        float val = acc[m][nn][rg];
        if (mode == 0) {
          Cf[(size_t)row * 1024 + col] = val;
        } else {
          int buf = col >> 10, cc = col & 1023;
          int b = row >> 11, tk = row & 2047;
          int h = cc >> 6, d = cc & 63;
          Cb[(size_t)buf * 8388608 + (((size_t)b * 16 + h) * 2048 + tk) * 64 + d] =
              (__bf16)val;
        }
      }
    }
  }
}

// ---------------- fused WY solve + A/B (doubling inverse, register-resident) ----
// LDS 51.2 KB -> 3 blocks/CU. Wave w owns rows w*16..+15 of U,W in C/D regs.
__global__ __launch_bounds__(512, 6) void wy_ab(const __bf16* __restrict__ kb,
                                                const __bf16* __restrict__ vb,
                                                const float* __restrict__ ar,
                                                const float* __restrict__ br,
                                                __bf16* __restrict__ Ug,
                                                __bf16* __restrict__ Wgb,
                                                __bf16* __restrict__ ATg,
                                                __bf16* __restrict__ Bop) {
  int n = blockIdx.x, h = (n >> 4) & 15;
  float a = sgm(ar[h]) * 0.5f;
  float b = sgm(br[h]) * 0.5f;
  int t = threadIdx.x, wid = t >> 6, lane = t & 63;
  int fr = lane & 15, fkq = lane >> 4, fk = fkq * 8;
  __shared__ __attribute__((aligned(16))) char pool[51200];
  __bf16* Ks  = (__bf16*)pool;            // [128][64] swz; dead after U-init
  __bf16* MTu = (__bf16*)pool;            // [64][128] swz == U^T (overlays Ks)
  __bf16* MTw = (__bf16*)(pool + 16384);  // [64][128] swz == W^T
  __bf16* Sng = (__bf16*)(pool + 32768);  // 36 tiles; diag slots -> inv
  __bf16* KT  = (__bf16*)(pool + 32768);  // [64][128] swz (built late over Sng)
  const __bf16* kg = kb + (size_t)n * 8192;
  const __bf16* vg = vb + (size_t)n * 8192;
  bf16x8 zz;
#pragma unroll
  for (int e = 0; e < 8; ++e) zz[e] = (__bf16)0.f;
  f32x4 c0 = {0.f, 0.f, 0.f, 0.f};
  // stage: normalize k -> Ks (values kept in kreg for the late KT build)
  bf16x4 kreg[4];
#pragma unroll
  for (int it = 0; it < 4; ++it) {
    int u = it * 512 + t;
    int row = u >> 4, c4 = (u & 15) * 4;
    bf16x4 kh = ((const bf16x4*)kg)[u];
    float kf[4];
#pragma unroll
    for (int e = 0; e < 4; ++e) kf[e] = (float)kh[e];
    float ssq = kf[0] * kf[0] + kf[1] * kf[1] + kf[2] * kf[2] + kf[3] * kf[3];
    ssq = row16_reduce(ssq);
    float inv = 1.f / fmaxf(sqrtf(ssq), 1e-12f);
    bf16x4 kn;
#pragma unroll
    for (int e = 0; e < 4; ++e) kn[e] = (__bf16)(kf[e] * inv);
    kreg[it] = kn;
    stb4(Ks, row, c4, 64, kn);
  }
  __syncthreads();
  // S_neg = -(a * tril(KK^T)) packed-lower bf16 (diag tiles: col>=row -> 0)
  for (int p = wid; p < 36; p += 8) {
    int tr = 0, pp = p;
    while (pp > tr) { pp -= (tr + 1); ++tr; }
    int sc = pp;
    f32x4 acc = {0.f, 0.f, 0.f, 0.f};
#pragma unroll
    for (int ks = 0; ks < 2; ++ks)
      acc = __builtin_amdgcn_mfma_f32_16x16x32_bf16(
          ldfrag(Ks, tr * 16 + fr, ks * 32 + fk, 64),
          ldfrag(Ks, sc * 16 + fr, ks * 32 + fk, 64), acc, 0, 0, 0);
    __bf16* dst = Sng + stile(tr, sc);
#pragma unroll
    for (int rg = 0; rg < 4; ++rg) {
      int r = fkq * 4 + rg;
      float v = -a * acc[rg];
      if (tr == sc && fr >= r) v = 0.f;
      dst[r * 16 + fr] = (__bf16)v;
    }
  }
  // U,W init in C/D-layout registers (Ks reads complete before overlays)
  f32x4 U[4], W[4];
#pragma unroll
  for (int ct = 0; ct < 4; ++ct) {
#pragma unroll
    for (int rg = 0; rg < 4; ++rg) {
      int row = wid * 16 + fkq * 4 + rg, col = ct * 16 + fr;
      U[ct][rg] = (float)ldsc(Ks, row, col, 64);
      W[ct][rg] = b * (float)vg[row * 64 + col];
    }
  }
  __syncthreads();
  // ---- parallel diag inverse: inv(I-N) = (I+N)(I+N^2)(I+N^4)(I+N^8) ----
  {
    __bf16* scr  = ((__bf16*)pool) + wid * 2048;  // 4KB per wave
    __bf16* tNT  = scr;
    __bf16* tN2R = scr + 256;
    __bf16* tN2T = scr + 512;
    __bf16* tN4R = scr + 768;
    __bf16* tN4T = scr + 1024;
    __bf16* tN8T = scr + 1280;
    __bf16* tPR  = scr + 1536;
    __bf16* Nd = Sng + stile(wid, wid);
    float nv[4];
#pragma unroll
    for (int rg = 0; rg < 4; ++rg) {
      nv[rg] = (float)Nd[(fkq * 4 + rg) * 16 + fr];
      tNT[fr * 16 + fkq * 4 + rg] = (__bf16)nv[rg];
    }
    asm volatile("s_waitcnt lgkmcnt(0)" ::: "memory");
    bf16x8 af = (fk < 16) ? *(const bf16x8*)(Nd + fr * 16 + fk) : zz;
    bf16x8 bop = (fk < 16) ? *(const bf16x8*)(tNT + fr * 16 + fk) : zz;
    f32x4 X = __builtin_amdgcn_mfma_f32_16x16x32_bf16(af, bop, c0, 0, 0, 0);  // N^2
#pragma unroll
    for (int rg = 0; rg < 4; ++rg) {
      __bf16 v = (__bf16)X[rg];
      tN2R[(fkq * 4 + rg) * 16 + fr] = v;
      tN2T[fr * 16 + fkq * 4 + rg] = v;
    }
    asm volatile("s_waitcnt lgkmcnt(0)" ::: "memory");
    af = (fk < 16) ? *(const bf16x8*)(tN2R + fr * 16 + fk) : zz;
    bop = (fk < 16) ? *(const bf16x8*)(tN2T + fr * 16 + fk) : zz;
    X = __builtin_amdgcn_mfma_f32_16x16x32_bf16(af, bop, c0, 0, 0, 0);        // N^4
#pragma unroll
    for (int rg = 0; rg < 4; ++rg) {
      __bf16 v = (__bf16)X[rg];
      tN4R[(fkq * 4 + rg) * 16 + fr] = v;
      tN4T[fr * 16 + fkq * 4 + rg] = v;
    }
    asm volatile("s_waitcnt lgkmcnt(0)" ::: "memory");
    af = (fk < 16) ? *(const bf16x8*)(tN4R + fr * 16 + fk) : zz;
    bop = (fk < 16) ? *(const bf16x8*)(tN4T + fr * 16 + fk) : zz;
    X = __builtin_amdgcn_mfma_f32_16x16x32_bf16(af, bop, c0, 0, 0, 0);        // N^8
#pragma unroll
    for (int rg = 0; rg < 4; ++rg)
      tN8T[fr * 16 + fkq * 4 + rg] = (__bf16)X[rg];
    // P = I + N, then P *= (I+N^2), (I+N^4), (I+N^8) via C-init MFMA
    f32x4 P;
#pragma unroll
    for (int rg = 0; rg < 4; ++rg)
      P[rg] = ((fkq * 4 + rg) == fr ? 1.f : 0.f) + nv[rg];
#pragma unroll
    for (int d = 0; d < 3; ++d) {
      const __bf16* tB = (d == 0) ? tN2T : (d == 1) ? tN4T : tN8T;
#pragma unroll
      for (int rg = 0; rg < 4; ++rg)
        tPR[(fkq * 4 + rg) * 16 + fr] = (__bf16)P[rg];
      asm volatile("s_waitcnt lgkmcnt(0)" ::: "memory");
      af = (fk < 16) ? *(const bf16x8*)(tPR + fr * 16 + fk) : zz;
      bop = (fk < 16) ? *(const bf16x8*)(tB + fr * 16 + fk) : zz;
      P = __builtin_amdgcn_mfma_f32_16x16x32_bf16(af, bop, P, 0, 0, 0);
    }
#pragma unroll
    for (int rg = 0; rg < 4; ++rg)
      Nd[(fkq * 4 + rg) * 16 + fr] = (__bf16)P[rg];  // inv -> diag slot
  }
  __syncthreads();
  // right-looking substitution: stage bb = {wave bb: stage rhs, x = inv*rhs,
  // rewrite; barrier; waves>bb rank-16 MFMA update}
  for (int bb = 0; bb < 8; ++bb) {
    if (wid == bb) {
#pragma unroll
      for (int ct = 0; ct < 4; ++ct) {
        bf16x4 uu, ww;
#pragma unroll
        for (int rg = 0; rg < 4; ++rg) {
          uu[rg] = (__bf16)U[ct][rg];
          ww[rg] = (__bf16)W[ct][rg];
        }
        stb4(MTu, ct * 16 + fr, bb * 16 + fkq * 4, 128, uu);
        stb4(MTw, ct * 16 + fr, bb * 16 + fkq * 4, 128, ww);
      }
      asm volatile("s_waitcnt lgkmcnt(0)" ::: "memory");
      const __bf16* invT = Sng + stile(bb, bb);
      bf16x8 afv = (fk < 16) ? *(const bf16x8*)(invT + fr * 16 + fk) : zz;
#pragma unroll
      for (int ct = 0; ct < 4; ++ct) {
        bf16x8 bu = (fk < 16) ? ldfrag(MTu, ct * 16 + fr, bb * 16 + fk, 128) : zz;
        bf16x8 bw = (fk < 16) ? ldfrag(MTw, ct * 16 + fr, bb * 16 + fk, 128) : zz;
        U[ct] = __builtin_amdgcn_mfma_f32_16x16x32_bf16(afv, bu, c0, 0, 0, 0);
        W[ct] = __builtin_amdgcn_mfma_f32_16x16x32_bf16(afv, bw, c0, 0, 0, 0);
      }
#pragma unroll
      for (int ct = 0; ct < 4; ++ct) {
        bf16x4 uu, ww;
#pragma unroll
        for (int rg = 0; rg < 4; ++rg) {
          uu[rg] = (__bf16)U[ct][rg];
          ww[rg] = (__bf16)W[ct][rg];
        }
        stb4(MTu, ct * 16 + fr, bb * 16 + fkq * 4, 128, uu);
        stb4(MTw, ct * 16 + fr, bb * 16 + fkq * 4, 128, ww);
      }
    }
    __syncthreads();
    if (wid > bb) {
      bf16x8 af = zz;
      if (fk < 16) af = *(const bf16x8*)(Sng + stile(wid, bb) + fr * 16 + fk);
#pragma unroll
      for (int ct = 0; ct < 4; ++ct) {
        bf16x8 bu = zz, bw = zz;
        if (fk < 16) {
          bu = ldfrag(MTu, ct * 16 + fr, bb * 16 + fk, 128);
          bw = ldfrag(MTw, ct * 16 + fr, bb * 16 + fk, 128);
        }
        U[ct] = __builtin_amdgcn_mfma_f32_16x16x32_bf16(af, bu, U[ct], 0, 0, 0);
        W[ct] = __builtin_amdgcn_mfma_f32_16x16x32_bf16(af, bw, W[ct], 0, 0, 0);
      }
    }
  }
  // build KT over Sng (dead after last stage barrier) from register-held k
#pragma unroll
  for (int it = 0; it < 4; ++it) {
    int u = it * 512 + t;
    int row = u >> 4, c4 = (u & 15) * 4;
#pragma unroll
    for (int e = 0; e < 4; ++e) stb(KT, c4 + e, row, 128, kreg[it][e]);
  }
  // global bf16 write of U,W in [t][d] layout, straight from registers
  __bf16* ugo = Ug + (size_t)n * 8192;
  __bf16* wgo = Wgb + (size_t)n * 8192;
#pragma unroll
  for (int ct = 0; ct < 4; ++ct)
#pragma unroll
    for (int rg = 0; rg < 4; ++rg) {
      int row = wid * 16 + fkq * 4 + rg, col = ct * 16 + fr;
      ugo[row * 64 + col] = (__bf16)U[ct][rg];
      wgo[row * 64 + col] = (__bf16)W[ct][rg];
    }
  __syncthreads();
  // AT = I - a*(K^T U)  (pre-swizzled bf16), B = W^T K (bf16)
#pragma unroll
  for (int q = 0; q < 4; ++q) {
    int tile = wid + q * 8;  // 0-15 -> AT, 16-31 -> B
    int mat = tile >> 4;
    int ti = (tile >> 2) & 3, tj = tile & 3;
    f32x4 acc = {0.f, 0.f, 0.f, 0.f};
    if (mat == 0) {
#pragma unroll
      for (int ks = 0; ks < 4; ++ks)
        acc = __builtin_amdgcn_mfma_f32_16x16x32_bf16(
            ldfrag(KT, ti * 16 + fr, ks * 32 + fk, 128),
            ldfrag(MTu, tj * 16 + fr, ks * 32 + fk, 128), acc, 0, 0, 0);
      char* dst = (char*)(ATg + (size_t)n * 4096);
#pragma unroll
      for (int rg = 0; rg < 4; ++rg) {
        int i = ti * 16 + fkq * 4 + rg, j = tj * 16 + fr;
        float v = (i == j ? 1.f : 0.f) - a * acc[rg];
        *(__bf16*)(dst + swzb(i, j, 64)) = (__bf16)v;
      }
    } else {
#pragma unroll
      for (int ks = 0; ks < 4; ++ks)
        acc = __builtin_amdgcn_mfma_f32_16x16x32_bf16(
            ldfrag(MTw, ti * 16 + fr, ks * 32 + fk, 128),
            ldfrag(KT, tj * 16 + fr, ks * 32 + fk, 128), acc, 0, 0, 0);
      __bf16* dst = Bop + (size_t)n * 4096;
#pragma unroll
      for (int rg = 0; rg < 4; ++rg)
        dst[(ti * 16 + fkq * 4 + rg) * 64 + tj * 16 + fr] = (__bf16)acc[rg];
    }
  }
}

// ---------------- inter-chunk scan (MFMA) ----------------
__global__ __launch_bounds__(512) void chunk_scan(const __bf16* __restrict__ ATg,
                                                  const __bf16* __restrict__ Bop,
                                                  __bf16* __restrict__ Mst,
                                                  float* __restrict__ Mfinal) {
  int bh = blockIdx.x;
  int t = threadIdx.x, wid = t >> 6, lane = t & 63;
  int fr = lane & 15, fkq = lane >> 4, fk = fkq * 8;
  int ti = wid & 3, tj0 = (wid >> 2) << 1;
  __shared__ __bf16 Mh[4096];    // [64][64] swz
  __shared__ __bf16 Ml[4096];    // [64][64] swz
  __shared__ __bf16 At[2][4096]; // [64][64], pre-swizzled via linear gload_lds
  f32x4 acc[2];
  acc[0] = 0.f;
  acc[1] = 0.f;
  gload_lds16(ATg + (size_t)bh * 16 * 4096 + t * 8, At[0] + t * 8);
  for (int c = 0; c < 16; ++c) {
    int cur = c & 1;
    if (c < 15)
      gload_lds16(ATg + ((size_t)(bh * 16 + c + 1)) * 4096 + t * 8,
                  At[cur ^ 1] + t * 8);
    __bf16* mstc = Mst + ((size_t)(bh * 16 + c)) * 4096;
#pragma unroll
    for (int p = 0; p < 2; ++p) {
      int tj = tj0 + p;
#pragma unroll
      for (int rg = 0; rg < 4; ++rg) {
        int row = ti * 16 + fkq * 4 + rg, col = tj * 16 + fr;
        float v = acc[p][rg];
        __bf16 hi = (__bf16)v;
        mstc[row * 64 + col] = hi;
        stb(Mh, row, col, 64, hi);
        stb(Ml, row, col, 64, (__bf16)(v - (float)hi));
      }
    }
    __syncthreads();
    size_t bb = ((size_t)(bh * 16 + c)) * 4096;
#pragma unroll
    for (int p = 0; p < 2; ++p) {
      int tj = tj0 + p;
      f32x4 na;
#pragma unroll
      for (int rg = 0; rg < 4; ++rg)
        na[rg] = (float)Bop[bb + (ti * 16 + fkq * 4 + rg) * 64 + tj * 16 + fr];
#pragma unroll
      for (int ks = 0; ks < 2; ++ks) {
        bf16x8 bfrag = ldfrag(At[cur], tj * 16 + fr, ks * 32 + fk, 64);
        bf16x8 ah = ldfrag(Mh, ti * 16 + fr, ks * 32 + fk, 64);
        bf16x8 al = ldfrag(Ml, ti * 16 + fr, ks * 32 + fk, 64);
        na = __builtin_amdgcn_mfma_f32_16x16x32_bf16(ah, bfrag, na, 0, 0, 0);
        na = __builtin_amdgcn_mfma_f32_16x16x32_bf16(al, bfrag, na, 0, 0, 0);
      }
      acc[p] = na;
    }
    __syncthreads();
  }
#pragma unroll
  for (int p = 0; p < 2; ++p) {
    int tj = tj0 + p;
#pragma unroll
    for (int rg = 0; rg < 4; ++rg)
      Mfinal[(size_t)bh * 4096 + (ti * 16 + fkq * 4 + rg) * 64 + tj * 16 + fr] =
          acc[p][rg];
  }
}

// ---------------- Y assembly (plain bf16) ----------------
__global__ __launch_bounds__(512, 4) void y_assemble(const __bf16* __restrict__ qb,
                                                     const __bf16* __restrict__ kb,
                                                     const __bf16* __restrict__ Ug,
                                                     const __bf16* __restrict__ Wgb,
                                                     const __bf16* __restrict__ Mst,
                                                     const float* __restrict__ ar,
                                                     __bf16* __restrict__ ybf) {
  int n = blockIdx.x, h = (n >> 4) & 15, b = n >> 8, c = n & 15;
  float a = sgm(ar[h]) * 0.5f;
  int t = threadIdx.x, wid = t >> 6, lane = t & 63;
  int fr = lane & 15, fk = (lane >> 4) * 8;
  __shared__ __bf16 Qs[8192];    // [128][64] swz
  __shared__ __bf16 Rs[8192];    // [128][64] swz: K then U
  __shared__ __bf16 M0s[4096];   // [64][64] swz
  __shared__ __bf16 Gs[10240];   // 40 packed 16x16 tiles
  __shared__ __bf16 WtT[8192];   // [64][128] swz
  const __bf16* qg = qb + (size_t)n * 8192;
  const __bf16* kg = kb + (size_t)n * 8192;
  const __bf16* mg = Mst + (size_t)n * 4096;
#pragma unroll
  for (int it = 0; it < 4; ++it) {
    int u = it * 512 + t;
    int row = u >> 4, c4 = (u & 15) * 4;
    stb4(Qs, row, c4, 64, ((const bf16x4*)qg)[u]);
    bf16x4 kh = ((const bf16x4*)kg)[u];
    float kf[4];
#pragma unroll
    for (int e = 0; e < 4; ++e) kf[e] = (float)kh[e];
    float ssq = kf[0] * kf[0] + kf[1] * kf[1] + kf[2] * kf[2] + kf[3] * kf[3];
    ssq = row16_reduce(ssq);
    float inv = 1.f / fmaxf(sqrtf(ssq), 1e-12f);
    bf16x4 kn;
#pragma unroll
    for (int e = 0; e < 4; ++e) kn[e] = (__bf16)(kf[e] * inv);
    stb4(Rs, row, c4, 64, kn);
  }
#pragma unroll
  for (int it = 0; it < 2; ++it) {
    int u = it * 512 + t;
    int row = u >> 4, c4 = (u & 15) * 4;
    stb4(M0s, row, c4, 64, ((const bf16x4*)mg)[u]);
  }
#pragma unroll
  for (int pz = 0; pz < 2; ++pz) {
    int e = pz * 512 + t;
    int m = e >> 8, idx = e & 255;
    Gs[(2 * m * m + 4 * m + 1) * 256 + idx] = (__bf16)0.f;
  }
  __syncthreads();
  // P1: G = tril(Q K^T, -1), packed-lower bf16
  for (int p = wid; p < 36; p += 8) {
    int tr = 0, pp = p;
    while (pp > tr) { pp -= (tr + 1); ++tr; }
    int sc = pp;
    f32x4 acc = {0.f, 0.f, 0.f, 0.f};
#pragma unroll
    for (int ks = 0; ks < 2; ++ks)
      acc = __builtin_amdgcn_mfma_f32_16x16x32_bf16(
          ldfrag(Qs, tr * 16 + fr, ks * 32 + fk, 64),
          ldfrag(Rs, sc * 16 + fr, ks * 32 + fk, 64), acc, 0, 0, 0);
    int row0 = (lane >> 4) * 4, col = lane & 15;
    __bf16* gt = Gs + (goffn(tr) + sc) * 256;
#pragma unroll
    for (int rg = 0; rg < 4; ++rg) {
      int r = row0 + rg;
      float v = acc[rg];
      if (tr == sc && col >= r) v = 0.f;
      gt[r * 16 + col] = (__bf16)v;
    }
  }
  __syncthreads();
  // P2: restage Rs <- U
  const __bf16* ug = Ug + (size_t)n * 8192;
  const __bf16* wg = Wgb + (size_t)n * 8192;
#pragma unroll
  for (int it = 0; it < 4; ++it) {
    int u = it * 512 + t;
    int row = u >> 4, c4 = (u & 15) * 4;
    stb4(Rs, row, c4, 64, ((const bf16x4*)ug)[u]);
  }
  __syncthreads();
  // P3: WtT[i][s] = W[s][i] - a*(U M0^T)[s][i]
#pragma unroll
  for (int q = 0; q < 4; ++q) {
    int tile = wid + q * 8;
    int ti = tile >> 2, tj = tile & 3;
    f32x4 acc = {0.f, 0.f, 0.f, 0.f};
#pragma unroll
    for (int ks = 0; ks < 2; ++ks)
      acc = __builtin_amdgcn_mfma_f32_16x16x32_bf16(
          ldfrag(Rs, ti * 16 + fr, ks * 32 + fk, 64),
          ldfrag(M0s, tj * 16 + fr, ks * 32 + fk, 64), acc, 0, 0, 0);
    int row0 = (lane >> 4) * 4, col = lane & 15;
#pragma unroll
    for (int rg = 0; rg < 4; ++rg) {
      int s = ti * 16 + row0 + rg, i = tj * 16 + col;
      float wv = (float)wg[s * 64 + i];
      stb(WtT, i, s, 128, (__bf16)(wv - a * acc[rg]));
    }
  }
  __syncthreads();
  // P4: Y = Q M0^T + G Wt
  __bf16* yg = ybf + ((size_t)(b * 2048 + c * 128)) * 1024 + h * 64;
#pragma unroll
  for (int q = 0; q < 4; ++q) {
    int tile = wid + q * 8;
    int ti = tile >> 2, tj = tile & 3;
    f32x4 acc = {0.f, 0.f, 0.f, 0.f};
#pragma unroll
    for (int ks = 0; ks < 2; ++ks)
      acc = __builtin_amdgcn_mfma_f32_16x16x32_bf16(
          ldfrag(Qs, ti * 16 + fr, ks * 32 + fk, 64),
          ldfrag(M0s, tj * 16 + fr, ks * 32 + fk, 64), acc, 0, 0, 0);
    int goffv = goffn(ti);
    int np = (ti + 2) >> 1;
    for (int ks = 0; ks < np; ++ks) {
      int gtile = goffv + ks * 2 + (fk >> 4);
      bf16x8 af = *(const bf16x8*)(Gs + gtile * 256 + fr * 16 + (fk & 15));
      acc = __builtin_amdgcn_mfma_f32_16x16x32_bf16(
          af, ldfrag(WtT, tj * 16 + fr, ks * 32 + fk, 128), acc, 0, 0, 0);
    }
    int row0 = (lane >> 4) * 4, col = lane & 15;
#pragma unroll
    for (int rg = 0; rg < 4; ++rg) {
      int tt = ti * 16 + row0 + rg, d = tj * 16 + col;
      yg[(size_t)tt * 1024 + d] = (__bf16)acc[rg];
    }
  }
}

extern "C" void kernel_launch(void* const* d_in, const int* in_sizes, int n_in,
                              void* d_out, int out_size, void* d_ws, size_t ws_size,
                              hipStream_t stream) {
  const float* x  = (const float*)d_in[0];
  const float* Wq = (const float*)d_in[1];
  const float* Wk = (const float*)d_in[2];
  const float* Wv = (const float*)d_in[3];
  const float* Wo = (const float*)d_in[4];
  const float* ar = (const float*)d_in[5];
  const float* br = (const float*)d_in[6];

  char* ws = (char*)d_ws;
  __bf16* xb    = (__bf16*)ws;                     // 16.8 MB, reused as ybf
  __bf16* ybf   = xb;
  __bf16* wqkvt = (__bf16*)(ws + (17u << 20));     // 6 MB packed [3072][1024]
  __bf16* wot   = (__bf16*)(ws + (23u << 20));     // 2 MB
  __bf16* qb    = (__bf16*)(ws + (25u << 20));     // q,k,v contiguous, 8388608 elems each
  __bf16* kb    = qb + 8388608;
  __bf16* vb    = kb + 8388608;                    // ends at ~75.3 MB
  __bf16* Ugb   = (__bf16*)(ws + (76u << 20));
  __bf16* Wgb   = (__bf16*)(ws + (93u << 20));
  __bf16* ATg   = (__bf16*)(ws + (110u << 20));    // 8.4 MB (pre-swizzled)
  __bf16* Bop   = (__bf16*)(ws + (127u << 20));    // 8.4 MB bf16
  __bf16* Mst   = (__bf16*)(ws + (144u << 20));    // 8.4 MB

  float* yout = (float*)d_out;                     // [8192,1024] f32
  float* Mfin = yout + 8388608;

  cast_f32_bf16<<<8192, 256, 0, stream>>>(x, xb);
  dim3 tg(32, 32);
  transpose_cast<<<tg, 256, 0, stream>>>(Wq, wqkvt);
  transpose_cast<<<tg, 256, 0, stream>>>(Wk, wqkvt + (1u << 20));
  transpose_cast<<<tg, 256, 0, stream>>>(Wv, wqkvt + (2u << 20));
  transpose_cast<<<tg, 256, 0, stream>>>(Wo, wot);

  // fused QKV GEMM: M=8192, N=3072 -> grid 32*24 = 768 (3.0 rounds of 256 CUs)
  gemm_bt<<<768, 512, 0, stream>>>(xb, wqkvt, nullptr, qb, 1, 24);

  wy_ab<<<1024, 512, 0, stream>>>(kb, vb, ar, br, Ugb, Wgb, ATg, Bop);
  chunk_scan<<<64, 512, 0, stream>>>(ATg, Bop, Mst, Mfin);
  y_assemble<<<1024, 512, 0, stream>>>(qb, kb, Ugb, Wgb, Mst, ar, ybf);

  // final GEMM: M=8192, N=1024 -> grid 32*8 = 256 (1.0 rounds)
  gemm_bt<<<256, 512, 0, stream>>>(ybf, wot, yout, nullptr, 0, 8);
}